// Round 1
// baseline (2620.322 us; speedup 1.0000x reference)
//
#include <hip/hip_runtime.h>
#include <math.h>

static inline int cdiv(int a, int b){ return (a + b - 1) / b; }

// ---------------- graph build (CSR by dst) ----------------

__global__ void k_count_deg(const int* __restrict__ dst, int E, int* __restrict__ deg) {
    int e = blockIdx.x * 256 + threadIdx.x;
    if (e < E) atomicAdd(&deg[dst[e]], 1);
}

__global__ void k_scan_partial(const int* __restrict__ deg, int n, int* __restrict__ partial) {
    __shared__ int sd[256];
    int base = blockIdx.x * 1024;
    int sum = 0;
    for (int i = threadIdx.x; i < 1024; i += 256) {
        int idx = base + i;
        if (idx < n) sum += deg[idx];
    }
    sd[threadIdx.x] = sum;
    __syncthreads();
    for (int s = 128; s > 0; s >>= 1) {
        if (threadIdx.x < s) sd[threadIdx.x] += sd[threadIdx.x + s];
        __syncthreads();
    }
    if (threadIdx.x == 0) partial[blockIdx.x] = sd[0];
}

__global__ void k_scan_top(int* __restrict__ partial, int nb, int* __restrict__ offs, int n) {
    if (blockIdx.x == 0 && threadIdx.x == 0) {
        int run = 0;
        for (int i = 0; i < nb; i++) { int v = partial[i]; partial[i] = run; run += v; }
        offs[n] = run;   // == E
    }
}

__global__ void k_scan_final(const int* __restrict__ deg, int n,
                             const int* __restrict__ partial, int* __restrict__ offs) {
    __shared__ int sd[256];
    int tid = threadIdx.x;
    int base = blockIdx.x * 1024;
    int v[4]; int s0 = 0;
    #pragma unroll
    for (int j = 0; j < 4; j++) { int idx = base + tid*4 + j; v[j] = (idx < n) ? deg[idx] : 0; s0 += v[j]; }
    sd[tid] = s0;
    __syncthreads();
    for (int st = 1; st < 256; st <<= 1) {
        int t = (tid >= st) ? sd[tid - st] : 0;
        __syncthreads();
        sd[tid] += t;
        __syncthreads();
    }
    int ex = (tid > 0 ? sd[tid - 1] : 0) + partial[blockIdx.x];
    #pragma unroll
    for (int j = 0; j < 4; j++) {
        int idx = base + tid*4 + j;
        if (idx < n) offs[idx] = ex;
        ex += v[j];
    }
}

__global__ void k_copy_int(const int* __restrict__ a, int* __restrict__ b, int n) {
    int i = blockIdx.x * 256 + threadIdx.x;
    if (i < n) b[i] = a[i];
}

__global__ void k_fill_csr(const int* __restrict__ src, const int* __restrict__ dst, int E,
                           int* __restrict__ cursor, int* __restrict__ csr) {
    int e = blockIdx.x * 256 + threadIdx.x;
    if (e < E) { int d = dst[e]; int p = atomicAdd(&cursor[d], 1); csr[p] = src[e]; }
}

__global__ void k_dinv(const int* __restrict__ deg, float* __restrict__ dinv, int n) {
    int i = blockIdx.x * 256 + threadIdx.x;
    if (i < n) dinv[i] = 1.0f / sqrtf((float)(deg[i] + 1));   // +1 self-loop
}

// ---------------- GEMMs (fp32) ----------------

// C[M,256] = A[M,256] @ B[256,256], 64x64 tile, BK=32, 4x4 per thread
__global__ __launch_bounds__(256) void k_gemm_x256(const float* __restrict__ A,
                                                   const float* __restrict__ B,
                                                   float* __restrict__ C, int M) {
    __shared__ float As[64][33];
    __shared__ float Bs[32][64];
    int tid = threadIdx.x;
    int bm = blockIdx.x * 64;
    int bn = blockIdx.y * 64;
    int ty = tid >> 4, tx = tid & 15;
    float acc[4][4] = {};
    for (int k0 = 0; k0 < 256; k0 += 32) {
        {
            int c = tid & 31, r0 = tid >> 5;
            #pragma unroll
            for (int it = 0; it < 8; it++) {
                int r = r0 + it * 8;
                int gr = bm + r;
                As[r][c] = (gr < M) ? A[(size_t)gr * 256 + k0 + c] : 0.f;
            }
        }
        {
            int c = tid & 63, r0 = tid >> 6;
            #pragma unroll
            for (int it = 0; it < 8; it++) {
                int r = r0 + it * 4;
                Bs[r][c] = B[(size_t)(k0 + r) * 256 + bn + c];
            }
        }
        __syncthreads();
        #pragma unroll
        for (int k = 0; k < 32; k++) {
            float a[4], b[4];
            #pragma unroll
            for (int i = 0; i < 4; i++) a[i] = As[ty + 16*i][k];
            #pragma unroll
            for (int j = 0; j < 4; j++) b[j] = Bs[k][tx + 16*j];
            #pragma unroll
            for (int i = 0; i < 4; i++)
                #pragma unroll
                for (int j = 0; j < 4; j++) acc[i][j] += a[i] * b[j];
        }
        __syncthreads();
    }
    #pragma unroll
    for (int i = 0; i < 4; i++) {
        int gr = bm + ty + 16*i;
        if (gr < M) {
            #pragma unroll
            for (int j = 0; j < 4; j++) C[(size_t)gr * 256 + bn + tx + 16*j] = acc[i][j];
        }
    }
}

// C[M,NC] = A[M,64] @ B[64,NC]   (NC = 128 or 32)
template<int NC>
__global__ __launch_bounds__(256) void k_gemm_k64(const float* __restrict__ A,
                                                  const float* __restrict__ B,
                                                  float* __restrict__ C, int M) {
    constexpr int TN = NC / 16;
    __shared__ float As[64][65];
    __shared__ float Bs[64][NC];
    int tid = threadIdx.x;
    int bm = blockIdx.x * 64;
    int ty = tid >> 4, tx = tid & 15;
    {
        int c = tid & 63, r0 = tid >> 6;
        #pragma unroll
        for (int it = 0; it < 16; it++) {
            int r = r0 + it * 4;
            int gr = bm + r;
            As[r][c] = (gr < M) ? A[(size_t)gr * 64 + c] : 0.f;
        }
    }
    for (int i = tid; i < 64 * NC; i += 256) Bs[i / NC][i % NC] = B[i];
    __syncthreads();
    float acc[4][TN] = {};
    #pragma unroll
    for (int k = 0; k < 64; k++) {
        float a[4], b[TN];
        #pragma unroll
        for (int i = 0; i < 4; i++) a[i] = As[ty + 16*i][k];
        #pragma unroll
        for (int j = 0; j < TN; j++) b[j] = Bs[k][tx + 16*j];
        #pragma unroll
        for (int i = 0; i < 4; i++)
            #pragma unroll
            for (int j = 0; j < TN; j++) acc[i][j] += a[i] * b[j];
    }
    #pragma unroll
    for (int i = 0; i < 4; i++) {
        int gr = bm + ty + 16*i;
        if (gr < M) {
            #pragma unroll
            for (int j = 0; j < TN; j++) C[(size_t)gr * NC + tx + 16*j] = acc[i][j];
        }
    }
}

// ---------------- attention dots: a_s[n,h] = <h[n,h,:], att_s[h,:]> ----------------

template<int HEADS>
__global__ void k_att_dots(const float* __restrict__ hpre, const float* __restrict__ att_s,
                           const float* __restrict__ att_d, float* __restrict__ as_n,
                           float* __restrict__ ad_n, int n_nodes) {
    int idx = blockIdx.x * 256 + threadIdx.x;
    if (idx >= n_nodes * HEADS) return;
    int h = idx & (HEADS - 1);
    const float* row = hpre + (size_t)idx * 64;
    float s = 0.f, d = 0.f;
    #pragma unroll
    for (int k = 0; k < 64; k++) {
        float v = row[k];
        s += v * att_s[h * 64 + k];
        d += v * att_d[h * 64 + k];
    }
    as_n[idx] = s; ad_n[idx] = d;
}

// ---------------- GAT aggregate: one wave per dst node, lane = feature dim ----------------

template<int HEADS>
__global__ __launch_bounds__(256) void k_gat_agg(const float* __restrict__ hpre,
        const float* __restrict__ as_n, const float* __restrict__ ad_n,
        const float* __restrict__ bias,
        const int* __restrict__ offs, const int* __restrict__ csr,
        float* __restrict__ out, int n_nodes) {
    int wid = (blockIdx.x * blockDim.x + threadIdx.x) >> 6;
    int lane = threadIdx.x & 63;
    if (wid >= n_nodes) return;
    const int n = wid;
    const int beg = offs[n], end = offs[n + 1];

    float adh[HEADS], eself[HEADS], m[HEADS];
    #pragma unroll
    for (int h = 0; h < HEADS; h++) {
        adh[h] = ad_n[n * HEADS + h];
        float e = as_n[n * HEADS + h] + adh[h];
        e = e > 0.f ? e : 0.2f * e;
        eself[h] = e; m[h] = e;
    }
    // pass A: max
    for (int j = beg; j < end; j++) {
        int s = csr[j];
        #pragma unroll
        for (int h = 0; h < HEADS; h++) {
            float e = as_n[s * HEADS + h] + adh[h];
            e = e > 0.f ? e : 0.2f * e;
            m[h] = fmaxf(m[h], e);
        }
    }
    // pass B: sum of exp
    float sum[HEADS];
    #pragma unroll
    for (int h = 0; h < HEADS; h++) sum[h] = expf(eself[h] - m[h]);
    for (int j = beg; j < end; j++) {
        int s = csr[j];
        #pragma unroll
        for (int h = 0; h < HEADS; h++) {
            float e = as_n[s * HEADS + h] + adh[h];
            e = e > 0.f ? e : 0.2f * e;
            sum[h] += expf(e - m[h]);
        }
    }
    float inv[HEADS];
    #pragma unroll
    for (int h = 0; h < HEADS; h++) inv[h] = 1.0f / (sum[h] + 1e-16f);
    // pass C: weighted gather, mean over heads folded in
    float acc = 0.f;
    #pragma unroll
    for (int h = 0; h < HEADS; h++)
        acc += expf(eself[h] - m[h]) * inv[h] * hpre[((size_t)n * HEADS + h) * 64 + lane];
    for (int j = beg; j < end; j++) {
        int s = csr[j];
        #pragma unroll
        for (int h = 0; h < HEADS; h++) {
            float e = as_n[s * HEADS + h] + adh[h];
            e = e > 0.f ? e : 0.2f * e;
            acc += expf(e - m[h]) * inv[h] * hpre[((size_t)s * HEADS + h) * 64 + lane];
        }
    }
    out[(size_t)n * 64 + lane] = fmaxf(acc * (1.0f / HEADS) + bias[lane], 0.f);
}

// ---------------- GCN aggregate ----------------

__global__ __launch_bounds__(256) void k_gcn_agg(const float* __restrict__ hpre,
        const float* __restrict__ dinv, const float* __restrict__ bias,
        const int* __restrict__ offs, const int* __restrict__ csr,
        float* __restrict__ out, int n_nodes) {
    int wid = (blockIdx.x * blockDim.x + threadIdx.x) >> 6;
    int lane = threadIdx.x & 63;
    if (wid >= n_nodes || lane >= 32) return;
    const int n = wid;
    const float dn = dinv[n];
    float acc = dn * dn * hpre[(size_t)n * 32 + lane];
    const int beg = offs[n], end = offs[n + 1];
    for (int j = beg; j < end; j++) {
        int s = csr[j];
        acc += dinv[s] * dn * hpre[(size_t)s * 32 + lane];
    }
    out[(size_t)n * 32 + lane] = fmaxf(acc + bias[lane], 0.f);
}

// ---------------- MLP head + sigmoid ----------------

__global__ __launch_bounds__(256) void k_mlp(const float* __restrict__ h3,
        const float* __restrict__ Wh1, const float* __restrict__ bh1,
        const float* __restrict__ Wh2, const float* __restrict__ bh2,
        float* __restrict__ out, int n_nodes) {
    __shared__ float w1[512];
    __shared__ float w2[16];
    __shared__ float b1s[16];
    __shared__ float b2s;
    int tid = threadIdx.x;
    for (int i = tid; i < 512; i += 256) w1[i] = Wh1[i];
    if (tid < 16) { w2[tid] = Wh2[tid]; b1s[tid] = bh1[tid]; }
    if (tid == 0) b2s = bh2[0];
    __syncthreads();
    int n = blockIdx.x * 256 + tid;
    if (n >= n_nodes) return;
    float x[32];
    const float4* p = (const float4*)(h3 + (size_t)n * 32);
    #pragma unroll
    for (int q = 0; q < 8; q++) { float4 v = p[q]; x[4*q] = v.x; x[4*q+1] = v.y; x[4*q+2] = v.z; x[4*q+3] = v.w; }
    float acc2 = b2s;
    #pragma unroll
    for (int j = 0; j < 16; j++) {
        float z = b1s[j];
        #pragma unroll
        for (int k = 0; k < 32; k++) z += x[k] * w1[k * 16 + j];
        z = fmaxf(z, 0.f);
        acc2 += z * w2[j];
    }
    out[n] = 1.0f / (1.0f + expf(-acc2));
}

// ---------------- launch ----------------

extern "C" void kernel_launch(void* const* d_in, const int* in_sizes, int n_in,
                              void* d_out, int out_size, void* d_ws, size_t ws_size,
                              hipStream_t stream) {
    const float* x   = (const float*)d_in[0];
    const int*   ei  = (const int*)d_in[1];
    const float* W1  = (const float*)d_in[2];
    const float* a1s = (const float*)d_in[3];
    const float* a1d = (const float*)d_in[4];
    const float* b1  = (const float*)d_in[5];
    const float* W2  = (const float*)d_in[6];
    const float* a2s = (const float*)d_in[7];
    const float* a2d = (const float*)d_in[8];
    const float* b2  = (const float*)d_in[9];
    const float* Wg  = (const float*)d_in[10];
    const float* bg  = (const float*)d_in[11];
    const float* Wh1 = (const float*)d_in[12];
    const float* bh1 = (const float*)d_in[13];
    const float* Wh2 = (const float*)d_in[14];
    const float* bh2 = (const float*)d_in[15];

    const int N = in_sizes[0] / 256;
    const int E = in_sizes[1] / 2;
    const int* srcs = ei;
    const int* dsts = ei + E;

    // workspace layout (fp32 unless noted); ~165 MB total
    float* R0   = (float*)d_ws;              // N*256  : h1pre / h2pre / h3pre
    float* R1   = R0 + (size_t)N * 256;      // N*64   : h1 / h3
    float* R2   = R1 + (size_t)N * 64;       // N*64   : h2
    float* As_  = R2 + (size_t)N * 64;       // N*4    : a_s per node
    float* Ad_  = As_ + (size_t)N * 4;       // N*4    : a_d per node
    float* dinv = Ad_ + (size_t)N * 4;       // N
    int* deg    = (int*)(dinv + N);          // N
    int* offs   = deg + N;                   // N+1
    int* cursor = offs + (N + 1);            // N
    int* csr    = cursor + N;                // E
    int* parts  = csr + E;                   // <=256

    // ---- CSR build ----
    hipMemsetAsync(deg, 0, (size_t)N * sizeof(int), stream);
    k_count_deg<<<cdiv(E, 256), 256, 0, stream>>>(dsts, E, deg);
    int nch = cdiv(N, 1024);
    k_scan_partial<<<nch, 256, 0, stream>>>(deg, N, parts);
    k_scan_top<<<1, 64, 0, stream>>>(parts, nch, offs, N);
    k_scan_final<<<nch, 256, 0, stream>>>(deg, N, parts, offs);
    k_copy_int<<<cdiv(N, 256), 256, 0, stream>>>(offs, cursor, N);
    k_fill_csr<<<cdiv(E, 256), 256, 0, stream>>>(srcs, dsts, E, cursor, csr);
    k_dinv<<<cdiv(N, 256), 256, 0, stream>>>(deg, dinv, N);

    // ---- GAT layer 1 (heads=4) ----
    dim3 g1(cdiv(N, 64), 4);
    k_gemm_x256<<<g1, 256, 0, stream>>>(x, W1, R0, N);
    k_att_dots<4><<<cdiv(N * 4, 256), 256, 0, stream>>>(R0, a1s, a1d, As_, Ad_, N);
    k_gat_agg<4><<<cdiv(N, 4), 256, 0, stream>>>(R0, As_, Ad_, b1, offs, csr, R1, N);

    // ---- GAT layer 2 (heads=2) ----
    k_gemm_k64<128><<<cdiv(N, 64), 256, 0, stream>>>(R1, W2, R0, N);
    k_att_dots<2><<<cdiv(N * 2, 256), 256, 0, stream>>>(R0, a2s, a2d, As_, Ad_, N);
    k_gat_agg<2><<<cdiv(N, 4), 256, 0, stream>>>(R0, As_, Ad_, b2, offs, csr, R2, N);

    // ---- GCN ----
    k_gemm_k64<32><<<cdiv(N, 64), 256, 0, stream>>>(R2, Wg, R0, N);
    k_gcn_agg<<<cdiv(N, 4), 256, 0, stream>>>(R0, dinv, bg, offs, csr, R1, N);

    // ---- MLP head ----
    k_mlp<<<cdiv(N, 256), 256, 0, stream>>>(R1, Wh1, bh1, Wh2, bh2, (float*)d_out, N);
}

// Round 2
// 1774.446 us; speedup vs baseline: 1.4767x; 1.4767x over previous
//
#include <hip/hip_runtime.h>
#include <math.h>

static inline int cdiv(int a, int b){ return (a + b - 1) / b; }

// ---------------- graph build (CSR by dst) ----------------

__global__ void k_count_deg(const int* __restrict__ dst, int E, int* __restrict__ deg) {
    int e = blockIdx.x * 256 + threadIdx.x;
    if (e < E) atomicAdd(&deg[dst[e]], 1);
}

__global__ void k_scan_partial(const int* __restrict__ deg, int n, int* __restrict__ partial) {
    __shared__ int sd[256];
    int base = blockIdx.x * 1024;
    int sum = 0;
    for (int i = threadIdx.x; i < 1024; i += 256) {
        int idx = base + i;
        if (idx < n) sum += deg[idx];
    }
    sd[threadIdx.x] = sum;
    __syncthreads();
    for (int s = 128; s > 0; s >>= 1) {
        if (threadIdx.x < s) sd[threadIdx.x] += sd[threadIdx.x + s];
        __syncthreads();
    }
    if (threadIdx.x == 0) partial[blockIdx.x] = sd[0];
}

__global__ void k_scan_top(int* __restrict__ partial, int nb, int* __restrict__ offs, int n) {
    if (blockIdx.x == 0 && threadIdx.x == 0) {
        int run = 0;
        for (int i = 0; i < nb; i++) { int v = partial[i]; partial[i] = run; run += v; }
        offs[n] = run;   // == E
    }
}

__global__ void k_scan_final(const int* __restrict__ deg, int n,
                             const int* __restrict__ partial, int* __restrict__ offs) {
    __shared__ int sd[256];
    int tid = threadIdx.x;
    int base = blockIdx.x * 1024;
    int v[4]; int s0 = 0;
    #pragma unroll
    for (int j = 0; j < 4; j++) { int idx = base + tid*4 + j; v[j] = (idx < n) ? deg[idx] : 0; s0 += v[j]; }
    sd[tid] = s0;
    __syncthreads();
    for (int st = 1; st < 256; st <<= 1) {
        int t = (tid >= st) ? sd[tid - st] : 0;
        __syncthreads();
        sd[tid] += t;
        __syncthreads();
    }
    int ex = (tid > 0 ? sd[tid - 1] : 0) + partial[blockIdx.x];
    #pragma unroll
    for (int j = 0; j < 4; j++) {
        int idx = base + tid*4 + j;
        if (idx < n) offs[idx] = ex;
        ex += v[j];
    }
}

__global__ void k_copy_int(const int* __restrict__ a, int* __restrict__ b, int n) {
    int i = blockIdx.x * 256 + threadIdx.x;
    if (i < n) b[i] = a[i];
}

__global__ void k_fill_csr(const int* __restrict__ src, const int* __restrict__ dst, int E,
                           int* __restrict__ cursor, int* __restrict__ csr) {
    int e = blockIdx.x * 256 + threadIdx.x;
    if (e < E) { int d = dst[e]; int p = atomicAdd(&cursor[d], 1); csr[p] = src[e]; }
}

__global__ void k_dinv(const int* __restrict__ deg, float* __restrict__ dinv, int n) {
    int i = blockIdx.x * 256 + threadIdx.x;
    if (i < n) dinv[i] = 1.0f / sqrtf((float)(deg[i] + 1));   // +1 self-loop
}

// ---------------- GEMMs (fp32) ----------------

// C[M,256] = A[M,256] @ B[256,256], 64x64 tile, BK=32, 4x4 per thread
__global__ __launch_bounds__(256) void k_gemm_x256(const float* __restrict__ A,
                                                   const float* __restrict__ B,
                                                   float* __restrict__ C, int M) {
    __shared__ float As[64][33];
    __shared__ float Bs[32][64];
    int tid = threadIdx.x;
    int bm = blockIdx.x * 64;
    int bn = blockIdx.y * 64;
    int ty = tid >> 4, tx = tid & 15;
    float acc[4][4] = {};
    for (int k0 = 0; k0 < 256; k0 += 32) {
        {
            int c = tid & 31, r0 = tid >> 5;
            #pragma unroll
            for (int it = 0; it < 8; it++) {
                int r = r0 + it * 8;
                int gr = bm + r;
                As[r][c] = (gr < M) ? A[(size_t)gr * 256 + k0 + c] : 0.f;
            }
        }
        {
            int c = tid & 63, r0 = tid >> 6;
            #pragma unroll
            for (int it = 0; it < 8; it++) {
                int r = r0 + it * 4;
                Bs[r][c] = B[(size_t)(k0 + r) * 256 + bn + c];
            }
        }
        __syncthreads();
        #pragma unroll
        for (int k = 0; k < 32; k++) {
            float a[4], b[4];
            #pragma unroll
            for (int i = 0; i < 4; i++) a[i] = As[ty + 16*i][k];
            #pragma unroll
            for (int j = 0; j < 4; j++) b[j] = Bs[k][tx + 16*j];
            #pragma unroll
            for (int i = 0; i < 4; i++)
                #pragma unroll
                for (int j = 0; j < 4; j++) acc[i][j] += a[i] * b[j];
        }
        __syncthreads();
    }
    #pragma unroll
    for (int i = 0; i < 4; i++) {
        int gr = bm + ty + 16*i;
        if (gr < M) {
            #pragma unroll
            for (int j = 0; j < 4; j++) C[(size_t)gr * 256 + bn + tx + 16*j] = acc[i][j];
        }
    }
}

// C[M,NC] = A[M,64] @ B[64,NC]; block computes 64 x NCB tile, 4xTN per thread.
// NCB<=64 so register tile is acc[4][<=4] -> no spilling (round-1 lesson:
// the TN=8 full-unroll variant hit the 256-VGPR cap and spilled ~1 GB to scratch).
template<int NCB, int NC>
__global__ __launch_bounds__(256) void k_gemm_k64(const float* __restrict__ A,
                                                  const float* __restrict__ B,
                                                  float* __restrict__ C, int M) {
    constexpr int TN = NCB / 16;
    __shared__ float As[64][65];
    __shared__ float Bs[64][NCB + 1];
    int tid = threadIdx.x;
    int bm = blockIdx.x * 64;
    int bn = blockIdx.y * NCB;
    {
        int c = tid & 63, r0 = tid >> 6;
        #pragma unroll
        for (int it = 0; it < 16; it++) {
            int r = r0 + it * 4;
            int gr = bm + r;
            As[r][c] = (gr < M) ? A[(size_t)gr * 64 + c] : 0.f;
        }
    }
    for (int i = tid; i < 64 * NCB; i += 256) {
        int r = i / NCB, cc = i % NCB;
        Bs[r][cc] = B[(size_t)r * NC + bn + cc];
    }
    __syncthreads();
    int ty = tid >> 4, tx = tid & 15;
    float acc[4][TN] = {};
    #pragma unroll 8
    for (int k = 0; k < 64; k++) {
        float a[4], b[TN];
        #pragma unroll
        for (int i = 0; i < 4; i++) a[i] = As[ty + 16*i][k];
        #pragma unroll
        for (int j = 0; j < TN; j++) b[j] = Bs[k][tx + 16*j];
        #pragma unroll
        for (int i = 0; i < 4; i++)
            #pragma unroll
            for (int j = 0; j < TN; j++) acc[i][j] += a[i] * b[j];
    }
    #pragma unroll
    for (int i = 0; i < 4; i++) {
        int gr = bm + ty + 16*i;
        if (gr < M) {
            #pragma unroll
            for (int j = 0; j < TN; j++) C[(size_t)gr * NC + bn + tx + 16*j] = acc[i][j];
        }
    }
}

// ---------------- attention dots: a_s[n,h] = <h[n,h,:], att_s[h,:]> ----------------

template<int HEADS>
__global__ void k_att_dots(const float* __restrict__ hpre, const float* __restrict__ att_s,
                           const float* __restrict__ att_d, float* __restrict__ as_n,
                           float* __restrict__ ad_n, int n_nodes) {
    int idx = blockIdx.x * 256 + threadIdx.x;
    if (idx >= n_nodes * HEADS) return;
    int h = idx & (HEADS - 1);
    const float* row = hpre + (size_t)idx * 64;
    float s = 0.f, d = 0.f;
    #pragma unroll
    for (int k = 0; k < 64; k++) {
        float v = row[k];
        s += v * att_s[h * 64 + k];
        d += v * att_d[h * 64 + k];
    }
    as_n[idx] = s; ad_n[idx] = d;
}

// ---------------- GAT aggregate: one wave per dst node, lane = feature dim ----------------

template<int HEADS>
__global__ __launch_bounds__(256) void k_gat_agg(const float* __restrict__ hpre,
        const float* __restrict__ as_n, const float* __restrict__ ad_n,
        const float* __restrict__ bias,
        const int* __restrict__ offs, const int* __restrict__ csr,
        float* __restrict__ out, int n_nodes) {
    int wid = (blockIdx.x * blockDim.x + threadIdx.x) >> 6;
    int lane = threadIdx.x & 63;
    if (wid >= n_nodes) return;
    const int n = wid;
    const int beg = offs[n], end = offs[n + 1];

    float adh[HEADS], eself[HEADS], m[HEADS];
    #pragma unroll
    for (int h = 0; h < HEADS; h++) {
        adh[h] = ad_n[n * HEADS + h];
        float e = as_n[n * HEADS + h] + adh[h];
        e = e > 0.f ? e : 0.2f * e;
        eself[h] = e; m[h] = e;
    }
    // pass A: max
    for (int j = beg; j < end; j++) {
        int s = csr[j];
        #pragma unroll
        for (int h = 0; h < HEADS; h++) {
            float e = as_n[s * HEADS + h] + adh[h];
            e = e > 0.f ? e : 0.2f * e;
            m[h] = fmaxf(m[h], e);
        }
    }
    // pass B: sum of exp
    float sum[HEADS];
    #pragma unroll
    for (int h = 0; h < HEADS; h++) sum[h] = expf(eself[h] - m[h]);
    for (int j = beg; j < end; j++) {
        int s = csr[j];
        #pragma unroll
        for (int h = 0; h < HEADS; h++) {
            float e = as_n[s * HEADS + h] + adh[h];
            e = e > 0.f ? e : 0.2f * e;
            sum[h] += expf(e - m[h]);
        }
    }
    float inv[HEADS];
    #pragma unroll
    for (int h = 0; h < HEADS; h++) inv[h] = 1.0f / (sum[h] + 1e-16f);
    // pass C: weighted gather, mean over heads folded in
    float acc = 0.f;
    #pragma unroll
    for (int h = 0; h < HEADS; h++)
        acc += expf(eself[h] - m[h]) * inv[h] * hpre[((size_t)n * HEADS + h) * 64 + lane];
    for (int j = beg; j < end; j++) {
        int s = csr[j];
        #pragma unroll
        for (int h = 0; h < HEADS; h++) {
            float e = as_n[s * HEADS + h] + adh[h];
            e = e > 0.f ? e : 0.2f * e;
            acc += expf(e - m[h]) * inv[h] * hpre[((size_t)s * HEADS + h) * 64 + lane];
        }
    }
    out[(size_t)n * 64 + lane] = fmaxf(acc * (1.0f / HEADS) + bias[lane], 0.f);
}

// ---------------- GCN aggregate ----------------

__global__ __launch_bounds__(256) void k_gcn_agg(const float* __restrict__ hpre,
        const float* __restrict__ dinv, const float* __restrict__ bias,
        const int* __restrict__ offs, const int* __restrict__ csr,
        float* __restrict__ out, int n_nodes) {
    int wid = (blockIdx.x * blockDim.x + threadIdx.x) >> 6;
    int lane = threadIdx.x & 63;
    if (wid >= n_nodes || lane >= 32) return;
    const int n = wid;
    const float dn = dinv[n];
    float acc = dn * dn * hpre[(size_t)n * 32 + lane];
    const int beg = offs[n], end = offs[n + 1];
    for (int j = beg; j < end; j++) {
        int s = csr[j];
        acc += dinv[s] * dn * hpre[(size_t)s * 32 + lane];
    }
    out[(size_t)n * 32 + lane] = fmaxf(acc + bias[lane], 0.f);
}

// ---------------- MLP head + sigmoid ----------------

__global__ __launch_bounds__(256) void k_mlp(const float* __restrict__ h3,
        const float* __restrict__ Wh1, const float* __restrict__ bh1,
        const float* __restrict__ Wh2, const float* __restrict__ bh2,
        float* __restrict__ out, int n_nodes) {
    __shared__ float w1[512];
    __shared__ float w2[16];
    __shared__ float b1s[16];
    __shared__ float b2s;
    int tid = threadIdx.x;
    for (int i = tid; i < 512; i += 256) w1[i] = Wh1[i];
    if (tid < 16) { w2[tid] = Wh2[tid]; b1s[tid] = bh1[tid]; }
    if (tid == 0) b2s = bh2[0];
    __syncthreads();
    int n = blockIdx.x * 256 + tid;
    if (n >= n_nodes) return;
    float x[32];
    const float4* p = (const float4*)(h3 + (size_t)n * 32);
    #pragma unroll
    for (int q = 0; q < 8; q++) { float4 v = p[q]; x[4*q] = v.x; x[4*q+1] = v.y; x[4*q+2] = v.z; x[4*q+3] = v.w; }
    float acc2 = b2s;
    #pragma unroll
    for (int j = 0; j < 16; j++) {
        float z = b1s[j];
        #pragma unroll
        for (int k = 0; k < 32; k++) z += x[k] * w1[k * 16 + j];
        z = fmaxf(z, 0.f);
        acc2 += z * w2[j];
    }
    out[n] = 1.0f / (1.0f + expf(-acc2));
}

// ---------------- launch ----------------

extern "C" void kernel_launch(void* const* d_in, const int* in_sizes, int n_in,
                              void* d_out, int out_size, void* d_ws, size_t ws_size,
                              hipStream_t stream) {
    const float* x   = (const float*)d_in[0];
    const int*   ei  = (const int*)d_in[1];
    const float* W1  = (const float*)d_in[2];
    const float* a1s = (const float*)d_in[3];
    const float* a1d = (const float*)d_in[4];
    const float* b1  = (const float*)d_in[5];
    const float* W2  = (const float*)d_in[6];
    const float* a2s = (const float*)d_in[7];
    const float* a2d = (const float*)d_in[8];
    const float* b2  = (const float*)d_in[9];
    const float* Wg  = (const float*)d_in[10];
    const float* bg  = (const float*)d_in[11];
    const float* Wh1 = (const float*)d_in[12];
    const float* bh1 = (const float*)d_in[13];
    const float* Wh2 = (const float*)d_in[14];
    const float* bh2 = (const float*)d_in[15];

    const int N = in_sizes[0] / 256;
    const int E = in_sizes[1] / 2;
    const int* srcs = ei;
    const int* dsts = ei + E;

    // workspace layout (fp32 unless noted)
    float* R0   = (float*)d_ws;              // N*256  : h1pre / h2pre / h3pre
    float* R1   = R0 + (size_t)N * 256;      // N*64   : h1 / h3
    float* R2   = R1 + (size_t)N * 64;       // N*64   : h2
    float* As_  = R2 + (size_t)N * 64;       // N*4    : a_s per node
    float* Ad_  = As_ + (size_t)N * 4;       // N*4    : a_d per node
    float* dinv = Ad_ + (size_t)N * 4;       // N
    int* deg    = (int*)(dinv + N);          // N
    int* offs   = deg + N;                   // N+1
    int* cursor = offs + (N + 1);            // N
    int* csr    = cursor + N;                // E
    int* parts  = csr + E;                   // <=256

    // ---- CSR build ----
    hipMemsetAsync(deg, 0, (size_t)N * sizeof(int), stream);
    k_count_deg<<<cdiv(E, 256), 256, 0, stream>>>(dsts, E, deg);
    int nch = cdiv(N, 1024);
    k_scan_partial<<<nch, 256, 0, stream>>>(deg, N, parts);
    k_scan_top<<<1, 64, 0, stream>>>(parts, nch, offs, N);
    k_scan_final<<<nch, 256, 0, stream>>>(deg, N, parts, offs);
    k_copy_int<<<cdiv(N, 256), 256, 0, stream>>>(offs, cursor, N);
    k_fill_csr<<<cdiv(E, 256), 256, 0, stream>>>(srcs, dsts, E, cursor, csr);
    k_dinv<<<cdiv(N, 256), 256, 0, stream>>>(deg, dinv, N);

    // ---- GAT layer 1 (heads=4) ----
    dim3 g1(cdiv(N, 64), 4);
    k_gemm_x256<<<g1, 256, 0, stream>>>(x, W1, R0, N);
    k_att_dots<4><<<cdiv(N * 4, 256), 256, 0, stream>>>(R0, a1s, a1d, As_, Ad_, N);
    k_gat_agg<4><<<cdiv(N, 4), 256, 0, stream>>>(R0, As_, Ad_, b1, offs, csr, R1, N);

    // ---- GAT layer 2 (heads=2) ----
    dim3 g2(cdiv(N, 64), 2);
    k_gemm_k64<64, 128><<<g2, 256, 0, stream>>>(R1, W2, R0, N);
    k_att_dots<2><<<cdiv(N * 2, 256), 256, 0, stream>>>(R0, a2s, a2d, As_, Ad_, N);
    k_gat_agg<2><<<cdiv(N, 4), 256, 0, stream>>>(R0, As_, Ad_, b2, offs, csr, R2, N);

    // ---- GCN ----
    dim3 g3(cdiv(N, 64), 1);
    k_gemm_k64<32, 32><<<g3, 256, 0, stream>>>(R2, Wg, R0, N);
    k_gcn_agg<<<cdiv(N, 4), 256, 0, stream>>>(R0, dinv, bg, offs, csr, R1, N);

    // ---- MLP head ----
    k_mlp<<<cdiv(N, 256), 256, 0, stream>>>(R1, Wh1, bh1, Wh2, bh2, (float*)d_out, N);
}

// Round 3
// 1095.740 us; speedup vs baseline: 2.3914x; 1.6194x over previous
//
#include <hip/hip_runtime.h>
#include <math.h>

static inline int cdiv(int a, int b){ return (a + b - 1) / b; }

// ---------------- graph build (CSR by dst, self-loops folded in) ----------------
// Slot layout per node n: [offs[n], offs[n]+deg_n) = real edges, offs[n+1]-1 = self loop.

__global__ void k_count_deg(const int* __restrict__ dst, int E, int* __restrict__ deg) {
    int e = blockIdx.x * 256 + threadIdx.x;
    if (e < E) atomicAdd(&deg[dst[e]], 1);
}

__global__ void k_scan_partial(const int* __restrict__ deg, int n, int* __restrict__ partial) {
    __shared__ int sd[256];
    int base = blockIdx.x * 1024;
    int sum = 0;
    for (int i = threadIdx.x; i < 1024; i += 256) {
        int idx = base + i;
        if (idx < n) sum += deg[idx] + 1;          // +1: self loop
    }
    sd[threadIdx.x] = sum;
    __syncthreads();
    for (int s = 128; s > 0; s >>= 1) {
        if (threadIdx.x < s) sd[threadIdx.x] += sd[threadIdx.x + s];
        __syncthreads();
    }
    if (threadIdx.x == 0) partial[blockIdx.x] = sd[0];
}

__global__ void k_scan_top(int* __restrict__ partial, int nb, int* __restrict__ offs, int n) {
    if (blockIdx.x == 0 && threadIdx.x == 0) {
        int run = 0;
        for (int i = 0; i < nb; i++) { int v = partial[i]; partial[i] = run; run += v; }
        offs[n] = run;   // == E + N
    }
}

__global__ void k_scan_final(const int* __restrict__ deg, int n,
                             const int* __restrict__ partial, int* __restrict__ offs) {
    __shared__ int sd[256];
    int tid = threadIdx.x;
    int base = blockIdx.x * 1024;
    int v[4]; int s0 = 0;
    #pragma unroll
    for (int j = 0; j < 4; j++) {
        int idx = base + tid*4 + j;
        v[j] = (idx < n) ? (deg[idx] + 1) : 0;     // +1: self loop
        s0 += v[j];
    }
    sd[tid] = s0;
    __syncthreads();
    for (int st = 1; st < 256; st <<= 1) {
        int t = (tid >= st) ? sd[tid - st] : 0;
        __syncthreads();
        sd[tid] += t;
        __syncthreads();
    }
    int ex = (tid > 0 ? sd[tid - 1] : 0) + partial[blockIdx.x];
    #pragma unroll
    for (int j = 0; j < 4; j++) {
        int idx = base + tid*4 + j;
        if (idx < n) offs[idx] = ex;
        ex += v[j];
    }
}

__global__ void k_copy_int(const int* __restrict__ a, int* __restrict__ b, int n) {
    int i = blockIdx.x * 256 + threadIdx.x;
    if (i < n) b[i] = a[i];
}

__global__ void k_fill_csr(const int* __restrict__ src, const int* __restrict__ dst, int E,
                           int* __restrict__ cursor, int* __restrict__ csr) {
    int e = blockIdx.x * 256 + threadIdx.x;
    if (e < E) { int d = dst[e]; int p = atomicAdd(&cursor[d], 1); csr[p] = src[e]; }
}

__global__ void k_self(const int* __restrict__ offs, int* __restrict__ csr, int n) {
    int i = blockIdx.x * 256 + threadIdx.x;
    if (i < n) csr[offs[i + 1] - 1] = i;           // self slot
}

__global__ void k_dinv(const int* __restrict__ offs, float* __restrict__ dinv, int n) {
    int i = blockIdx.x * 256 + threadIdx.x;
    if (i < n) dinv[i] = rsqrtf((float)(offs[i + 1] - offs[i]));  // deg incl. self
}

// ---------------- GEMMs (fp32) ----------------

// C[M,256] = A[M,256] @ B[256,256], 64x64 tile, BK=32, 4x4 per thread
__global__ __launch_bounds__(256) void k_gemm_x256(const float* __restrict__ A,
                                                   const float* __restrict__ B,
                                                   float* __restrict__ C, int M) {
    __shared__ float As[64][33];
    __shared__ float Bs[32][64];
    int tid = threadIdx.x;
    int bm = blockIdx.x * 64;
    int bn = blockIdx.y * 64;
    int ty = tid >> 4, tx = tid & 15;
    float acc[4][4] = {};
    for (int k0 = 0; k0 < 256; k0 += 32) {
        {
            int c = tid & 31, r0 = tid >> 5;
            #pragma unroll
            for (int it = 0; it < 8; it++) {
                int r = r0 + it * 8;
                int gr = bm + r;
                As[r][c] = (gr < M) ? A[(size_t)gr * 256 + k0 + c] : 0.f;
            }
        }
        {
            int c = tid & 63, r0 = tid >> 6;
            #pragma unroll
            for (int it = 0; it < 8; it++) {
                int r = r0 + it * 4;
                Bs[r][c] = B[(size_t)(k0 + r) * 256 + bn + c];
            }
        }
        __syncthreads();
        #pragma unroll
        for (int k = 0; k < 32; k++) {
            float a[4], b[4];
            #pragma unroll
            for (int i = 0; i < 4; i++) a[i] = As[ty + 16*i][k];
            #pragma unroll
            for (int j = 0; j < 4; j++) b[j] = Bs[k][tx + 16*j];
            #pragma unroll
            for (int i = 0; i < 4; i++)
                #pragma unroll
                for (int j = 0; j < 4; j++) acc[i][j] += a[i] * b[j];
        }
        __syncthreads();
    }
    #pragma unroll
    for (int i = 0; i < 4; i++) {
        int gr = bm + ty + 16*i;
        if (gr < M) {
            #pragma unroll
            for (int j = 0; j < 4; j++) C[(size_t)gr * 256 + bn + tx + 16*j] = acc[i][j];
        }
    }
}

// C[M,NC] = A[M,64] @ B[64,NC]; block = 64 x NCB tile, acc[4][NCB/16] per thread (no spill)
template<int NCB, int NC>
__global__ __launch_bounds__(256) void k_gemm_k64(const float* __restrict__ A,
                                                  const float* __restrict__ B,
                                                  float* __restrict__ C, int M) {
    constexpr int TN = NCB / 16;
    __shared__ float As[64][65];
    __shared__ float Bs[64][NCB + 1];
    int tid = threadIdx.x;
    int bm = blockIdx.x * 64;
    int bn = blockIdx.y * NCB;
    {
        int c = tid & 63, r0 = tid >> 6;
        #pragma unroll
        for (int it = 0; it < 16; it++) {
            int r = r0 + it * 4;
            int gr = bm + r;
            As[r][c] = (gr < M) ? A[(size_t)gr * 64 + c] : 0.f;
        }
    }
    for (int i = tid; i < 64 * NCB; i += 256) {
        int r = i / NCB, cc = i % NCB;
        Bs[r][cc] = B[(size_t)r * NC + bn + cc];
    }
    __syncthreads();
    int ty = tid >> 4, tx = tid & 15;
    float acc[4][TN] = {};
    #pragma unroll 8
    for (int k = 0; k < 64; k++) {
        float a[4], b[TN];
        #pragma unroll
        for (int i = 0; i < 4; i++) a[i] = As[ty + 16*i][k];
        #pragma unroll
        for (int j = 0; j < TN; j++) b[j] = Bs[k][tx + 16*j];
        #pragma unroll
        for (int i = 0; i < 4; i++)
            #pragma unroll
            for (int j = 0; j < TN; j++) acc[i][j] += a[i] * b[j];
    }
    #pragma unroll
    for (int i = 0; i < 4; i++) {
        int gr = bm + ty + 16*i;
        if (gr < M) {
            #pragma unroll
            for (int j = 0; j < TN; j++) C[(size_t)gr * NC + bn + tx + 16*j] = acc[i][j];
        }
    }
}

// ---------------- attention dots ----------------

template<int HEADS>
__global__ void k_att_dots(const float* __restrict__ hpre, const float* __restrict__ att_s,
                           const float* __restrict__ att_d, float* __restrict__ as_n,
                           float* __restrict__ ad_n, int n_nodes) {
    int idx = blockIdx.x * 256 + threadIdx.x;   // node*head row
    if (idx >= n_nodes * HEADS) return;
    int h = idx & (HEADS - 1);
    const float4* row = (const float4*)(hpre + (size_t)idx * 64);
    const float4* vs  = (const float4*)(att_s + h * 64);
    const float4* vd  = (const float4*)(att_d + h * 64);
    float s = 0.f, d = 0.f;
    #pragma unroll
    for (int k = 0; k < 16; k++) {
        float4 v = row[k], a = vs[k], b = vd[k];
        s += v.x*a.x + v.y*a.y + v.z*a.z + v.w*a.w;
        d += v.x*b.x + v.y*b.y + v.z*b.z + v.w*b.w;
    }
    as_n[idx] = s; ad_n[idx] = d;
}

// ---------------- fused GAT aggregate ----------------
// One wave per dst node. Single pass over CSR slots (self included):
//   lanes-over-edges compute p = exp(leaky(a_s[src]+a_d[n])) ONCE per edge
//   (softmax shift-invariance: |e| <~ 3 << 88, no max-subtraction needed),
//   stash (src, p[heads]) in LDS per 64-edge chunk, then lanes-over-features
//   accumulate unnormalized acc[h] += p * hpre[src,h,lane].
// Normalization 1/sum applied once at the end (butterfly reduce).

template<int HEADS>
__global__ __launch_bounds__(256) void k_gat_fused(const float* __restrict__ hpre,
        const float* __restrict__ as_n, const float* __restrict__ ad_n,
        const float* __restrict__ bias,
        const int* __restrict__ offs, const int* __restrict__ csr,
        float* __restrict__ out, int n_nodes) {
    __shared__ int   s_src[4][64];
    __shared__ float s_p[4][64 * HEADS];
    int wif  = threadIdx.x >> 6;
    int lane = threadIdx.x & 63;
    int n = blockIdx.x * 4 + wif;
    if (n >= n_nodes) return;
    const int beg = offs[n], end = offs[n + 1];
    const int deg = end - beg;                  // >= 1 (self)

    float adv[HEADS];
    if constexpr (HEADS == 4) {
        float4 t = *(const float4*)(ad_n + (size_t)n * 4);
        adv[0]=t.x; adv[1]=t.y; adv[2]=t.z; adv[3]=t.w;
    } else {
        float2 t = *(const float2*)(ad_n + (size_t)n * 2);
        adv[0]=t.x; adv[1]=t.y;
    }

    float sum[HEADS], acc[HEADS];
    #pragma unroll
    for (int h = 0; h < HEADS; h++) { sum[h] = 0.f; acc[h] = 0.f; }

    for (int j0 = 0; j0 < deg; j0 += 64) {
        int j = j0 + lane;
        int cnt = min(64, deg - j0);
        if (j < deg) {
            int s = csr[beg + j];
            float ev[HEADS];
            if constexpr (HEADS == 4) {
                float4 t = *(const float4*)(as_n + (size_t)s * 4);
                ev[0]=t.x; ev[1]=t.y; ev[2]=t.z; ev[3]=t.w;
            } else {
                float2 t = *(const float2*)(as_n + (size_t)s * 2);
                ev[0]=t.x; ev[1]=t.y;
            }
            s_src[wif][lane] = s;
            #pragma unroll
            for (int h = 0; h < HEADS; h++) {
                float e = ev[h] + adv[h];
                e = fmaxf(e, 0.2f * e);          // leaky_relu(e, 0.2)
                float p = __expf(e);
                sum[h] += p;
                s_p[wif][lane * HEADS + h] = p;
            }
        }
        #pragma unroll 4
        for (int q = 0; q < cnt; q++) {
            int s = s_src[wif][q];
            const float* hp = hpre + (size_t)s * (HEADS * 64) + lane;
            #pragma unroll
            for (int h = 0; h < HEADS; h++)
                acc[h] += s_p[wif][q * HEADS + h] * hp[h * 64];
        }
    }
    #pragma unroll
    for (int off = 32; off > 0; off >>= 1)
        #pragma unroll
        for (int h = 0; h < HEADS; h++)
            sum[h] += __shfl_xor(sum[h], off);
    float r = 0.f;
    #pragma unroll
    for (int h = 0; h < HEADS; h++) r += acc[h] / (sum[h] + 1e-16f);
    out[(size_t)n * 64 + lane] = fmaxf(r * (1.0f / HEADS) + bias[lane], 0.f);
}

// ---------------- GCN aggregate: 32 lanes per node, CSR includes self ----------------

__global__ __launch_bounds__(256) void k_gcn_agg(const float* __restrict__ hpre,
        const float* __restrict__ dinv, const float* __restrict__ bias,
        const int* __restrict__ offs, const int* __restrict__ csr,
        float* __restrict__ out, int n_nodes) {
    int gid = blockIdx.x * 256 + threadIdx.x;
    int n = gid >> 5;
    int l = gid & 31;
    if (n >= n_nodes) return;
    const int beg = offs[n], end = offs[n + 1];
    float acc = 0.f;
    for (int j = beg; j < end; j++) {
        int s = csr[j];
        acc += dinv[s] * hpre[(size_t)s * 32 + l];
    }
    out[(size_t)n * 32 + l] = fmaxf(acc * dinv[n] + bias[l], 0.f);
}

// ---------------- MLP head + sigmoid ----------------

__global__ __launch_bounds__(256) void k_mlp(const float* __restrict__ h3,
        const float* __restrict__ Wh1, const float* __restrict__ bh1,
        const float* __restrict__ Wh2, const float* __restrict__ bh2,
        float* __restrict__ out, int n_nodes) {
    __shared__ float w1[512];
    __shared__ float w2[16];
    __shared__ float b1s[16];
    __shared__ float b2s;
    int tid = threadIdx.x;
    for (int i = tid; i < 512; i += 256) w1[i] = Wh1[i];
    if (tid < 16) { w2[tid] = Wh2[tid]; b1s[tid] = bh1[tid]; }
    if (tid == 0) b2s = bh2[0];
    __syncthreads();
    int n = blockIdx.x * 256 + tid;
    if (n >= n_nodes) return;
    float x[32];
    const float4* p = (const float4*)(h3 + (size_t)n * 32);
    #pragma unroll
    for (int q = 0; q < 8; q++) { float4 v = p[q]; x[4*q] = v.x; x[4*q+1] = v.y; x[4*q+2] = v.z; x[4*q+3] = v.w; }
    float acc2 = b2s;
    #pragma unroll
    for (int j = 0; j < 16; j++) {
        float z = b1s[j];
        #pragma unroll
        for (int k = 0; k < 32; k++) z += x[k] * w1[k * 16 + j];
        z = fmaxf(z, 0.f);
        acc2 += z * w2[j];
    }
    out[n] = 1.0f / (1.0f + expf(-acc2));
}

// ---------------- launch ----------------

extern "C" void kernel_launch(void* const* d_in, const int* in_sizes, int n_in,
                              void* d_out, int out_size, void* d_ws, size_t ws_size,
                              hipStream_t stream) {
    const float* x   = (const float*)d_in[0];
    const int*   ei  = (const int*)d_in[1];
    const float* W1  = (const float*)d_in[2];
    const float* a1s = (const float*)d_in[3];
    const float* a1d = (const float*)d_in[4];
    const float* b1  = (const float*)d_in[5];
    const float* W2  = (const float*)d_in[6];
    const float* a2s = (const float*)d_in[7];
    const float* a2d = (const float*)d_in[8];
    const float* b2  = (const float*)d_in[9];
    const float* Wg  = (const float*)d_in[10];
    const float* bg  = (const float*)d_in[11];
    const float* Wh1 = (const float*)d_in[12];
    const float* bh1 = (const float*)d_in[13];
    const float* Wh2 = (const float*)d_in[14];
    const float* bh2 = (const float*)d_in[15];

    const int N = in_sizes[0] / 256;
    const int E = in_sizes[1] / 2;
    const int* srcs = ei;
    const int* dsts = ei + E;

    // workspace layout (fp32 unless noted)
    float* R0   = (float*)d_ws;              // N*256  : h1pre / h2pre / h3pre
    float* R1   = R0 + (size_t)N * 256;      // N*64   : h1 / h3
    float* R2   = R1 + (size_t)N * 64;       // N*64   : h2
    float* As_  = R2 + (size_t)N * 64;       // N*4    : a_s per node
    float* Ad_  = As_ + (size_t)N * 4;       // N*4    : a_d per node
    float* dinv = Ad_ + (size_t)N * 4;       // N
    int* deg    = (int*)(dinv + N);          // N
    int* offs   = deg + N;                   // N+1
    int* cursor = offs + (N + 1);            // N
    int* csr    = cursor + N;                // E + N (self loops included)
    int* parts  = csr + (E + N);             // <=256

    // ---- CSR build (with self loops) ----
    hipMemsetAsync(deg, 0, (size_t)N * sizeof(int), stream);
    k_count_deg<<<cdiv(E, 256), 256, 0, stream>>>(dsts, E, deg);
    int nch = cdiv(N, 1024);
    k_scan_partial<<<nch, 256, 0, stream>>>(deg, N, parts);
    k_scan_top<<<1, 64, 0, stream>>>(parts, nch, offs, N);
    k_scan_final<<<nch, 256, 0, stream>>>(deg, N, parts, offs);
    k_copy_int<<<cdiv(N, 256), 256, 0, stream>>>(offs, cursor, N);
    k_fill_csr<<<cdiv(E, 256), 256, 0, stream>>>(srcs, dsts, E, cursor, csr);
    k_self<<<cdiv(N, 256), 256, 0, stream>>>(offs, csr, N);
    k_dinv<<<cdiv(N, 256), 256, 0, stream>>>(offs, dinv, N);

    // ---- GAT layer 1 (heads=4) ----
    dim3 g1(cdiv(N, 64), 4);
    k_gemm_x256<<<g1, 256, 0, stream>>>(x, W1, R0, N);
    k_att_dots<4><<<cdiv(N * 4, 256), 256, 0, stream>>>(R0, a1s, a1d, As_, Ad_, N);
    k_gat_fused<4><<<cdiv(N, 4), 256, 0, stream>>>(R0, As_, Ad_, b1, offs, csr, R1, N);

    // ---- GAT layer 2 (heads=2) ----
    dim3 g2(cdiv(N, 64), 2);
    k_gemm_k64<64, 128><<<g2, 256, 0, stream>>>(R1, W2, R0, N);
    k_att_dots<2><<<cdiv(N * 2, 256), 256, 0, stream>>>(R0, a2s, a2d, As_, Ad_, N);
    k_gat_fused<2><<<cdiv(N, 4), 256, 0, stream>>>(R0, As_, Ad_, b2, offs, csr, R2, N);

    // ---- GCN ----
    dim3 g3(cdiv(N, 64), 1);
    k_gemm_k64<32, 32><<<g3, 256, 0, stream>>>(R2, Wg, R0, N);
    k_gcn_agg<<<cdiv(N * 32, 256), 256, 0, stream>>>(R0, dinv, bg, offs, csr, R1, N);

    // ---- MLP head ----
    k_mlp<<<cdiv(N, 256), 256, 0, stream>>>(R1, Wh1, bh1, Wh2, bh2, (float*)d_out, N);
}

// Round 4
// 825.383 us; speedup vs baseline: 3.1747x; 1.3276x over previous
//
#include <hip/hip_runtime.h>
#include <math.h>

static inline int cdiv(int a, int b){ return (a + b - 1) / b; }

typedef __attribute__((ext_vector_type(8))) short short8_t;   // 8 bf16 (4 VGPRs)
typedef __attribute__((ext_vector_type(4))) float f32x4;      // MFMA acc

static __device__ inline unsigned short f2bf(float f) {       // fp32 -> bf16 RTNE
    union { float f; unsigned u; } v; v.f = f;
    unsigned r = v.u + 0x7fff + ((v.u >> 16) & 1);
    return (unsigned short)(r >> 16);
}

// ---------------- graph build (CSR by dst, self-loops folded in) ----------------

__global__ void k_count_deg(const int* __restrict__ dst, int E, int* __restrict__ deg) {
    int e = blockIdx.x * 256 + threadIdx.x;
    if (e < E) atomicAdd(&deg[dst[e]], 1);
}

__global__ void k_scan_partial(const int* __restrict__ deg, int n, int* __restrict__ partial) {
    __shared__ int sd[256];
    int base = blockIdx.x * 1024;
    int sum = 0;
    for (int i = threadIdx.x; i < 1024; i += 256) {
        int idx = base + i;
        if (idx < n) sum += deg[idx] + 1;          // +1: self loop
    }
    sd[threadIdx.x] = sum;
    __syncthreads();
    for (int s = 128; s > 0; s >>= 1) {
        if (threadIdx.x < s) sd[threadIdx.x] += sd[threadIdx.x + s];
        __syncthreads();
    }
    if (threadIdx.x == 0) partial[blockIdx.x] = sd[0];
}

__global__ void k_scan_top(int* __restrict__ partial, int nb, int* __restrict__ offs, int n) {
    if (blockIdx.x == 0 && threadIdx.x == 0) {
        int run = 0;
        for (int i = 0; i < nb; i++) { int v = partial[i]; partial[i] = run; run += v; }
        offs[n] = run;   // == E + N
    }
}

__global__ void k_scan_final(const int* __restrict__ deg, int n,
                             const int* __restrict__ partial, int* __restrict__ offs) {
    __shared__ int sd[256];
    int tid = threadIdx.x;
    int base = blockIdx.x * 1024;
    int v[4]; int s0 = 0;
    #pragma unroll
    for (int j = 0; j < 4; j++) {
        int idx = base + tid*4 + j;
        v[j] = (idx < n) ? (deg[idx] + 1) : 0;
        s0 += v[j];
    }
    sd[tid] = s0;
    __syncthreads();
    for (int st = 1; st < 256; st <<= 1) {
        int t = (tid >= st) ? sd[tid - st] : 0;
        __syncthreads();
        sd[tid] += t;
        __syncthreads();
    }
    int ex = (tid > 0 ? sd[tid - 1] : 0) + partial[blockIdx.x];
    #pragma unroll
    for (int j = 0; j < 4; j++) {
        int idx = base + tid*4 + j;
        if (idx < n) offs[idx] = ex;
        ex += v[j];
    }
}

__global__ void k_copy_int(const int* __restrict__ a, int* __restrict__ b, int n) {
    int i = blockIdx.x * 256 + threadIdx.x;
    if (i < n) b[i] = a[i];
}

__global__ void k_fill_csr(const int* __restrict__ src, const int* __restrict__ dst, int E,
                           int* __restrict__ cursor, int* __restrict__ csr) {
    int e = blockIdx.x * 256 + threadIdx.x;
    if (e < E) { int d = dst[e]; int p = atomicAdd(&cursor[d], 1); csr[p] = src[e]; }
}

__global__ void k_self(const int* __restrict__ offs, int* __restrict__ csr, int n) {
    int i = blockIdx.x * 256 + threadIdx.x;
    if (i < n) csr[offs[i + 1] - 1] = i;
}

__global__ void k_dinv(const int* __restrict__ offs, float* __restrict__ dinv, int n) {
    int i = blockIdx.x * 256 + threadIdx.x;
    if (i < n) dinv[i] = rsqrtf((float)(offs[i + 1] - offs[i]));
}

// ---------------- GEMM1: C[M,256] = A_fp32[M,256] @ W1[256,256] via bf16 MFMA ----------------

// W1 [k][c] fp32 -> Bt [c][k] bf16 (transposed so B-fragments are k-contiguous)
__global__ void k_prep_w1(const float* __restrict__ W, unsigned short* __restrict__ Bt) {
    int t = blockIdx.x * 256 + threadIdx.x;    // 65536 elements
    int k = t >> 8, c = t & 255;
    Bt[c * 256 + k] = f2bf(W[t]);
}

// BM=128, BN=256 (full width, one pass over A), BK=32, 512 thr / 8 waves.
// Wave tile 32x128: 2 row-frags x 8 col-frags of 16x16, acc 16 x f32x4.
__global__ __launch_bounds__(512) void k_gemm1_mfma(const float* __restrict__ A,
        const unsigned short* __restrict__ Bt, float* __restrict__ C, int M) {
    constexpr int LDP = 40;                    // 32 bf16 + 8 pad = 80 B row (2-way banks: free)
    __shared__ __align__(16) unsigned short As[128 * LDP];
    __shared__ __align__(16) unsigned short Bs[256 * LDP];
    int tid = threadIdx.x;
    int bm = blockIdx.x * 128;
    int wave = tid >> 6, lane = tid & 63;
    int wr = wave >> 1, wc = wave & 1;         // wave rows wr*32, cols wc*128
    int lg = lane >> 4, lr = lane & 15;        // k-group, row/col-in-frag

    f32x4 acc[2][8] = {};

    for (int k0 = 0; k0 < 256; k0 += 32) {
        __syncthreads();                       // protect LDS from prior-iter readers
        {   // stage A: 128 rows x 32 k fp32 -> bf16 (8 floats/thread)
            int row = tid >> 2, part = tid & 3;
            int gr = bm + row;
            float4 v0, v1;
            if (gr < M) {
                const float4* p = (const float4*)(A + (size_t)gr * 256 + k0 + part * 8);
                v0 = p[0]; v1 = p[1];
            } else {
                v0 = make_float4(0.f,0.f,0.f,0.f); v1 = v0;
            }
            unsigned short* w = &As[row * LDP + part * 8];
            w[0]=f2bf(v0.x); w[1]=f2bf(v0.y); w[2]=f2bf(v0.z); w[3]=f2bf(v0.w);
            w[4]=f2bf(v1.x); w[5]=f2bf(v1.y); w[6]=f2bf(v1.z); w[7]=f2bf(v1.w);
        }
        {   // stage B: 256 cols x 32 k bf16 copy (32 B/thread)
            int col = tid >> 1, part = tid & 1;
            const uint4* p = (const uint4*)(Bt + (size_t)col * 256 + k0 + part * 16);
            uint4 u0 = p[0], u1 = p[1];
            *(uint4*)&Bs[col * LDP + part * 16]     = u0;
            *(uint4*)&Bs[col * LDP + part * 16 + 8] = u1;
        }
        __syncthreads();
        short8_t a[2], b[8];
        #pragma unroll
        for (int i = 0; i < 2; i++)
            a[i] = *(const short8_t*)&As[(wr * 32 + i * 16 + lr) * LDP + lg * 8];
        #pragma unroll
        for (int j = 0; j < 8; j++)
            b[j] = *(const short8_t*)&Bs[(wc * 128 + j * 16 + lr) * LDP + lg * 8];
        #pragma unroll
        for (int i = 0; i < 2; i++)
            #pragma unroll
            for (int j = 0; j < 8; j++)
                acc[i][j] = __builtin_amdgcn_mfma_f32_16x16x32_bf16(a[i], b[j], acc[i][j], 0, 0, 0);
    }
    // epilogue: D col=lane&15, row=4*(lane>>4)+reg  [m89-verified layout]
    #pragma unroll
    for (int i = 0; i < 2; i++) {
        #pragma unroll
        for (int j = 0; j < 8; j++) {
            int col = wc * 128 + j * 16 + lr;
            #pragma unroll
            for (int b2 = 0; b2 < 4; b2++) {
                int row = bm + wr * 32 + i * 16 + lg * 4 + b2;
                if (row < M) C[(size_t)row * 256 + col] = acc[i][j][b2];
            }
        }
    }
}

// ---------------- small fp32 GEMM: C[M,NC] = A[M,64] @ B[64,NC] ----------------

template<int NCB, int NC>
__global__ __launch_bounds__(256) void k_gemm_k64(const float* __restrict__ A,
                                                  const float* __restrict__ B,
                                                  float* __restrict__ C, int M) {
    constexpr int TN = NCB / 16;
    __shared__ float As[64][65];
    __shared__ float Bs[64][NCB + 1];
    int tid = threadIdx.x;
    int bm = blockIdx.x * 64;
    int bn = blockIdx.y * NCB;
    {
        int c = tid & 63, r0 = tid >> 6;
        #pragma unroll
        for (int it = 0; it < 16; it++) {
            int r = r0 + it * 4;
            int gr = bm + r;
            As[r][c] = (gr < M) ? A[(size_t)gr * 64 + c] : 0.f;
        }
    }
    for (int i = tid; i < 64 * NCB; i += 256) {
        int r = i / NCB, cc = i % NCB;
        Bs[r][cc] = B[(size_t)r * NC + bn + cc];
    }
    __syncthreads();
    int ty = tid >> 4, tx = tid & 15;
    float acc[4][TN] = {};
    #pragma unroll 8
    for (int k = 0; k < 64; k++) {
        float a[4], b[TN];
        #pragma unroll
        for (int i = 0; i < 4; i++) a[i] = As[ty + 16*i][k];
        #pragma unroll
        for (int j = 0; j < TN; j++) b[j] = Bs[k][tx + 16*j];
        #pragma unroll
        for (int i = 0; i < 4; i++)
            #pragma unroll
            for (int j = 0; j < TN; j++) acc[i][j] += a[i] * b[j];
    }
    #pragma unroll
    for (int i = 0; i < 4; i++) {
        int gr = bm + ty + 16*i;
        if (gr < M) {
            #pragma unroll
            for (int j = 0; j < TN; j++) C[(size_t)gr * NC + bn + tx + 16*j] = acc[i][j];
        }
    }
}

// ---------------- attention dots ----------------

template<int HEADS>
__global__ void k_att_dots(const float* __restrict__ hpre, const float* __restrict__ att_s,
                           const float* __restrict__ att_d, float* __restrict__ as_n,
                           float* __restrict__ ad_n, int n_nodes) {
    int idx = blockIdx.x * 256 + threadIdx.x;
    if (idx >= n_nodes * HEADS) return;
    int h = idx & (HEADS - 1);
    const float4* row = (const float4*)(hpre + (size_t)idx * 64);
    const float4* vs  = (const float4*)(att_s + h * 64);
    const float4* vd  = (const float4*)(att_d + h * 64);
    float s = 0.f, d = 0.f;
    #pragma unroll
    for (int k = 0; k < 16; k++) {
        float4 v = row[k], a = vs[k], b = vd[k];
        s += v.x*a.x + v.y*a.y + v.z*a.z + v.w*a.w;
        d += v.x*b.x + v.y*b.y + v.z*b.z + v.w*b.w;
    }
    as_n[idx] = s; ad_n[idx] = d;
}

// ---------------- fused GAT aggregate ----------------
// One wave per node. Phase 1 (lanes over edges): p = exp(leaky(a_s[src]+a_d[n]))
// computed ONCE per edge-head, stashed in LDS. Phase 2 (lanes over (head, dim)):
// lane = h_id * (64/HEADS) + dq, loads vecN of h[src, h_id, dq*N..] per edge ->
// whole wave touches the node row contiguously; per-lane sumh accumulates its
// head's denominator for free. Softmax shift-invariance: |e| small, no max needed.

template<int HEADS>
__global__ __launch_bounds__(256) void k_gat_fused(const float* __restrict__ hpre,
        const float* __restrict__ as_n, const float* __restrict__ ad_n,
        const float* __restrict__ bias,
        const int* __restrict__ offs, const int* __restrict__ csr,
        float* __restrict__ out, int n_nodes) {
    __shared__ int   s_src[4][64];
    __shared__ float s_p[4][64 * HEADS];
    int wif  = threadIdx.x >> 6;
    int lane = threadIdx.x & 63;
    int n = blockIdx.x * 4 + wif;
    if (n >= n_nodes) return;
    const int beg = offs[n];
    const int deg = offs[n + 1] - beg;          // >= 1 (self)

    int h_id, dq;
    if constexpr (HEADS == 4) { h_id = lane >> 4; dq = lane & 15; }
    else                      { h_id = lane >> 5; dq = lane & 31; }

    float adv[HEADS];
    if constexpr (HEADS == 4) {
        float4 t = *(const float4*)(ad_n + (size_t)n * 4);
        adv[0]=t.x; adv[1]=t.y; adv[2]=t.z; adv[3]=t.w;
    } else {
        float2 t = *(const float2*)(ad_n + (size_t)n * 2);
        adv[0]=t.x; adv[1]=t.y;
    }

    float sumh = 0.f;
    float acc[HEADS] = {};                      // HEADS == floats-per-lane of the row

    for (int j0 = 0; j0 < deg; j0 += 64) {
        int j = j0 + lane;
        int cnt = min(64, deg - j0);
        if (j < deg) {
            int s = csr[beg + j];
            s_src[wif][lane] = s;
            float ev[HEADS];
            if constexpr (HEADS == 4) {
                float4 t = *(const float4*)(as_n + (size_t)s * 4);
                ev[0]=t.x; ev[1]=t.y; ev[2]=t.z; ev[3]=t.w;
            } else {
                float2 t = *(const float2*)(as_n + (size_t)s * 2);
                ev[0]=t.x; ev[1]=t.y;
            }
            #pragma unroll
            for (int h = 0; h < HEADS; h++) {
                float e = ev[h] + adv[h];
                e = fmaxf(e, 0.2f * e);          // leaky_relu
                s_p[wif][lane * HEADS + h] = __expf(e);
            }
        }
        for (int q = 0; q < cnt; q++) {
            int s = s_src[wif][q];
            float p = s_p[wif][q * HEADS + h_id];
            sumh += p;
            if constexpr (HEADS == 4) {
                float4 v = *(const float4*)(hpre + (size_t)s * 256 + h_id * 64 + dq * 4);
                acc[0] += p * v.x; acc[1] += p * v.y; acc[2] += p * v.z; acc[3] += p * v.w;
            } else {
                float2 v = *(const float2*)(hpre + (size_t)s * 128 + h_id * 64 + dq * 2);
                acc[0] += p * v.x; acc[1] += p * v.y;
            }
        }
    }
    float inv = 1.0f / (sumh + 1e-16f);
    float r[HEADS];
    #pragma unroll
    for (int c = 0; c < HEADS; c++) r[c] = acc[c] * inv;
    // combine over head groups (lane bit 4/5 = h_id bits), then mean + bias + relu
    if constexpr (HEADS == 4) {
        #pragma unroll
        for (int c = 0; c < 4; c++) {
            r[c] += __shfl_xor(r[c], 16);
            r[c] += __shfl_xor(r[c], 32);
            r[c] *= 0.25f;
        }
        if (h_id == 0) {
            float4 b = *(const float4*)(bias + dq * 4);
            float4 o;
            o.x = fmaxf(r[0] + b.x, 0.f); o.y = fmaxf(r[1] + b.y, 0.f);
            o.z = fmaxf(r[2] + b.z, 0.f); o.w = fmaxf(r[3] + b.w, 0.f);
            *(float4*)(out + (size_t)n * 64 + dq * 4) = o;
        }
    } else {
        #pragma unroll
        for (int c = 0; c < 2; c++) {
            r[c] += __shfl_xor(r[c], 32);
            r[c] *= 0.5f;
        }
        if (h_id == 0) {
            float2 b = *(const float2*)(bias + dq * 2);
            float2 o;
            o.x = fmaxf(r[0] + b.x, 0.f); o.y = fmaxf(r[1] + b.y, 0.f);
            *(float2*)(out + (size_t)n * 64 + dq * 2) = o;
        }
    }
}

// ---------------- GCN aggregate: 8 lanes per node, float4 ----------------

__global__ __launch_bounds__(256) void k_gcn_agg(const float* __restrict__ hpre,
        const float* __restrict__ dinv, const float* __restrict__ bias,
        const int* __restrict__ offs, const int* __restrict__ csr,
        float* __restrict__ out, int n_nodes) {
    int gid = blockIdx.x * 256 + threadIdx.x;
    int n = gid >> 3, q = gid & 7;
    if (n >= n_nodes) return;
    const int beg = offs[n], end = offs[n + 1];
    float4 acc = make_float4(0.f,0.f,0.f,0.f);
    for (int j = beg; j < end; j++) {
        int s = csr[j];
        float ds = dinv[s];
        float4 v = *(const float4*)(hpre + (size_t)s * 32 + q * 4);
        acc.x += ds * v.x; acc.y += ds * v.y; acc.z += ds * v.z; acc.w += ds * v.w;
    }
    float dn = dinv[n];
    float4 b = *(const float4*)(bias + q * 4);
    float4 o;
    o.x = fmaxf(acc.x * dn + b.x, 0.f); o.y = fmaxf(acc.y * dn + b.y, 0.f);
    o.z = fmaxf(acc.z * dn + b.z, 0.f); o.w = fmaxf(acc.w * dn + b.w, 0.f);
    *(float4*)(out + (size_t)n * 32 + q * 4) = o;
}

// ---------------- MLP head + sigmoid ----------------

__global__ __launch_bounds__(256) void k_mlp(const float* __restrict__ h3,
        const float* __restrict__ Wh1, const float* __restrict__ bh1,
        const float* __restrict__ Wh2, const float* __restrict__ bh2,
        float* __restrict__ out, int n_nodes) {
    __shared__ float w1[512];
    __shared__ float w2[16];
    __shared__ float b1s[16];
    __shared__ float b2s;
    int tid = threadIdx.x;
    for (int i = tid; i < 512; i += 256) w1[i] = Wh1[i];
    if (tid < 16) { w2[tid] = Wh2[tid]; b1s[tid] = bh1[tid]; }
    if (tid == 0) b2s = bh2[0];
    __syncthreads();
    int n = blockIdx.x * 256 + tid;
    if (n >= n_nodes) return;
    float x[32];
    const float4* p = (const float4*)(h3 + (size_t)n * 32);
    #pragma unroll
    for (int q = 0; q < 8; q++) { float4 v = p[q]; x[4*q] = v.x; x[4*q+1] = v.y; x[4*q+2] = v.z; x[4*q+3] = v.w; }
    float acc2 = b2s;
    #pragma unroll
    for (int j = 0; j < 16; j++) {
        float z = b1s[j];
        #pragma unroll
        for (int k = 0; k < 32; k++) z += x[k] * w1[k * 16 + j];
        z = fmaxf(z, 0.f);
        acc2 += z * w2[j];
    }
    out[n] = 1.0f / (1.0f + expf(-acc2));
}

// ---------------- launch ----------------

extern "C" void kernel_launch(void* const* d_in, const int* in_sizes, int n_in,
                              void* d_out, int out_size, void* d_ws, size_t ws_size,
                              hipStream_t stream) {
    const float* x   = (const float*)d_in[0];
    const int*   ei  = (const int*)d_in[1];
    const float* W1  = (const float*)d_in[2];
    const float* a1s = (const float*)d_in[3];
    const float* a1d = (const float*)d_in[4];
    const float* b1  = (const float*)d_in[5];
    const float* W2  = (const float*)d_in[6];
    const float* a2s = (const float*)d_in[7];
    const float* a2d = (const float*)d_in[8];
    const float* b2  = (const float*)d_in[9];
    const float* Wg  = (const float*)d_in[10];
    const float* bg  = (const float*)d_in[11];
    const float* Wh1 = (const float*)d_in[12];
    const float* bh1 = (const float*)d_in[13];
    const float* Wh2 = (const float*)d_in[14];
    const float* bh2 = (const float*)d_in[15];

    const int N = in_sizes[0] / 256;
    const int E = in_sizes[1] / 2;
    const int* srcs = ei;
    const int* dsts = ei + E;

    // workspace layout
    float* R0   = (float*)d_ws;              // N*256 : h1pre / h2pre / h3pre
    float* R1   = R0 + (size_t)N * 256;      // N*64  : h1 / h3
    float* R2   = R1 + (size_t)N * 64;       // N*64  : h2
    float* As_  = R2 + (size_t)N * 64;       // N*4
    float* Ad_  = As_ + (size_t)N * 4;       // N*4
    float* dinv = Ad_ + (size_t)N * 4;       // N
    int* deg    = (int*)(dinv + N);          // N
    int* offs   = deg + N;                   // N+1
    int* cursor = offs + (N + 1);            // N
    int* csr    = cursor + N;                // E + N
    int* parts  = csr + (E + N);             // <=256
    unsigned short* W1t = (unsigned short*)(parts + 256);   // 256*256 bf16

    // ---- CSR build (with self loops) ----
    hipMemsetAsync(deg, 0, (size_t)N * sizeof(int), stream);
    k_count_deg<<<cdiv(E, 256), 256, 0, stream>>>(dsts, E, deg);
    int nch = cdiv(N, 1024);
    k_scan_partial<<<nch, 256, 0, stream>>>(deg, N, parts);
    k_scan_top<<<1, 64, 0, stream>>>(parts, nch, offs, N);
    k_scan_final<<<nch, 256, 0, stream>>>(deg, N, parts, offs);
    k_copy_int<<<cdiv(N, 256), 256, 0, stream>>>(offs, cursor, N);
    k_fill_csr<<<cdiv(E, 256), 256, 0, stream>>>(srcs, dsts, E, cursor, csr);
    k_self<<<cdiv(N, 256), 256, 0, stream>>>(offs, csr, N);
    k_dinv<<<cdiv(N, 256), 256, 0, stream>>>(offs, dinv, N);

    // ---- GAT layer 1 (heads=4): bf16 MFMA GEMM ----
    k_prep_w1<<<256, 256, 0, stream>>>(W1, W1t);
    k_gemm1_mfma<<<cdiv(N, 128), 512, 0, stream>>>(x, W1t, R0, N);
    k_att_dots<4><<<cdiv(N * 4, 256), 256, 0, stream>>>(R0, a1s, a1d, As_, Ad_, N);
    k_gat_fused<4><<<cdiv(N, 4), 256, 0, stream>>>(R0, As_, Ad_, b1, offs, csr, R1, N);

    // ---- GAT layer 2 (heads=2) ----
    dim3 g2(cdiv(N, 64), 2);
    k_gemm_k64<64, 128><<<g2, 256, 0, stream>>>(R1, W2, R0, N);
    k_att_dots<2><<<cdiv(N * 2, 256), 256, 0, stream>>>(R0, a2s, a2d, As_, Ad_, N);
    k_gat_fused<2><<<cdiv(N, 4), 256, 0, stream>>>(R0, As_, Ad_, b2, offs, csr, R2, N);

    // ---- GCN ----
    dim3 g3(cdiv(N, 64), 1);
    k_gemm_k64<32, 32><<<g3, 256, 0, stream>>>(R2, Wg, R0, N);
    k_gcn_agg<<<cdiv(N * 8, 256), 256, 0, stream>>>(R0, dinv, bg, offs, csr, R1, N);

    // ---- MLP head ----
    k_mlp<<<cdiv(N, 256), 256, 0, stream>>>(R1, Wh1, bh1, Wh2, bh2, (float*)d_out, N);
}

// Round 5
// 614.735 us; speedup vs baseline: 4.2625x; 1.3427x over previous
//
#include <hip/hip_runtime.h>
#include <math.h>

static inline int cdiv(int a, int b){ return (a + b - 1) / b; }

typedef __attribute__((ext_vector_type(8))) short short8_t;   // 8 bf16 (4 VGPRs)
typedef __attribute__((ext_vector_type(4))) float f32x4;      // MFMA acc

static __device__ inline unsigned short f2bf(float f) {       // fp32 -> bf16 RTNE
    union { float f; unsigned u; } v; v.f = f;
    unsigned r = v.u + 0x7fff + ((v.u >> 16) & 1);
    return (unsigned short)(r >> 16);
}
static __device__ inline float bflo(unsigned u){ union{unsigned x;float f;}v; v.x = u << 16;        return v.f; }
static __device__ inline float bfhi(unsigned u){ union{unsigned x;float f;}v; v.x = u & 0xffff0000u; return v.f; }

// ---------------- graph build (CSR by dst, self-loops folded in) ----------------
// Slot layout per node n: [offs[n], offs[n]+deg_n) real edges, offs[n+1]-1 self.

__global__ void k_count_deg(const int* __restrict__ dst, int E, int* __restrict__ deg) {
    int e = blockIdx.x * 256 + threadIdx.x;
    if (e < E) atomicAdd(&deg[dst[e]], 1);
}

__global__ void k_scan_partial(const int* __restrict__ deg, int n, int* __restrict__ partial) {
    __shared__ int sd[256];
    int base = blockIdx.x * 1024;
    int sum = 0;
    for (int i = threadIdx.x; i < 1024; i += 256) {
        int idx = base + i;
        if (idx < n) sum += deg[idx] + 1;          // +1: self loop
    }
    sd[threadIdx.x] = sum;
    __syncthreads();
    for (int s = 128; s > 0; s >>= 1) {
        if (threadIdx.x < s) sd[threadIdx.x] += sd[threadIdx.x + s];
        __syncthreads();
    }
    if (threadIdx.x == 0) partial[blockIdx.x] = sd[0];
}

__global__ void k_scan_top(int* __restrict__ partial, int nb, int* __restrict__ offs, int n) {
    if (blockIdx.x == 0 && threadIdx.x == 0) {
        int run = 0;
        for (int i = 0; i < nb; i++) { int v = partial[i]; partial[i] = run; run += v; }
        offs[n] = run;   // == E + N
    }
}

// scan + fused: offs, cursor init, self-loop slot, dinv
__global__ void k_scan_final(const int* __restrict__ deg, int n,
                             const int* __restrict__ partial, int* __restrict__ offs,
                             int* __restrict__ cursor, int* __restrict__ csr,
                             float* __restrict__ dinv) {
    __shared__ int sd[256];
    int tid = threadIdx.x;
    int base = blockIdx.x * 1024;
    int v[4]; int s0 = 0;
    #pragma unroll
    for (int j = 0; j < 4; j++) {
        int idx = base + tid*4 + j;
        v[j] = (idx < n) ? (deg[idx] + 1) : 0;
        s0 += v[j];
    }
    sd[tid] = s0;
    __syncthreads();
    for (int st = 1; st < 256; st <<= 1) {
        int t = (tid >= st) ? sd[tid - st] : 0;
        __syncthreads();
        sd[tid] += t;
        __syncthreads();
    }
    int ex = (tid > 0 ? sd[tid - 1] : 0) + partial[blockIdx.x];
    #pragma unroll
    for (int j = 0; j < 4; j++) {
        int idx = base + tid*4 + j;
        if (idx < n) {
            offs[idx]   = ex;
            cursor[idx] = ex;
            dinv[idx]   = rsqrtf((float)v[j]);
            csr[ex + v[j] - 1] = idx;          // self slot (fill never touches it)
        }
        ex += v[j];
    }
}

__global__ void k_fill_csr(const int* __restrict__ src, const int* __restrict__ dst, int E,
                           int* __restrict__ cursor, int* __restrict__ csr) {
    int e = blockIdx.x * 256 + threadIdx.x;
    if (e < E) { int d = dst[e]; int p = atomicAdd(&cursor[d], 1); csr[p] = src[e]; }
}

// ---------------- GEMM1: C_bf16[M,256] = A_fp32[M,256] @ W1[256,256] via MFMA ----------------

__global__ void k_prep_w1(const float* __restrict__ W, unsigned short* __restrict__ Bt) {
    int t = blockIdx.x * 256 + threadIdx.x;    // 65536 elements
    int k = t >> 8, c = t & 255;
    Bt[c * 256 + k] = f2bf(W[t]);
}

__global__ __launch_bounds__(512) void k_gemm1_mfma(const float* __restrict__ A,
        const unsigned short* __restrict__ Bt, unsigned short* __restrict__ C, int M) {
    constexpr int LDP = 40;                    // 80 B row: 2-way bank alias only (free)
    __shared__ __align__(16) unsigned short As[128 * LDP];
    __shared__ __align__(16) unsigned short Bs[256 * LDP];
    int tid = threadIdx.x;
    int bm = blockIdx.x * 128;
    int wave = tid >> 6, lane = tid & 63;
    int wr = wave >> 1, wc = wave & 1;
    int lg = lane >> 4, lr = lane & 15;

    f32x4 acc[2][8] = {};

    for (int k0 = 0; k0 < 256; k0 += 32) {
        __syncthreads();
        {   // stage A: fp32 -> bf16
            int row = tid >> 2, part = tid & 3;
            int gr = bm + row;
            float4 v0, v1;
            if (gr < M) {
                const float4* p = (const float4*)(A + (size_t)gr * 256 + k0 + part * 8);
                v0 = p[0]; v1 = p[1];
            } else {
                v0 = make_float4(0.f,0.f,0.f,0.f); v1 = v0;
            }
            unsigned short* w = &As[row * LDP + part * 8];
            w[0]=f2bf(v0.x); w[1]=f2bf(v0.y); w[2]=f2bf(v0.z); w[3]=f2bf(v0.w);
            w[4]=f2bf(v1.x); w[5]=f2bf(v1.y); w[6]=f2bf(v1.z); w[7]=f2bf(v1.w);
        }
        {   // stage B
            int col = tid >> 1, part = tid & 1;
            const uint4* p = (const uint4*)(Bt + (size_t)col * 256 + k0 + part * 16);
            uint4 u0 = p[0], u1 = p[1];
            *(uint4*)&Bs[col * LDP + part * 16]     = u0;
            *(uint4*)&Bs[col * LDP + part * 16 + 8] = u1;
        }
        __syncthreads();
        short8_t a[2], b[8];
        #pragma unroll
        for (int i = 0; i < 2; i++)
            a[i] = *(const short8_t*)&As[(wr * 32 + i * 16 + lr) * LDP + lg * 8];
        #pragma unroll
        for (int j = 0; j < 8; j++)
            b[j] = *(const short8_t*)&Bs[(wc * 128 + j * 16 + lr) * LDP + lg * 8];
        #pragma unroll
        for (int i = 0; i < 2; i++)
            #pragma unroll
            for (int j = 0; j < 8; j++)
                acc[i][j] = __builtin_amdgcn_mfma_f32_16x16x32_bf16(a[i], b[j], acc[i][j], 0, 0, 0);
    }
    #pragma unroll
    for (int i = 0; i < 2; i++) {
        #pragma unroll
        for (int j = 0; j < 8; j++) {
            int col = wc * 128 + j * 16 + lr;
            #pragma unroll
            for (int b2 = 0; b2 < 4; b2++) {
                int row = bm + wr * 32 + i * 16 + lg * 4 + b2;
                if (row < M) C[(size_t)row * 256 + col] = f2bf(acc[i][j][b2]);
            }
        }
    }
}

// ---------------- small fp32 GEMM: C[M,NC] = A[M,64] @ B[64,NC]; optional bf16 out ----------------

template<int NCB, int NC, bool OB>
__global__ __launch_bounds__(256) void k_gemm_k64(const float* __restrict__ A,
                                                  const float* __restrict__ B,
                                                  void* __restrict__ Cv, int M) {
    constexpr int TN = NCB / 16;
    __shared__ float As[64][65];
    __shared__ float Bs[64][NCB + 1];
    int tid = threadIdx.x;
    int bm = blockIdx.x * 64;
    int bn = blockIdx.y * NCB;
    {
        int c = tid & 63, r0 = tid >> 6;
        #pragma unroll
        for (int it = 0; it < 16; it++) {
            int r = r0 + it * 4;
            int gr = bm + r;
            As[r][c] = (gr < M) ? A[(size_t)gr * 64 + c] : 0.f;
        }
    }
    for (int i = tid; i < 64 * NCB; i += 256) {
        int r = i / NCB, cc = i % NCB;
        Bs[r][cc] = B[(size_t)r * NC + bn + cc];
    }
    __syncthreads();
    int ty = tid >> 4, tx = tid & 15;
    float acc[4][TN] = {};
    #pragma unroll 8
    for (int k = 0; k < 64; k++) {
        float a[4], b[TN];
        #pragma unroll
        for (int i = 0; i < 4; i++) a[i] = As[ty + 16*i][k];
        #pragma unroll
        for (int j = 0; j < TN; j++) b[j] = Bs[k][tx + 16*j];
        #pragma unroll
        for (int i = 0; i < 4; i++)
            #pragma unroll
            for (int j = 0; j < TN; j++) acc[i][j] += a[i] * b[j];
    }
    #pragma unroll
    for (int i = 0; i < 4; i++) {
        int gr = bm + ty + 16*i;
        if (gr < M) {
            #pragma unroll
            for (int j = 0; j < TN; j++) {
                if constexpr (OB)
                    ((unsigned short*)Cv)[(size_t)gr * NC + bn + tx + 16*j] = f2bf(acc[i][j]);
                else
                    ((float*)Cv)[(size_t)gr * NC + bn + tx + 16*j] = acc[i][j];
            }
        }
    }
}

// ---------------- attention dots (bf16 input) ----------------

template<int HEADS>
__global__ void k_att_dots(const unsigned short* __restrict__ hpre,
                           const float* __restrict__ att_s, const float* __restrict__ att_d,
                           float* __restrict__ as_n, float* __restrict__ ad_n, int n_nodes) {
    int idx = blockIdx.x * 256 + threadIdx.x;   // node*head row
    if (idx >= n_nodes * HEADS) return;
    int h = idx & (HEADS - 1);
    const uint4* row = (const uint4*)(hpre + (size_t)idx * 64);
    const float* vs = att_s + h * 64;
    const float* vd = att_d + h * 64;
    float s = 0.f, d = 0.f;
    #pragma unroll
    for (int k = 0; k < 8; k++) {               // 8 bf16 per uint4
        uint4 u = row[k];
        float f0 = bflo(u.x), f1 = bfhi(u.x), f2 = bflo(u.y), f3 = bfhi(u.y);
        float f4 = bflo(u.z), f5 = bfhi(u.z), f6 = bflo(u.w), f7 = bfhi(u.w);
        const float* a = vs + k * 8; const float* b = vd + k * 8;
        s += f0*a[0]+f1*a[1]+f2*a[2]+f3*a[3]+f4*a[4]+f5*a[5]+f6*a[6]+f7*a[7];
        d += f0*b[0]+f1*b[1]+f2*b[2]+f3*b[3]+f4*b[4]+f5*b[5]+f6*b[6]+f7*b[7];
    }
    as_n[idx] = s; ad_n[idx] = d;
}

// ---------------- fused GAT aggregate (bf16 gather) ----------------
// One wave per node. Phase 1 (lanes over edges): p = exp(leaky(a_s[src]+a_d[n]))
// once per edge-head -> LDS. Phase 2 (lanes over (head,dim)): lane=h_id*(64/H)+dq
// gathers bf16 dims contiguously (512 B/edge for H=4, 256 B for H=2); per-lane
// sumh accumulates its head's denominator for free. No max-subtraction needed
// (|e| small; softmax shift-invariant).

template<int HEADS>
__global__ __launch_bounds__(256) void k_gat_fused(const unsigned short* __restrict__ hpre,
        const float* __restrict__ as_n, const float* __restrict__ ad_n,
        const float* __restrict__ bias,
        const int* __restrict__ offs, const int* __restrict__ csr,
        float* __restrict__ out, int n_nodes) {
    __shared__ int   s_src[4][64];
    __shared__ float s_p[4][64 * HEADS];
    int wif  = threadIdx.x >> 6;
    int lane = threadIdx.x & 63;
    int n = blockIdx.x * 4 + wif;
    if (n >= n_nodes) return;
    const int beg = offs[n];
    const int deg = offs[n + 1] - beg;

    int h_id, dq;
    if constexpr (HEADS == 4) { h_id = lane >> 4; dq = lane & 15; }
    else                      { h_id = lane >> 5; dq = lane & 31; }

    float adv[HEADS];
    if constexpr (HEADS == 4) {
        float4 t = *(const float4*)(ad_n + (size_t)n * 4);
        adv[0]=t.x; adv[1]=t.y; adv[2]=t.z; adv[3]=t.w;
    } else {
        float2 t = *(const float2*)(ad_n + (size_t)n * 2);
        adv[0]=t.x; adv[1]=t.y;
    }

    float sumh = 0.f;
    float acc[HEADS] = {};

    for (int j0 = 0; j0 < deg; j0 += 64) {
        int j = j0 + lane;
        int cnt = min(64, deg - j0);
        if (j < deg) {
            int s = csr[beg + j];
            s_src[wif][lane] = s;
            float ev[HEADS];
            if constexpr (HEADS == 4) {
                float4 t = *(const float4*)(as_n + (size_t)s * 4);
                ev[0]=t.x; ev[1]=t.y; ev[2]=t.z; ev[3]=t.w;
            } else {
                float2 t = *(const float2*)(as_n + (size_t)s * 2);
                ev[0]=t.x; ev[1]=t.y;
            }
            #pragma unroll
            for (int h = 0; h < HEADS; h++) {
                float e = ev[h] + adv[h];
                e = fmaxf(e, 0.2f * e);
                s_p[wif][lane * HEADS + h] = __expf(e);
            }
        }
        for (int q = 0; q < cnt; q++) {
            int s = s_src[wif][q];
            float p = s_p[wif][q * HEADS + h_id];
            sumh += p;
            if constexpr (HEADS == 4) {
                uint2 v = *(const uint2*)(hpre + (size_t)s * 256 + h_id * 64 + dq * 4);
                acc[0] += p * bflo(v.x); acc[1] += p * bfhi(v.x);
                acc[2] += p * bflo(v.y); acc[3] += p * bfhi(v.y);
            } else {
                unsigned v = *(const unsigned*)(hpre + (size_t)s * 128 + h_id * 64 + dq * 2);
                acc[0] += p * bflo(v); acc[1] += p * bfhi(v);
            }
        }
    }
    float inv = 1.0f / (sumh + 1e-16f);
    float r[HEADS];
    #pragma unroll
    for (int c = 0; c < HEADS; c++) r[c] = acc[c] * inv;
    if constexpr (HEADS == 4) {
        #pragma unroll
        for (int c = 0; c < 4; c++) {
            r[c] += __shfl_xor(r[c], 16);
            r[c] += __shfl_xor(r[c], 32);
            r[c] *= 0.25f;
        }
        if (h_id == 0) {
            float4 b = *(const float4*)(bias + dq * 4);
            float4 o;
            o.x = fmaxf(r[0] + b.x, 0.f); o.y = fmaxf(r[1] + b.y, 0.f);
            o.z = fmaxf(r[2] + b.z, 0.f); o.w = fmaxf(r[3] + b.w, 0.f);
            *(float4*)(out + (size_t)n * 64 + dq * 4) = o;
        }
    } else {
        #pragma unroll
        for (int c = 0; c < 2; c++) {
            r[c] += __shfl_xor(r[c], 32);
            r[c] *= 0.5f;
        }
        if (h_id == 0) {
            float2 b = *(const float2*)(bias + dq * 2);
            float2 o;
            o.x = fmaxf(r[0] + b.x, 0.f); o.y = fmaxf(r[1] + b.y, 0.f);
            *(float2*)(out + (size_t)n * 64 + dq * 2) = o;
        }
    }
}

// ---------------- GCN aggregate: 8 lanes per node, bf16 gather ----------------

__global__ __launch_bounds__(256) void k_gcn_agg(const unsigned short* __restrict__ hpre,
        const float* __restrict__ dinv, const float* __restrict__ bias,
        const int* __restrict__ offs, const int* __restrict__ csr,
        float* __restrict__ out, int n_nodes) {
    int gid = blockIdx.x * 256 + threadIdx.x;
    int n = gid >> 3, q = gid & 7;
    if (n >= n_nodes) return;
    const int beg = offs[n], end = offs[n + 1];
    float4 acc = make_float4(0.f,0.f,0.f,0.f);
    for (int j = beg; j < end; j++) {
        int s = csr[j];
        float ds = dinv[s];
        uint2 v = *(const uint2*)(hpre + (size_t)s * 32 + q * 4);
        acc.x += ds * bflo(v.x); acc.y += ds * bfhi(v.x);
        acc.z += ds * bflo(v.y); acc.w += ds * bfhi(v.y);
    }
    float dn = dinv[n];
    float4 b = *(const float4*)(bias + q * 4);
    float4 o;
    o.x = fmaxf(acc.x * dn + b.x, 0.f); o.y = fmaxf(acc.y * dn + b.y, 0.f);
    o.z = fmaxf(acc.z * dn + b.z, 0.f); o.w = fmaxf(acc.w * dn + b.w, 0.f);
    *(float4*)(out + (size_t)n * 32 + q * 4) = o;
}

// ---------------- MLP head + sigmoid ----------------

__global__ __launch_bounds__(256) void k_mlp(const float* __restrict__ h3,
        const float* __restrict__ Wh1, const float* __restrict__ bh1,
        const float* __restrict__ Wh2, const float* __restrict__ bh2,
        float* __restrict__ out, int n_nodes) {
    __shared__ float w1[512];
    __shared__ float w2[16];
    __shared__ float b1s[16];
    __shared__ float b2s;
    int tid = threadIdx.x;
    for (int i = tid; i < 512; i += 256) w1[i] = Wh1[i];
    if (tid < 16) { w2[tid] = Wh2[tid]; b1s[tid] = bh1[tid]; }
    if (tid == 0) b2s = bh2[0];
    __syncthreads();
    int n = blockIdx.x * 256 + tid;
    if (n >= n_nodes) return;
    float x[32];
    const float4* p = (const float4*)(h3 + (size_t)n * 32);
    #pragma unroll
    for (int q = 0; q < 8; q++) { float4 v = p[q]; x[4*q] = v.x; x[4*q+1] = v.y; x[4*q+2] = v.z; x[4*q+3] = v.w; }
    float acc2 = b2s;
    #pragma unroll
    for (int j = 0; j < 16; j++) {
        float z = b1s[j];
        #pragma unroll
        for (int k = 0; k < 32; k++) z += x[k] * w1[k * 16 + j];
        z = fmaxf(z, 0.f);
        acc2 += z * w2[j];
    }
    out[n] = 1.0f / (1.0f + expf(-acc2));
}

// ---------------- launch ----------------

extern "C" void kernel_launch(void* const* d_in, const int* in_sizes, int n_in,
                              void* d_out, int out_size, void* d_ws, size_t ws_size,
                              hipStream_t stream) {
    const float* x   = (const float*)d_in[0];
    const int*   ei  = (const int*)d_in[1];
    const float* W1  = (const float*)d_in[2];
    const float* a1s = (const float*)d_in[3];
    const float* a1d = (const float*)d_in[4];
    const float* b1  = (const float*)d_in[5];
    const float* W2  = (const float*)d_in[6];
    const float* a2s = (const float*)d_in[7];
    const float* a2d = (const float*)d_in[8];
    const float* b2  = (const float*)d_in[9];
    const float* Wg  = (const float*)d_in[10];
    const float* bg  = (const float*)d_in[11];
    const float* Wh1 = (const float*)d_in[12];
    const float* bh1 = (const float*)d_in[13];
    const float* Wh2 = (const float*)d_in[14];
    const float* bh2 = (const float*)d_in[15];

    const int N = in_sizes[0] / 256;
    const int E = in_sizes[1] / 2;
    const int* srcs = ei;
    const int* dsts = ei + E;

    // workspace layout
    float* R0   = (float*)d_ws;              // N*256 fp32 region; reused as bf16 hpre
    float* R1   = R0 + (size_t)N * 256;      // N*64  : h1 / h3 (fp32)
    float* R2   = R1 + (size_t)N * 64;       // N*64  : h2 (fp32)
    float* As_  = R2 + (size_t)N * 64;       // N*4
    float* Ad_  = As_ + (size_t)N * 4;       // N*4
    float* dinv = Ad_ + (size_t)N * 4;       // N
    int* deg    = (int*)(dinv + N);          // N
    int* offs   = deg + N;                   // N+1
    int* cursor = offs + (N + 1);            // N
    int* csr    = cursor + N;                // E + N
    int* parts  = csr + (E + N);             // <=256
    unsigned short* W1t = (unsigned short*)(parts + 256);   // 256*256 bf16
    unsigned short* HP  = (unsigned short*)R0;              // bf16 h1pre/h2pre/h3pre

    // ---- CSR build (with self loops; cursor/self/dinv fused into scan) ----
    hipMemsetAsync(deg, 0, (size_t)N * sizeof(int), stream);
    k_count_deg<<<cdiv(E, 256), 256, 0, stream>>>(dsts, E, deg);
    int nch = cdiv(N, 1024);
    k_scan_partial<<<nch, 256, 0, stream>>>(deg, N, parts);
    k_scan_top<<<1, 64, 0, stream>>>(parts, nch, offs, N);
    k_scan_final<<<nch, 256, 0, stream>>>(deg, N, parts, offs, cursor, csr, dinv);
    k_fill_csr<<<cdiv(E, 256), 256, 0, stream>>>(srcs, dsts, E, cursor, csr);

    // ---- GAT layer 1 (heads=4): bf16 MFMA GEMM -> bf16 hpre ----
    k_prep_w1<<<256, 256, 0, stream>>>(W1, W1t);
    k_gemm1_mfma<<<cdiv(N, 128), 512, 0, stream>>>(x, W1t, HP, N);
    k_att_dots<4><<<cdiv(N * 4, 256), 256, 0, stream>>>(HP, a1s, a1d, As_, Ad_, N);
    k_gat_fused<4><<<cdiv(N, 4), 256, 0, stream>>>(HP, As_, Ad_, b1, offs, csr, R1, N);

    // ---- GAT layer 2 (heads=2) ----
    dim3 g2(cdiv(N, 64), 2);
    k_gemm_k64<64, 128, true><<<g2, 256, 0, stream>>>(R1, W2, HP, N);
    k_att_dots<2><<<cdiv(N * 2, 256), 256, 0, stream>>>(HP, a2s, a2d, As_, Ad_, N);
    k_gat_fused<2><<<cdiv(N, 4), 256, 0, stream>>>(HP, As_, Ad_, b2, offs, csr, R2, N);

    // ---- GCN ----
    dim3 g3(cdiv(N, 64), 1);
    k_gemm_k64<32, 32, true><<<g3, 256, 0, stream>>>(R2, Wg, HP, N);
    k_gcn_agg<<<cdiv(N * 8, 256), 256, 0, stream>>>(HP, dinv, bg, offs, csr, R1, N);

    // ---- MLP head ----
    k_mlp<<<cdiv(N, 256), 256, 0, stream>>>(R1, Wh1, bh1, Wh2, bh2, (float*)d_out, N);
}

// Round 6
// 512.872 us; speedup vs baseline: 5.1091x; 1.1986x over previous
//
#include <hip/hip_runtime.h>
#include <math.h>

static inline int cdiv(int a, int b){ return (a + b - 1) / b; }

typedef __attribute__((ext_vector_type(8))) short short8_t;   // 8 bf16 (4 VGPRs)
typedef __attribute__((ext_vector_type(4))) float f32x4;      // MFMA acc
typedef __attribute__((ext_vector_type(2))) float f32x2;

static __device__ inline unsigned short f2bf(float f) {       // fp32 -> bf16 RTNE
    union { float f; unsigned u; } v; v.f = f;
    unsigned r = v.u + 0x7fff + ((v.u >> 16) & 1);
    return (unsigned short)(r >> 16);
}

// ---- fp8 e4m3fn (OCP) helpers ----
static __device__ inline unsigned char f2fp8(float f) {       // RTNE, saturating
    union { float f; unsigned u; } v; v.f = f;
    unsigned s = (v.u >> 24) & 0x80u;
    v.u &= 0x7fffffffu;
    v.f = fminf(v.f, 448.f);
    unsigned out;
    if (v.u >= (121u << 23)) {                 // |x| >= 2^-6 : normal
        unsigned u = v.u + 0x7FFFFu + ((v.u >> 20) & 1u);
        out = (((u >> 23) - 120u) << 3) | ((u >> 20) & 7u);
    } else {                                   // denormal: round(x * 2^9)
        out = (unsigned)(v.f * 512.f + 0.5f);  // ==8 -> 0x08 == smallest normal
    }
    return (unsigned char)(out | s);
}

static __device__ inline float fp8_1(unsigned b) {            // scalar decode (fallback)
    unsigned s = (b & 0x80u) << 24;
    unsigned em = b & 0x7fu;
    union { unsigned u; float f; } n;
    n.u = (((em >> 3) + 120u) << 23) | ((em & 7u) << 20);
    float mag = (em >= 8u) ? n.f : (float)em * 0.001953125f;
    union { unsigned u; float f; } r; r.f = mag; r.u |= s;
    return r.f;
}

static __device__ __forceinline__ f32x2 fp8lo(unsigned v) {   // bytes 0,1
#if __has_builtin(__builtin_amdgcn_cvt_pk_f32_fp8)
    return __builtin_amdgcn_cvt_pk_f32_fp8((int)v, false);
#else
    f32x2 r; r[0] = fp8_1(v & 0xff); r[1] = fp8_1((v >> 8) & 0xff); return r;
#endif
}
static __device__ __forceinline__ f32x2 fp8hi(unsigned v) {   // bytes 2,3
#if __has_builtin(__builtin_amdgcn_cvt_pk_f32_fp8)
    return __builtin_amdgcn_cvt_pk_f32_fp8((int)v, true);
#else
    f32x2 r; r[0] = fp8_1((v >> 16) & 0xff); r[1] = fp8_1(v >> 24); return r;
#endif
}

// ---------------- graph build (CSR by dst, self-loops folded in) ----------------

__global__ void k_count_deg(const int* __restrict__ dst, int E, int* __restrict__ deg) {
    int e = blockIdx.x * 256 + threadIdx.x;
    if (e < E) atomicAdd(&deg[dst[e]], 1);
}

__global__ void k_scan_partial(const int* __restrict__ deg, int n, int* __restrict__ partial) {
    __shared__ int sd[256];
    int base = blockIdx.x * 1024;
    int sum = 0;
    for (int i = threadIdx.x; i < 1024; i += 256) {
        int idx = base + i;
        if (idx < n) sum += deg[idx] + 1;          // +1: self loop
    }
    sd[threadIdx.x] = sum;
    __syncthreads();
    for (int s = 128; s > 0; s >>= 1) {
        if (threadIdx.x < s) sd[threadIdx.x] += sd[threadIdx.x + s];
        __syncthreads();
    }
    if (threadIdx.x == 0) partial[blockIdx.x] = sd[0];
}

__global__ void k_scan_top(int* __restrict__ partial, int nb, int* __restrict__ offs, int n) {
    if (blockIdx.x == 0 && threadIdx.x == 0) {
        int run = 0;
        for (int i = 0; i < nb; i++) { int v = partial[i]; partial[i] = run; run += v; }
        offs[n] = run;   // == E + N
    }
}

// scan + fused: offs, cursor init, self-loop slot, dinv
__global__ void k_scan_final(const int* __restrict__ deg, int n,
                             const int* __restrict__ partial, int* __restrict__ offs,
                             int* __restrict__ cursor, int* __restrict__ csr,
                             float* __restrict__ dinv) {
    __shared__ int sd[256];
    int tid = threadIdx.x;
    int base = blockIdx.x * 1024;
    int v[4]; int s0 = 0;
    #pragma unroll
    for (int j = 0; j < 4; j++) {
        int idx = base + tid*4 + j;
        v[j] = (idx < n) ? (deg[idx] + 1) : 0;
        s0 += v[j];
    }
    sd[tid] = s0;
    __syncthreads();
    for (int st = 1; st < 256; st <<= 1) {
        int t = (tid >= st) ? sd[tid - st] : 0;
        __syncthreads();
        sd[tid] += t;
        __syncthreads();
    }
    int ex = (tid > 0 ? sd[tid - 1] : 0) + partial[blockIdx.x];
    #pragma unroll
    for (int j = 0; j < 4; j++) {
        int idx = base + tid*4 + j;
        if (idx < n) {
            offs[idx]   = ex;
            cursor[idx] = ex;
            dinv[idx]   = rsqrtf((float)v[j]);
            csr[ex + v[j] - 1] = idx;          // self slot (fill never touches it)
        }
        ex += v[j];
    }
}

__global__ void k_fill_csr(const int* __restrict__ src, const int* __restrict__ dst, int E,
                           int* __restrict__ cursor, int* __restrict__ csr) {
    int e = blockIdx.x * 256 + threadIdx.x;
    if (e < E) { int d = dst[e]; int p = atomicAdd(&cursor[d], 1); csr[p] = src[e]; }
}

// ---------------- GEMM1: fp8 hpre + fused att-dots, via bf16 MFMA ----------------

__global__ void k_prep_w1(const float* __restrict__ W, unsigned short* __restrict__ Bt) {
    int t = blockIdx.x * 256 + threadIdx.x;    // 65536 elements
    int k = t >> 8, c = t & 255;
    Bt[c * 256 + k] = f2bf(W[t]);
}

// BM=128, BN=256 (full width), BK=32, 512 thr / 8 waves, wave tile 32x128.
// Epilogue: fp8 store of h1pre + per-(row,head) a_s/a_d via frag-group shfl reduce
// (head cols are complete within one wave -> direct store, no atomics).
__global__ __launch_bounds__(512) void k_gemm1_mfma(const float* __restrict__ A,
        const unsigned short* __restrict__ Bt, const float* __restrict__ att_s_g,
        const float* __restrict__ att_d_g, unsigned char* __restrict__ C,
        float* __restrict__ out_as, float* __restrict__ out_ad, int M) {
    constexpr int LDP = 40;                    // 80 B row: 2-way bank alias only (free)
    __shared__ __align__(16) unsigned short As[128 * LDP];
    __shared__ __align__(16) unsigned short Bs[256 * LDP];
    __shared__ float att_l[512];               // [0:256) att_s, [256:512) att_d (flat col)
    int tid = threadIdx.x;
    int bm = blockIdx.x * 128;
    int wave = tid >> 6, lane = tid & 63;
    int wr = wave >> 1, wc = wave & 1;
    int lg = lane >> 4, lr = lane & 15;

    att_l[tid] = (tid < 256) ? att_s_g[tid] : att_d_g[tid - 256];

    f32x4 acc[2][8] = {};

    for (int k0 = 0; k0 < 256; k0 += 32) {
        __syncthreads();
        {   // stage A: fp32 -> bf16
            int row = tid >> 2, part = tid & 3;
            int gr = bm + row;
            float4 v0, v1;
            if (gr < M) {
                const float4* p = (const float4*)(A + (size_t)gr * 256 + k0 + part * 8);
                v0 = p[0]; v1 = p[1];
            } else {
                v0 = make_float4(0.f,0.f,0.f,0.f); v1 = v0;
            }
            unsigned short* w = &As[row * LDP + part * 8];
            w[0]=f2bf(v0.x); w[1]=f2bf(v0.y); w[2]=f2bf(v0.z); w[3]=f2bf(v0.w);
            w[4]=f2bf(v1.x); w[5]=f2bf(v1.y); w[6]=f2bf(v1.z); w[7]=f2bf(v1.w);
        }
        {   // stage B
            int col = tid >> 1, part = tid & 1;
            const uint4* p = (const uint4*)(Bt + (size_t)col * 256 + k0 + part * 16);
            uint4 u0 = p[0], u1 = p[1];
            *(uint4*)&Bs[col * LDP + part * 16]     = u0;
            *(uint4*)&Bs[col * LDP + part * 16 + 8] = u1;
        }
        __syncthreads();
        short8_t a[2], b[8];
        #pragma unroll
        for (int i = 0; i < 2; i++)
            a[i] = *(const short8_t*)&As[(wr * 32 + i * 16 + lr) * LDP + lg * 8];
        #pragma unroll
        for (int j = 0; j < 8; j++)
            b[j] = *(const short8_t*)&Bs[(wc * 128 + j * 16 + lr) * LDP + lg * 8];
        #pragma unroll
        for (int i = 0; i < 2; i++)
            #pragma unroll
            for (int j = 0; j < 8; j++)
                acc[i][j] = __builtin_amdgcn_mfma_f32_16x16x32_bf16(a[i], b[j], acc[i][j], 0, 0, 0);
    }
    // att weights for this thread's 8 cols (j*16+lr within wave half wc)
    float ws[8], wd[8];
    #pragma unroll
    for (int j = 0; j < 8; j++) {
        int c = wc * 128 + j * 16 + lr;
        ws[j] = att_l[c]; wd[j] = att_l[256 + c];
    }
    #pragma unroll
    for (int i = 0; i < 2; i++) {
        #pragma unroll
        for (int b2 = 0; b2 < 4; b2++) {
            int row = bm + wr * 32 + i * 16 + lg * 4 + b2;
            // fp8 store of this row's 8 cols
            #pragma unroll
            for (int j = 0; j < 8; j++) {
                int col = wc * 128 + j * 16 + lr;
                if (row < M) C[(size_t)row * 256 + col] = f2fp8(acc[i][j][b2]);
            }
            // fused att-dot partials: head wc*2 = j 0..3, head wc*2+1 = j 4..7
            float s0=0.f, s1=0.f, d0=0.f, d1=0.f;
            #pragma unroll
            for (int j = 0; j < 4; j++) { float v = acc[i][j][b2];   s0 += v*ws[j];   d0 += v*wd[j]; }
            #pragma unroll
            for (int j = 4; j < 8; j++) { float v = acc[i][j][b2];   s1 += v*ws[j];   d1 += v*wd[j]; }
            #pragma unroll
            for (int off = 1; off < 16; off <<= 1) {
                s0 += __shfl_xor(s0, off); s1 += __shfl_xor(s1, off);
                d0 += __shfl_xor(d0, off); d1 += __shfl_xor(d1, off);
            }
            if (lr == 0 && row < M) {
                out_as[row * 4 + wc * 2]     = s0;
                out_as[row * 4 + wc * 2 + 1] = s1;
                out_ad[row * 4 + wc * 2]     = d0;
                out_ad[row * 4 + wc * 2 + 1] = d1;
            }
        }
    }
}

// ---------------- small fp32 GEMM: C[M,NC] = A[M,64] @ B[64,NC] ----------------
// OB: fp8 output. ATT: fuse a_s/a_d epilogue (block = one head; HEADS=2 layout).

template<int NCB, int NC, bool OB, bool ATT>
__global__ __launch_bounds__(256) void k_gemm_k64(const float* __restrict__ A,
                                                  const float* __restrict__ B,
                                                  const float* __restrict__ att_s_g,
                                                  const float* __restrict__ att_d_g,
                                                  void* __restrict__ Cv,
                                                  float* __restrict__ out_as,
                                                  float* __restrict__ out_ad, int M) {
    constexpr int TN = NCB / 16;
    __shared__ float As[64][65];
    __shared__ float Bs[64][NCB + 1];
    __shared__ float att_l[ATT ? 2 * NCB : 1];
    int tid = threadIdx.x;
    int bm = blockIdx.x * 64;
    int bn = blockIdx.y * NCB;
    if constexpr (ATT) {
        if (tid < 2 * NCB)
            att_l[tid] = (tid < NCB) ? att_s_g[bn + tid] : att_d_g[bn + tid - NCB];
    }
    {
        int c = tid & 63, r0 = tid >> 6;
        #pragma unroll
        for (int it = 0; it < 16; it++) {
            int r = r0 + it * 4;
            int gr = bm + r;
            As[r][c] = (gr < M) ? A[(size_t)gr * 64 + c] : 0.f;
        }
    }
    for (int i = tid; i < 64 * NCB; i += 256) {
        int r = i / NCB, cc = i % NCB;
        Bs[r][cc] = B[(size_t)r * NC + bn + cc];
    }
    __syncthreads();
    int ty = tid >> 4, tx = tid & 15;
    float acc[4][TN] = {};
    #pragma unroll 8
    for (int k = 0; k < 64; k++) {
        float a[4], b[TN];
        #pragma unroll
        for (int i = 0; i < 4; i++) a[i] = As[ty + 16*i][k];
        #pragma unroll
        for (int j = 0; j < TN; j++) b[j] = Bs[k][tx + 16*j];
        #pragma unroll
        for (int i = 0; i < 4; i++)
            #pragma unroll
            for (int j = 0; j < TN; j++) acc[i][j] += a[i] * b[j];
    }
    float ws[TN], wd[TN];
    if constexpr (ATT) {
        #pragma unroll
        for (int j = 0; j < TN; j++) { ws[j] = att_l[tx + 16*j]; wd[j] = att_l[NCB + tx + 16*j]; }
    }
    #pragma unroll
    for (int i = 0; i < 4; i++) {
        int gr = bm + ty + 16*i;
        #pragma unroll
        for (int j = 0; j < TN; j++) {
            if (gr < M) {
                if constexpr (OB)
                    ((unsigned char*)Cv)[(size_t)gr * NC + bn + tx + 16*j] = f2fp8(acc[i][j]);
                else
                    ((float*)Cv)[(size_t)gr * NC + bn + tx + 16*j] = acc[i][j];
            }
        }
        if constexpr (ATT) {
            float s = 0.f, d = 0.f;
            #pragma unroll
            for (int j = 0; j < TN; j++) { s += acc[i][j]*ws[j]; d += acc[i][j]*wd[j]; }
            #pragma unroll
            for (int off = 1; off < 16; off <<= 1) { s += __shfl_xor(s, off); d += __shfl_xor(d, off); }
            if (tx == 0 && gr < M) {
                out_as[gr * 2 + blockIdx.y] = s;
                out_ad[gr * 2 + blockIdx.y] = d;
            }
        }
    }
}

// ---------------- fused GAT aggregate (fp8 gather) ----------------
// One wave per node. Phase 1 (lanes over edges): p = exp(leaky(a_s[src]+a_d[n]))
// once per edge-head -> LDS. Phase 2 (lanes over (head,dim)): fp8 gather, row
// read contiguously by the wave (256 B for H=4, 128 B for H=2); per-lane sumh
// accumulates its head's denominator. No max-subtraction (|e| small, shift-inv).

template<int HEADS>
__global__ __launch_bounds__(256) void k_gat_fused(const unsigned char* __restrict__ hpre,
        const float* __restrict__ as_n, const float* __restrict__ ad_n,
        const float* __restrict__ bias,
        const int* __restrict__ offs, const int* __restrict__ csr,
        float* __restrict__ out, int n_nodes) {
    __shared__ int   s_src[4][64];
    __shared__ float s_p[4][64 * HEADS];
    int wif  = threadIdx.x >> 6;
    int lane = threadIdx.x & 63;
    int n = blockIdx.x * 4 + wif;
    if (n >= n_nodes) return;
    const int beg = offs[n];
    const int deg = offs[n + 1] - beg;

    int h_id, dq;
    if constexpr (HEADS == 4) { h_id = lane >> 4; dq = lane & 15; }
    else                      { h_id = lane >> 5; dq = lane & 31; }

    float adv[HEADS];
    if constexpr (HEADS == 4) {
        float4 t = *(const float4*)(ad_n + (size_t)n * 4);
        adv[0]=t.x; adv[1]=t.y; adv[2]=t.z; adv[3]=t.w;
    } else {
        float2 t = *(const float2*)(ad_n + (size_t)n * 2);
        adv[0]=t.x; adv[1]=t.y;
    }

    float sumh = 0.f;
    float acc[HEADS] = {};

    for (int j0 = 0; j0 < deg; j0 += 64) {
        int j = j0 + lane;
        int cnt = min(64, deg - j0);
        if (j < deg) {
            int s = csr[beg + j];
            s_src[wif][lane] = s;
            float ev[HEADS];
            if constexpr (HEADS == 4) {
                float4 t = *(const float4*)(as_n + (size_t)s * 4);
                ev[0]=t.x; ev[1]=t.y; ev[2]=t.z; ev[3]=t.w;
            } else {
                float2 t = *(const float2*)(as_n + (size_t)s * 2);
                ev[0]=t.x; ev[1]=t.y;
            }
            #pragma unroll
            for (int h = 0; h < HEADS; h++) {
                float e = ev[h] + adv[h];
                e = fmaxf(e, 0.2f * e);
                s_p[wif][lane * HEADS + h] = __expf(e);
            }
        }
        for (int q = 0; q < cnt; q++) {
            int s = s_src[wif][q];
            float p = s_p[wif][q * HEADS + h_id];
            sumh += p;
            if constexpr (HEADS == 4) {
                unsigned v = *(const unsigned*)(hpre + (size_t)s * 256 + h_id * 64 + dq * 4);
                f32x2 l = fp8lo(v), h2 = fp8hi(v);
                acc[0] += p * l[0]; acc[1] += p * l[1];
                acc[2] += p * h2[0]; acc[3] += p * h2[1];
            } else {
                unsigned v = *(const unsigned short*)(hpre + (size_t)s * 128 + h_id * 64 + dq * 2);
                f32x2 l = fp8lo(v);
                acc[0] += p * l[0]; acc[1] += p * l[1];
            }
        }
    }
    float inv = 1.0f / (sumh + 1e-16f);
    float r[HEADS];
    #pragma unroll
    for (int c = 0; c < HEADS; c++) r[c] = acc[c] * inv;
    if constexpr (HEADS == 4) {
        #pragma unroll
        for (int c = 0; c < 4; c++) {
            r[c] += __shfl_xor(r[c], 16);
            r[c] += __shfl_xor(r[c], 32);
            r[c] *= 0.25f;
        }
        if (h_id == 0) {
            float4 b = *(const float4*)(bias + dq * 4);
            float4 o;
            o.x = fmaxf(r[0] + b.x, 0.f); o.y = fmaxf(r[1] + b.y, 0.f);
            o.z = fmaxf(r[2] + b.z, 0.f); o.w = fmaxf(r[3] + b.w, 0.f);
            *(float4*)(out + (size_t)n * 64 + dq * 4) = o;
        }
    } else {
        #pragma unroll
        for (int c = 0; c < 2; c++) {
            r[c] += __shfl_xor(r[c], 32);
            r[c] *= 0.5f;
        }
        if (h_id == 0) {
            float2 b = *(const float2*)(bias + dq * 2);
            float2 o;
            o.x = fmaxf(r[0] + b.x, 0.f); o.y = fmaxf(r[1] + b.y, 0.f);
            *(float2*)(out + (size_t)n * 64 + dq * 2) = o;
        }
    }
}

// ---------------- GCN aggregate: 8 lanes per node, fp8 gather ----------------

__global__ __launch_bounds__(256) void k_gcn_agg(const unsigned char* __restrict__ hpre,
        const float* __restrict__ dinv, const float* __restrict__ bias,
        const int* __restrict__ offs, const int* __restrict__ csr,
        float* __restrict__ out, int n_nodes) {
    int gid = blockIdx.x * 256 + threadIdx.x;
    int n = gid >> 3, q = gid & 7;
    if (n >= n_nodes) return;
    const int beg = offs[n], end = offs[n + 1];
    float4 acc = make_float4(0.f,0.f,0.f,0.f);
    for (int j = beg; j < end; j++) {
        int s = csr[j];
        float ds = dinv[s];
        unsigned v = *(const unsigned*)(hpre + (size_t)s * 32 + q * 4);
        f32x2 l = fp8lo(v), h2 = fp8hi(v);
        acc.x += ds * l[0]; acc.y += ds * l[1];
        acc.z += ds * h2[0]; acc.w += ds * h2[1];
    }
    float dn = dinv[n];
    float4 b = *(const float4*)(bias + q * 4);
    float4 o;
    o.x = fmaxf(acc.x * dn + b.x, 0.f); o.y = fmaxf(acc.y * dn + b.y, 0.f);
    o.z = fmaxf(acc.z * dn + b.z, 0.f); o.w = fmaxf(acc.w * dn + b.w, 0.f);
    *(float4*)(out + (size_t)n * 32 + q * 4) = o;
}

// ---------------- MLP head + sigmoid ----------------

__global__ __launch_bounds__(256) void k_mlp(const float* __restrict__ h3,
        const float* __restrict__ Wh1, const float* __restrict__ bh1,
        const float* __restrict__ Wh2, const float* __restrict__ bh2,
        float* __restrict__ out, int n_nodes) {
    __shared__ float w1[512];
    __shared__ float w2[16];
    __shared__ float b1s[16];
    __shared__ float b2s;
    int tid = threadIdx.x;
    for (int i = tid; i < 512; i += 256) w1[i] = Wh1[i];
    if (tid < 16) { w2[tid] = Wh2[tid]; b1s[tid] = bh1[tid]; }
    if (tid == 0) b2s = bh2[0];
    __syncthreads();
    int n = blockIdx.x * 256 + tid;
    if (n >= n_nodes) return;
    float x[32];
    const float4* p = (const float4*)(h3 + (size_t)n * 32);
    #pragma unroll
    for (int q = 0; q < 8; q++) { float4 v = p[q]; x[4*q] = v.x; x[4*q+1] = v.y; x[4*q+2] = v.z; x[4*q+3] = v.w; }
    float acc2 = b2s;
    #pragma unroll
    for (int j = 0; j < 16; j++) {
        float z = b1s[j];
        #pragma unroll
        for (int k = 0; k < 32; k++) z += x[k] * w1[k * 16 + j];
        z = fmaxf(z, 0.f);
        acc2 += z * w2[j];
    }
    out[n] = 1.0f / (1.0f + expf(-acc2));
}

// ---------------- launch ----------------

extern "C" void kernel_launch(void* const* d_in, const int* in_sizes, int n_in,
                              void* d_out, int out_size, void* d_ws, size_t ws_size,
                              hipStream_t stream) {
    const float* x   = (const float*)d_in[0];
    const int*   ei  = (const int*)d_in[1];
    const float* W1  = (const float*)d_in[2];
    const float* a1s = (const float*)d_in[3];
    const float* a1d = (const float*)d_in[4];
    const float* b1  = (const float*)d_in[5];
    const float* W2  = (const float*)d_in[6];
    const float* a2s = (const float*)d_in[7];
    const float* a2d = (const float*)d_in[8];
    const float* b2  = (const float*)d_in[9];
    const float* Wg  = (const float*)d_in[10];
    const float* bg  = (const float*)d_in[11];
    const float* Wh1 = (const float*)d_in[12];
    const float* bh1 = (const float*)d_in[13];
    const float* Wh2 = (const float*)d_in[14];
    const float* bh2 = (const float*)d_in[15];

    const int N = in_sizes[0] / 256;
    const int E = in_sizes[1] / 2;
    const int* srcs = ei;
    const int* dsts = ei + E;

    // workspace layout
    float* R0   = (float*)d_ws;              // N*256 fp32 region; reused as fp8 hpre
    float* R1   = R0 + (size_t)N * 256;      // N*64  : h1 / h3 (fp32)
    float* R2   = R1 + (size_t)N * 64;       // N*64  : h2 (fp32)
    float* As_  = R2 + (size_t)N * 64;       // N*4
    float* Ad_  = As_ + (size_t)N * 4;       // N*4
    float* dinv = Ad_ + (size_t)N * 4;       // N
    int* deg    = (int*)(dinv + N);          // N
    int* offs   = deg + N;                   // N+1
    int* cursor = offs + (N + 1);            // N
    int* csr    = cursor + N;                // E + N
    int* parts  = csr + (E + N);             // <=256
    unsigned short* W1t = (unsigned short*)(parts + 256);   // 256*256 bf16
    unsigned char*  HP  = (unsigned char*)R0;               // fp8 h1pre/h2pre/h3pre

    // ---- CSR build (with self loops; cursor/self/dinv fused into scan) ----
    hipMemsetAsync(deg, 0, (size_t)N * sizeof(int), stream);
    k_count_deg<<<cdiv(E, 256), 256, 0, stream>>>(dsts, E, deg);
    int nch = cdiv(N, 1024);
    k_scan_partial<<<nch, 256, 0, stream>>>(deg, N, parts);
    k_scan_top<<<1, 64, 0, stream>>>(parts, nch, offs, N);
    k_scan_final<<<nch, 256, 0, stream>>>(deg, N, parts, offs, cursor, csr, dinv);
    k_fill_csr<<<cdiv(E, 256), 256, 0, stream>>>(srcs, dsts, E, cursor, csr);

    // ---- GAT layer 1 (heads=4): MFMA GEMM w/ fused att-dots -> fp8 hpre ----
    k_prep_w1<<<256, 256, 0, stream>>>(W1, W1t);
    k_gemm1_mfma<<<cdiv(N, 128), 512, 0, stream>>>(x, W1t, a1s, a1d, HP, As_, Ad_, N);
    k_gat_fused<4><<<cdiv(N, 4), 256, 0, stream>>>(HP, As_, Ad_, b1, offs, csr, R1, N);

    // ---- GAT layer 2 (heads=2): fp32 GEMM w/ fused att-dots -> fp8 hpre ----
    dim3 g2(cdiv(N, 64), 2);
    k_gemm_k64<64, 128, true, true><<<g2, 256, 0, stream>>>(R1, W2, a2s, a2d, HP, As_, Ad_, N);
    k_gat_fused<2><<<cdiv(N, 4), 256, 0, stream>>>(HP, As_, Ad_, b2, offs, csr, R2, N);

    // ---- GCN ----
    dim3 g3(cdiv(N, 64), 1);
    k_gemm_k64<32, 32, true, false><<<g3, 256, 0, stream>>>(R2, Wg, nullptr, nullptr, HP, nullptr, nullptr, N);
    k_gcn_agg<<<cdiv(N * 8, 256), 256, 0, stream>>>(HP, dinv, bg, offs, csr, R1, N);

    // ---- MLP head ----
    k_mlp<<<cdiv(N, 256), 256, 0, stream>>>(R1, Wh1, bh1, Wh2, bh2, (float*)d_out, N);
}

// Round 7
// 449.754 us; speedup vs baseline: 5.8261x; 1.1403x over previous
//
#include <hip/hip_runtime.h>
#include <math.h>

static inline int cdiv(int a, int b){ return (a + b - 1) / b; }

typedef __attribute__((ext_vector_type(8))) short short8_t;   // 8 bf16 (4 VGPRs)
typedef __attribute__((ext_vector_type(4))) float f32x4;      // MFMA acc
typedef __attribute__((ext_vector_type(2))) float f32x2;

static __device__ inline unsigned short f2bf(float f) {       // fp32 -> bf16 RTNE
    union { float f; unsigned u; } v; v.f = f;
    unsigned r = v.u + 0x7fff + ((v.u >> 16) & 1);
    return (unsigned short)(r >> 16);
}

// ---- fp8 e4m3fn (OCP) helpers ----
static __device__ inline unsigned char f2fp8(float f) {       // RTNE, saturating
    union { float f; unsigned u; } v; v.f = f;
    unsigned s = (v.u >> 24) & 0x80u;
    v.u &= 0x7fffffffu;
    v.f = fminf(v.f, 448.f);
    unsigned out;
    if (v.u >= (121u << 23)) {                 // |x| >= 2^-6 : normal
        unsigned u = v.u + 0x7FFFFu + ((v.u >> 20) & 1u);
        out = (((u >> 23) - 120u) << 3) | ((u >> 20) & 7u);
    } else {                                   // denormal: round(x * 2^9)
        out = (unsigned)(v.f * 512.f + 0.5f);
    }
    return (unsigned char)(out | s);
}

static __device__ inline float fp8_1(unsigned b) {            // scalar decode (fallback)
    unsigned s = (b & 0x80u) << 24;
    unsigned em = b & 0x7fu;
    union { unsigned u; float f; } n;
    n.u = (((em >> 3) + 120u) << 23) | ((em & 7u) << 20);
    float mag = (em >= 8u) ? n.f : (float)em * 0.001953125f;
    union { unsigned u; float f; } r; r.f = mag; r.u |= s;
    return r.f;
}

static __device__ __forceinline__ f32x2 fp8lo(unsigned v) {   // bytes 0,1
#if __has_builtin(__builtin_amdgcn_cvt_pk_f32_fp8)
    return __builtin_amdgcn_cvt_pk_f32_fp8((int)v, false);
#else
    f32x2 r; r[0] = fp8_1(v & 0xff); r[1] = fp8_1((v >> 8) & 0xff); return r;
#endif
}
static __device__ __forceinline__ f32x2 fp8hi(unsigned v) {   // bytes 2,3
#if __has_builtin(__builtin_amdgcn_cvt_pk_f32_fp8)
    return __builtin_amdgcn_cvt_pk_f32_fp8((int)v, true);
#else
    f32x2 r; r[0] = fp8_1((v >> 16) & 0xff); r[1] = fp8_1(v >> 24); return r;
#endif
}

// ---------------- graph build (CSR by dst, self-loops folded in) ----------------

__global__ void k_count_deg(const int* __restrict__ dst, int E, int* __restrict__ deg) {
    int base = (blockIdx.x * 256 + threadIdx.x) * 4;
    if (base + 3 < E) {
        int4 d = *(const int4*)(dst + base);
        atomicAdd(&deg[d.x], 1); atomicAdd(&deg[d.y], 1);
        atomicAdd(&deg[d.z], 1); atomicAdd(&deg[d.w], 1);
    } else {
        for (int k = 0; k < 4; k++)
            if (base + k < E) atomicAdd(&deg[dst[base + k]], 1);
    }
}

__global__ void k_scan_partial(const int* __restrict__ deg, int n, int* __restrict__ partial) {
    __shared__ int sd[256];
    int base = blockIdx.x * 1024;
    int sum = 0;
    for (int i = threadIdx.x; i < 1024; i += 256) {
        int idx = base + i;
        if (idx < n) sum += deg[idx] + 1;          // +1: self loop
    }
    sd[threadIdx.x] = sum;
    __syncthreads();
    for (int s = 128; s > 0; s >>= 1) {
        if (threadIdx.x < s) sd[threadIdx.x] += sd[threadIdx.x + s];
        __syncthreads();
    }
    if (threadIdx.x == 0) partial[blockIdx.x] = sd[0];
}

__global__ void k_scan_top(int* __restrict__ partial, int nb, int* __restrict__ offs, int n) {
    if (blockIdx.x == 0 && threadIdx.x == 0) {
        int run = 0;
        for (int i = 0; i < nb; i++) { int v = partial[i]; partial[i] = run; run += v; }
        offs[n] = run;   // == E + N
    }
}

// scan + fused: offs, cursor init, self-loop slot, dinv
__global__ void k_scan_final(const int* __restrict__ deg, int n,
                             const int* __restrict__ partial, int* __restrict__ offs,
                             int* __restrict__ cursor, int* __restrict__ csr,
                             float* __restrict__ dinv) {
    __shared__ int sd[256];
    int tid = threadIdx.x;
    int base = blockIdx.x * 1024;
    int v[4]; int s0 = 0;
    #pragma unroll
    for (int j = 0; j < 4; j++) {
        int idx = base + tid*4 + j;
        v[j] = (idx < n) ? (deg[idx] + 1) : 0;
        s0 += v[j];
    }
    sd[tid] = s0;
    __syncthreads();
    for (int st = 1; st < 256; st <<= 1) {
        int t = (tid >= st) ? sd[tid - st] : 0;
        __syncthreads();
        sd[tid] += t;
        __syncthreads();
    }
    int ex = (tid > 0 ? sd[tid - 1] : 0) + partial[blockIdx.x];
    #pragma unroll
    for (int j = 0; j < 4; j++) {
        int idx = base + tid*4 + j;
        if (idx < n) {
            offs[idx]   = ex;
            cursor[idx] = ex;
            dinv[idx]   = rsqrtf((float)v[j]);
            csr[ex + v[j] - 1] = idx;          // self slot (fill never touches it)
        }
        ex += v[j];
    }
}

// XCD-pinned windowed fill: window = blockIdx.x & 7 (consecutive blockIdx
// round-robin across the 8 XCDs), so window w's csr region (~850 KB) and
// cursor slice (~50 KB) stay resident in ONE XCD's L2. Round-6 profile:
// unwindowed scatter wrote 104 MB (64 B line writeback per 4 B slot, lines
// bouncing across incoherent L2s). Cost: 8x re-stream of the edge list
// (L3-resident, cheap).
__global__ __launch_bounds__(256) void k_fill_csr_win(const int* __restrict__ src,
        const int* __restrict__ dst, int E,
        int* __restrict__ cursor, int* __restrict__ csr, int wsize) {
    int win   = blockIdx.x & 7;
    int chunk = blockIdx.x >> 3;
    int lo = win * wsize, hi = lo + wsize;
    int base = (chunk * 256 + threadIdx.x) * 4;
    if (base + 3 < E) {
        int4 d = *(const int4*)(dst + base);
        int4 s = *(const int4*)(src + base);
        if (d.x >= lo && d.x < hi) { int p = atomicAdd(&cursor[d.x], 1); csr[p] = s.x; }
        if (d.y >= lo && d.y < hi) { int p = atomicAdd(&cursor[d.y], 1); csr[p] = s.y; }
        if (d.z >= lo && d.z < hi) { int p = atomicAdd(&cursor[d.z], 1); csr[p] = s.z; }
        if (d.w >= lo && d.w < hi) { int p = atomicAdd(&cursor[d.w], 1); csr[p] = s.w; }
    } else {
        for (int k = 0; k < 4; k++) {
            int e = base + k;
            if (e < E) {
                int d = dst[e];
                if (d >= lo && d < hi) { int p = atomicAdd(&cursor[d], 1); csr[p] = src[e]; }
            }
        }
    }
}

// ---------------- GEMM1: fp8 hpre + fused att-dots, via bf16 MFMA ----------------

__global__ void k_prep_w1(const float* __restrict__ W, unsigned short* __restrict__ Bt) {
    int t = blockIdx.x * 256 + threadIdx.x;    // 65536 elements
    int k = t >> 8, c = t & 255;
    Bt[c * 256 + k] = f2bf(W[t]);
}

// BM=128, BN=256 (full width), BK=32, 512 thr / 8 waves, wave tile 32x128.
__global__ __launch_bounds__(512) void k_gemm1_mfma(const float* __restrict__ A,
        const unsigned short* __restrict__ Bt, const float* __restrict__ att_s_g,
        const float* __restrict__ att_d_g, unsigned char* __restrict__ C,
        float* __restrict__ out_as, float* __restrict__ out_ad, int M) {
    constexpr int LDP = 40;                    // 80 B row: 2-way bank alias only (free)
    __shared__ __align__(16) unsigned short As[128 * LDP];
    __shared__ __align__(16) unsigned short Bs[256 * LDP];
    __shared__ float att_l[512];               // [0:256) att_s, [256:512) att_d (flat col)
    int tid = threadIdx.x;
    int bm = blockIdx.x * 128;
    int wave = tid >> 6, lane = tid & 63;
    int wr = wave >> 1, wc = wave & 1;
    int lg = lane >> 4, lr = lane & 15;

    att_l[tid] = (tid < 256) ? att_s_g[tid] : att_d_g[tid - 256];

    f32x4 acc[2][8] = {};

    for (int k0 = 0; k0 < 256; k0 += 32) {
        __syncthreads();
        {   // stage A: fp32 -> bf16
            int row = tid >> 2, part = tid & 3;
            int gr = bm + row;
            float4 v0, v1;
            if (gr < M) {
                const float4* p = (const float4*)(A + (size_t)gr * 256 + k0 + part * 8);
                v0 = p[0]; v1 = p[1];
            } else {
                v0 = make_float4(0.f,0.f,0.f,0.f); v1 = v0;
            }
            unsigned short* w = &As[row * LDP + part * 8];
            w[0]=f2bf(v0.x); w[1]=f2bf(v0.y); w[2]=f2bf(v0.z); w[3]=f2bf(v0.w);
            w[4]=f2bf(v1.x); w[5]=f2bf(v1.y); w[6]=f2bf(v1.z); w[7]=f2bf(v1.w);
        }
        {   // stage B
            int col = tid >> 1, part = tid & 1;
            const uint4* p = (const uint4*)(Bt + (size_t)col * 256 + k0 + part * 16);
            uint4 u0 = p[0], u1 = p[1];
            *(uint4*)&Bs[col * LDP + part * 16]     = u0;
            *(uint4*)&Bs[col * LDP + part * 16 + 8] = u1;
        }
        __syncthreads();
        short8_t a[2], b[8];
        #pragma unroll
        for (int i = 0; i < 2; i++)
            a[i] = *(const short8_t*)&As[(wr * 32 + i * 16 + lr) * LDP + lg * 8];
        #pragma unroll
        for (int j = 0; j < 8; j++)
            b[j] = *(const short8_t*)&Bs[(wc * 128 + j * 16 + lr) * LDP + lg * 8];
        #pragma unroll
        for (int i = 0; i < 2; i++)
            #pragma unroll
            for (int j = 0; j < 8; j++)
                acc[i][j] = __builtin_amdgcn_mfma_f32_16x16x32_bf16(a[i], b[j], acc[i][j], 0, 0, 0);
    }
    float ws[8], wd[8];
    #pragma unroll
    for (int j = 0; j < 8; j++) {
        int c = wc * 128 + j * 16 + lr;
        ws[j] = att_l[c]; wd[j] = att_l[256 + c];
    }
    #pragma unroll
    for (int i = 0; i < 2; i++) {
        #pragma unroll
        for (int b2 = 0; b2 < 4; b2++) {
            int row = bm + wr * 32 + i * 16 + lg * 4 + b2;
            #pragma unroll
            for (int j = 0; j < 8; j++) {
                int col = wc * 128 + j * 16 + lr;
                if (row < M) C[(size_t)row * 256 + col] = f2fp8(acc[i][j][b2]);
            }
            float s0=0.f, s1=0.f, d0=0.f, d1=0.f;
            #pragma unroll
            for (int j = 0; j < 4; j++) { float v = acc[i][j][b2];   s0 += v*ws[j];   d0 += v*wd[j]; }
            #pragma unroll
            for (int j = 4; j < 8; j++) { float v = acc[i][j][b2];   s1 += v*ws[j];   d1 += v*wd[j]; }
            #pragma unroll
            for (int off = 1; off < 16; off <<= 1) {
                s0 += __shfl_xor(s0, off); s1 += __shfl_xor(s1, off);
                d0 += __shfl_xor(d0, off); d1 += __shfl_xor(d1, off);
            }
            if (lr == 0 && row < M) {
                out_as[row * 4 + wc * 2]     = s0;
                out_as[row * 4 + wc * 2 + 1] = s1;
                out_ad[row * 4 + wc * 2]     = d0;
                out_ad[row * 4 + wc * 2 + 1] = d1;
            }
        }
    }
}

// ---------------- small fp32 GEMM: C[M,NC] = A[M,64] @ B[64,NC] ----------------

template<int NCB, int NC, bool OB, bool ATT>
__global__ __launch_bounds__(256) void k_gemm_k64(const float* __restrict__ A,
                                                  const float* __restrict__ B,
                                                  const float* __restrict__ att_s_g,
                                                  const float* __restrict__ att_d_g,
                                                  void* __restrict__ Cv,
                                                  float* __restrict__ out_as,
                                                  float* __restrict__ out_ad, int M) {
    constexpr int TN = NCB / 16;
    __shared__ float As[64][65];
    __shared__ float Bs[64][NCB + 1];
    __shared__ float att_l[ATT ? 2 * NCB : 1];
    int tid = threadIdx.x;
    int bm = blockIdx.x * 64;
    int bn = blockIdx.y * NCB;
    if constexpr (ATT) {
        if (tid < 2 * NCB)
            att_l[tid] = (tid < NCB) ? att_s_g[bn + tid] : att_d_g[bn + tid - NCB];
    }
    {
        int c = tid & 63, r0 = tid >> 6;
        #pragma unroll
        for (int it = 0; it < 16; it++) {
            int r = r0 + it * 4;
            int gr = bm + r;
            As[r][c] = (gr < M) ? A[(size_t)gr * 64 + c] : 0.f;
        }
    }
    for (int i = tid; i < 64 * NCB; i += 256) {
        int r = i / NCB, cc = i % NCB;
        Bs[r][cc] = B[(size_t)r * NC + bn + cc];
    }
    __syncthreads();
    int ty = tid >> 4, tx = tid & 15;
    float acc[4][TN] = {};
    #pragma unroll 8
    for (int k = 0; k < 64; k++) {
        float a[4], b[TN];
        #pragma unroll
        for (int i = 0; i < 4; i++) a[i] = As[ty + 16*i][k];
        #pragma unroll
        for (int j = 0; j < TN; j++) b[j] = Bs[k][tx + 16*j];
        #pragma unroll
        for (int i = 0; i < 4; i++)
            #pragma unroll
            for (int j = 0; j < TN; j++) acc[i][j] += a[i] * b[j];
    }
    float ws[TN], wd[TN];
    if constexpr (ATT) {
        #pragma unroll
        for (int j = 0; j < TN; j++) { ws[j] = att_l[tx + 16*j]; wd[j] = att_l[NCB + tx + 16*j]; }
    }
    #pragma unroll
    for (int i = 0; i < 4; i++) {
        int gr = bm + ty + 16*i;
        #pragma unroll
        for (int j = 0; j < TN; j++) {
            if (gr < M) {
                if constexpr (OB)
                    ((unsigned char*)Cv)[(size_t)gr * NC + bn + tx + 16*j] = f2fp8(acc[i][j]);
                else
                    ((float*)Cv)[(size_t)gr * NC + bn + tx + 16*j] = acc[i][j];
            }
        }
        if constexpr (ATT) {
            float s = 0.f, d = 0.f;
            #pragma unroll
            for (int j = 0; j < TN; j++) { s += acc[i][j]*ws[j]; d += acc[i][j]*wd[j]; }
            #pragma unroll
            for (int off = 1; off < 16; off <<= 1) { s += __shfl_xor(s, off); d += __shfl_xor(d, off); }
            if (tx == 0 && gr < M) {
                out_as[gr * 2 + blockIdx.y] = s;
                out_ad[gr * 2 + blockIdx.y] = d;
            }
        }
    }
}

// ---------------- fused GAT aggregate (fp8 gather) ----------------

template<int HEADS>
__global__ __launch_bounds__(256) void k_gat_fused(const unsigned char* __restrict__ hpre,
        const float* __restrict__ as_n, const float* __restrict__ ad_n,
        const float* __restrict__ bias,
        const int* __restrict__ offs, const int* __restrict__ csr,
        float* __restrict__ out, int n_nodes) {
    __shared__ int   s_src[4][64];
    __shared__ float s_p[4][64 * HEADS];
    int wif  = threadIdx.x >> 6;
    int lane = threadIdx.x & 63;
    int n = blockIdx.x * 4 + wif;
    if (n >= n_nodes) return;
    const int beg = offs[n];
    const int deg = offs[n + 1] - beg;

    int h_id, dq;
    if constexpr (HEADS == 4) { h_id = lane >> 4; dq = lane & 15; }
    else                      { h_id = lane >> 5; dq = lane & 31; }

    float adv[HEADS];
    if constexpr (HEADS == 4) {
        float4 t = *(const float4*)(ad_n + (size_t)n * 4);
        adv[0]=t.x; adv[1]=t.y; adv[2]=t.z; adv[3]=t.w;
    } else {
        float2 t = *(const float2*)(ad_n + (size_t)n * 2);
        adv[0]=t.x; adv[1]=t.y;
    }

    float sumh = 0.f;
    float acc[HEADS] = {};

    for (int j0 = 0; j0 < deg; j0 += 64) {
        int j = j0 + lane;
        int cnt = min(64, deg - j0);
        if (j < deg) {
            int s = csr[beg + j];
            s_src[wif][lane] = s;
            float ev[HEADS];
            if constexpr (HEADS == 4) {
                float4 t = *(const float4*)(as_n + (size_t)s * 4);
                ev[0]=t.x; ev[1]=t.y; ev[2]=t.z; ev[3]=t.w;
            } else {
                float2 t = *(const float2*)(as_n + (size_t)s * 2);
                ev[0]=t.x; ev[1]=t.y;
            }
            #pragma unroll
            for (int h = 0; h < HEADS; h++) {
                float e = ev[h] + adv[h];
                e = fmaxf(e, 0.2f * e);
                s_p[wif][lane * HEADS + h] = __expf(e);
            }
        }
        #pragma unroll 4
        for (int q = 0; q < cnt; q++) {
            int s = s_src[wif][q];
            float p = s_p[wif][q * HEADS + h_id];
            sumh += p;
            if constexpr (HEADS == 4) {
                unsigned v = *(const unsigned*)(hpre + (size_t)s * 256 + h_id * 64 + dq * 4);
                f32x2 l = fp8lo(v), h2 = fp8hi(v);
                acc[0] += p * l[0]; acc[1] += p * l[1];
                acc[2] += p * h2[0]; acc[3] += p * h2[1];
            } else {
                unsigned v = *(const unsigned short*)(hpre + (size_t)s * 128 + h_id * 64 + dq * 2);
                f32x2 l = fp8lo(v);
                acc[0] += p * l[0]; acc[1] += p * l[1];
            }
        }
    }
    float inv = 1.0f / (sumh + 1e-16f);
    float r[HEADS];
    #pragma unroll
    for (int c = 0; c < HEADS; c++) r[c] = acc[c] * inv;
    if constexpr (HEADS == 4) {
        #pragma unroll
        for (int c = 0; c < 4; c++) {
            r[c] += __shfl_xor(r[c], 16);
            r[c] += __shfl_xor(r[c], 32);
            r[c] *= 0.25f;
        }
        if (h_id == 0) {
            float4 b = *(const float4*)(bias + dq * 4);
            float4 o;
            o.x = fmaxf(r[0] + b.x, 0.f); o.y = fmaxf(r[1] + b.y, 0.f);
            o.z = fmaxf(r[2] + b.z, 0.f); o.w = fmaxf(r[3] + b.w, 0.f);
            *(float4*)(out + (size_t)n * 64 + dq * 4) = o;
        }
    } else {
        #pragma unroll
        for (int c = 0; c < 2; c++) {
            r[c] += __shfl_xor(r[c], 32);
            r[c] *= 0.5f;
        }
        if (h_id == 0) {
            float2 b = *(const float2*)(bias + dq * 2);
            float2 o;
            o.x = fmaxf(r[0] + b.x, 0.f); o.y = fmaxf(r[1] + b.y, 0.f);
            *(float2*)(out + (size_t)n * 64 + dq * 2) = o;
        }
    }
}

// ---------------- GCN aggregate: 8 lanes per node, fp8 gather ----------------

__global__ __launch_bounds__(256) void k_gcn_agg(const unsigned char* __restrict__ hpre,
        const float* __restrict__ dinv, const float* __restrict__ bias,
        const int* __restrict__ offs, const int* __restrict__ csr,
        float* __restrict__ out, int n_nodes) {
    int gid = blockIdx.x * 256 + threadIdx.x;
    int n = gid >> 3, q = gid & 7;
    if (n >= n_nodes) return;
    const int beg = offs[n], end = offs[n + 1];
    float4 acc = make_float4(0.f,0.f,0.f,0.f);
    #pragma unroll 4
    for (int j = beg; j < end; j++) {
        int s = csr[j];
        float ds = dinv[s];
        unsigned v = *(const unsigned*)(hpre + (size_t)s * 32 + q * 4);
        f32x2 l = fp8lo(v), h2 = fp8hi(v);
        acc.x += ds * l[0]; acc.y += ds * l[1];
        acc.z += ds * h2[0]; acc.w += ds * h2[1];
    }
    float dn = dinv[n];
    float4 b = *(const float4*)(bias + q * 4);
    float4 o;
    o.x = fmaxf(acc.x * dn + b.x, 0.f); o.y = fmaxf(acc.y * dn + b.y, 0.f);
    o.z = fmaxf(acc.z * dn + b.z, 0.f); o.w = fmaxf(acc.w * dn + b.w, 0.f);
    *(float4*)(out + (size_t)n * 32 + q * 4) = o;
}

// ---------------- MLP head + sigmoid ----------------

__global__ __launch_bounds__(256) void k_mlp(const float* __restrict__ h3,
        const float* __restrict__ Wh1, const float* __restrict__ bh1,
        const float* __restrict__ Wh2, const float* __restrict__ bh2,
        float* __restrict__ out, int n_nodes) {
    __shared__ float w1[512];
    __shared__ float w2[16];
    __shared__ float b1s[16];
    __shared__ float b2s;
    int tid = threadIdx.x;
    for (int i = tid; i < 512; i += 256) w1[i] = Wh1[i];
    if (tid < 16) { w2[tid] = Wh2[tid]; b1s[tid] = bh1[tid]; }
    if (tid == 0) b2s = bh2[0];
    __syncthreads();
    int n = blockIdx.x * 256 + tid;
    if (n >= n_nodes) return;
    float x[32];
    const float4* p = (const float4*)(h3 + (size_t)n * 32);
    #pragma unroll
    for (int q = 0; q < 8; q++) { float4 v = p[q]; x[4*q] = v.x; x[4*q+1] = v.y; x[4*q+2] = v.z; x[4*q+3] = v.w; }
    float acc2 = b2s;
    #pragma unroll
    for (int j = 0; j < 16; j++) {
        float z = b1s[j];
        #pragma unroll
        for (int k = 0; k < 32; k++) z += x[k] * w1[k * 16 + j];
        z = fmaxf(z, 0.f);
        acc2 += z * w2[j];
    }
    out[n] = 1.0f / (1.0f + expf(-acc2));
}

// ---------------- launch ----------------

extern "C" void kernel_launch(void* const* d_in, const int* in_sizes, int n_in,
                              void* d_out, int out_size, void* d_ws, size_t ws_size,
                              hipStream_t stream) {
    const float* x   = (const float*)d_in[0];
    const int*   ei  = (const int*)d_in[1];
    const float* W1  = (const float*)d_in[2];
    const float* a1s = (const float*)d_in[3];
    const float* a1d = (const float*)d_in[4];
    const float* b1  = (const float*)d_in[5];
    const float* W2  = (const float*)d_in[6];
    const float* a2s = (const float*)d_in[7];
    const float* a2d = (const float*)d_in[8];
    const float* b2  = (const float*)d_in[9];
    const float* Wg  = (const float*)d_in[10];
    const float* bg  = (const float*)d_in[11];
    const float* Wh1 = (const float*)d_in[12];
    const float* bh1 = (const float*)d_in[13];
    const float* Wh2 = (const float*)d_in[14];
    const float* bh2 = (const float*)d_in[15];

    const int N = in_sizes[0] / 256;
    const int E = in_sizes[1] / 2;
    const int* srcs = ei;
    const int* dsts = ei + E;

    // workspace layout
    float* R0   = (float*)d_ws;              // N*256 fp32 region; reused as fp8 hpre
    float* R1   = R0 + (size_t)N * 256;      // N*64  : h1 / h3 (fp32)
    float* R2   = R1 + (size_t)N * 64;       // N*64  : h2 (fp32)
    float* As_  = R2 + (size_t)N * 64;       // N*4
    float* Ad_  = As_ + (size_t)N * 4;       // N*4
    float* dinv = Ad_ + (size_t)N * 4;       // N
    int* deg    = (int*)(dinv + N);          // N
    int* offs   = deg + N;                   // N+1
    int* cursor = offs + (N + 1);            // N
    int* csr    = cursor + N;                // E + N
    int* parts  = csr + (E + N);             // <=256
    unsigned short* W1t = (unsigned short*)(parts + 256);   // 256*256 bf16
    unsigned char*  HP  = (unsigned char*)R0;               // fp8 h1pre/h2pre/h3pre

    // ---- CSR build (with self loops) ----
    hipMemsetAsync(deg, 0, (size_t)N * sizeof(int), stream);
    k_count_deg<<<cdiv(E, 1024), 256, 0, stream>>>(dsts, E, deg);
    int nch = cdiv(N, 1024);
    k_scan_partial<<<nch, 256, 0, stream>>>(deg, N, parts);
    k_scan_top<<<1, 64, 0, stream>>>(parts, nch, offs, N);
    k_scan_final<<<nch, 256, 0, stream>>>(deg, N, parts, offs, cursor, csr, dinv);
    int wsize = cdiv(N, 8);
    k_fill_csr_win<<<cdiv(E, 1024) * 8, 256, 0, stream>>>(srcs, dsts, E, cursor, csr, wsize);

    // ---- GAT layer 1 (heads=4): MFMA GEMM w/ fused att-dots -> fp8 hpre ----
    k_prep_w1<<<256, 256, 0, stream>>>(W1, W1t);
    k_gemm1_mfma<<<cdiv(N, 128), 512, 0, stream>>>(x, W1t, a1s, a1d, HP, As_, Ad_, N);
    k_gat_fused<4><<<cdiv(N, 4), 256, 0, stream>>>(HP, As_, Ad_, b1, offs, csr, R1, N);

    // ---- GAT layer 2 (heads=2): fp32 GEMM w/ fused att-dots -> fp8 hpre ----
    dim3 g2(cdiv(N, 64), 2);
    k_gemm_k64<64, 128, true, true><<<g2, 256, 0, stream>>>(R1, W2, a2s, a2d, HP, As_, Ad_, N);
    k_gat_fused<2><<<cdiv(N, 4), 256, 0, stream>>>(HP, As_, Ad_, b2, offs, csr, R2, N);

    // ---- GCN ----
    dim3 g3(cdiv(N, 64), 1);
    k_gemm_k64<32, 32, true, false><<<g3, 256, 0, stream>>>(R2, Wg, nullptr, nullptr, HP, nullptr, nullptr, N);
    k_gcn_agg<<<cdiv(N * 8, 256), 256, 0, stream>>>(HP, dinv, bg, offs, csr, R1, N);

    // ---- MLP head ----
    k_mlp<<<cdiv(N, 256), 256, 0, stream>>>(R1, Wh1, bh1, Wh2, bh2, (float*)d_out, N);
}

// Round 8
// 426.195 us; speedup vs baseline: 6.1482x; 1.0553x over previous
//
#include <hip/hip_runtime.h>
#include <math.h>

static inline int cdiv(int a, int b){ return (a + b - 1) / b; }

typedef __attribute__((ext_vector_type(8))) short short8_t;   // 8 bf16 (4 VGPRs)
typedef __attribute__((ext_vector_type(4))) float f32x4;      // MFMA acc
typedef __attribute__((ext_vector_type(2))) float f32x2;

static __device__ inline unsigned short f2bf(float f) {       // fp32 -> bf16 RTNE
    union { float f; unsigned u; } v; v.f = f;
    unsigned r = v.u + 0x7fff + ((v.u >> 16) & 1);
    return (unsigned short)(r >> 16);
}

// ---- fp8 e4m3fn (OCP) helpers ----
static __device__ inline unsigned char f2fp8(float f) {       // RTNE, saturating
    union { float f; unsigned u; } v; v.f = f;
    unsigned s = (v.u >> 24) & 0x80u;
    v.u &= 0x7fffffffu;
    v.f = fminf(v.f, 448.f);
    unsigned out;
    if (v.u >= (121u << 23)) {                 // |x| >= 2^-6 : normal
        unsigned u = v.u + 0x7FFFFu + ((v.u >> 20) & 1u);
        out = (((u >> 23) - 120u) << 3) | ((u >> 20) & 7u);
    } else {                                   // denormal: round(x * 2^9)
        out = (unsigned)(v.f * 512.f + 0.5f);
    }
    return (unsigned char)(out | s);
}

static __device__ inline float fp8_1(unsigned b) {            // scalar decode (fallback)
    unsigned s = (b & 0x80u) << 24;
    unsigned em = b & 0x7fu;
    union { unsigned u; float f; } n;
    n.u = (((em >> 3) + 120u) << 23) | ((em & 7u) << 20);
    float mag = (em >= 8u) ? n.f : (float)em * 0.001953125f;
    union { unsigned u; float f; } r; r.f = mag; r.u |= s;
    return r.f;
}

static __device__ __forceinline__ f32x2 fp8lo(unsigned v) {   // bytes 0,1
#if __has_builtin(__builtin_amdgcn_cvt_pk_f32_fp8)
    return __builtin_amdgcn_cvt_pk_f32_fp8((int)v, false);
#else
    f32x2 r; r[0] = fp8_1(v & 0xff); r[1] = fp8_1((v >> 8) & 0xff); return r;
#endif
}
static __device__ __forceinline__ f32x2 fp8hi(unsigned v) {   // bytes 2,3
#if __has_builtin(__builtin_amdgcn_cvt_pk_f32_fp8)
    return __builtin_amdgcn_cvt_pk_f32_fp8((int)v, true);
#else
    f32x2 r; r[0] = fp8_1((v >> 16) & 0xff); r[1] = fp8_1(v >> 24); return r;
#endif
}

// ---------------- graph build (CSR by dst, self-loops folded in) ----------------

// XCD-windowed count: window = blockIdx.x & 7 -> each XCD's deg slice (~50 KB)
// stays in its own L2 instead of 64 B lines bouncing across 8 incoherent L2s.
__global__ __launch_bounds__(256) void k_count_deg_win(const int* __restrict__ dst, int E,
        int* __restrict__ deg, int wsize) {
    int win   = blockIdx.x & 7;
    int chunk = blockIdx.x >> 3;
    int lo = win * wsize, hi = lo + wsize;
    int base = (chunk * 256 + threadIdx.x) * 4;
    if (base + 3 < E) {
        int4 d = *(const int4*)(dst + base);
        if (d.x >= lo && d.x < hi) atomicAdd(&deg[d.x], 1);
        if (d.y >= lo && d.y < hi) atomicAdd(&deg[d.y], 1);
        if (d.z >= lo && d.z < hi) atomicAdd(&deg[d.z], 1);
        if (d.w >= lo && d.w < hi) atomicAdd(&deg[d.w], 1);
    } else {
        for (int k = 0; k < 4; k++) {
            int e = base + k;
            if (e < E) { int d = dst[e]; if (d >= lo && d < hi) atomicAdd(&deg[d], 1); }
        }
    }
}

__global__ void k_scan_partial(const int* __restrict__ deg, int n, int* __restrict__ partial) {
    __shared__ int sd[256];
    int base = blockIdx.x * 1024;
    int sum = 0;
    for (int i = threadIdx.x; i < 1024; i += 256) {
        int idx = base + i;
        if (idx < n) sum += deg[idx] + 1;          // +1: self loop
    }
    sd[threadIdx.x] = sum;
    __syncthreads();
    for (int s = 128; s > 0; s >>= 1) {
        if (threadIdx.x < s) sd[threadIdx.x] += sd[threadIdx.x + s];
        __syncthreads();
    }
    if (threadIdx.x == 0) partial[blockIdx.x] = sd[0];
}

__global__ void k_scan_top(int* __restrict__ partial, int nb, int* __restrict__ offs, int n) {
    if (blockIdx.x == 0 && threadIdx.x == 0) {
        int run = 0;
        for (int i = 0; i < nb; i++) { int v = partial[i]; partial[i] = run; run += v; }
        offs[n] = run;   // == E + N
    }
}

// scan + fused: offs, cursor init, self-loop slot, dinv
__global__ void k_scan_final(const int* __restrict__ deg, int n,
                             const int* __restrict__ partial, int* __restrict__ offs,
                             int* __restrict__ cursor, int* __restrict__ csr,
                             float* __restrict__ dinv) {
    __shared__ int sd[256];
    int tid = threadIdx.x;
    int base = blockIdx.x * 1024;
    int v[4]; int s0 = 0;
    #pragma unroll
    for (int j = 0; j < 4; j++) {
        int idx = base + tid*4 + j;
        v[j] = (idx < n) ? (deg[idx] + 1) : 0;
        s0 += v[j];
    }
    sd[tid] = s0;
    __syncthreads();
    for (int st = 1; st < 256; st <<= 1) {
        int t = (tid >= st) ? sd[tid - st] : 0;
        __syncthreads();
        sd[tid] += t;
        __syncthreads();
    }
    int ex = (tid > 0 ? sd[tid - 1] : 0) + partial[blockIdx.x];
    #pragma unroll
    for (int j = 0; j < 4; j++) {
        int idx = base + tid*4 + j;
        if (idx < n) {
            offs[idx]   = ex;
            cursor[idx] = ex;
            dinv[idx]   = rsqrtf((float)v[j]);
            csr[ex + v[j] - 1] = idx;          // self slot (fill never touches it)
        }
        ex += v[j];
    }
}

// XCD-pinned windowed fill (round-7 win). New: skip the src int4 load when
// no lane of the quad matches the window (58% of quads).
__global__ __launch_bounds__(256) void k_fill_csr_win(const int* __restrict__ src,
        const int* __restrict__ dst, int E,
        int* __restrict__ cursor, int* __restrict__ csr, int wsize) {
    int win   = blockIdx.x & 7;
    int chunk = blockIdx.x >> 3;
    int lo = win * wsize, hi = lo + wsize;
    int base = (chunk * 256 + threadIdx.x) * 4;
    if (base + 3 < E) {
        int4 d = *(const int4*)(dst + base);
        bool ix = d.x >= lo && d.x < hi, iy = d.y >= lo && d.y < hi;
        bool iz = d.z >= lo && d.z < hi, iw = d.w >= lo && d.w < hi;
        if (ix | iy | iz | iw) {
            int4 s = *(const int4*)(src + base);
            if (ix) { int p = atomicAdd(&cursor[d.x], 1); csr[p] = s.x; }
            if (iy) { int p = atomicAdd(&cursor[d.y], 1); csr[p] = s.y; }
            if (iz) { int p = atomicAdd(&cursor[d.z], 1); csr[p] = s.z; }
            if (iw) { int p = atomicAdd(&cursor[d.w], 1); csr[p] = s.w; }
        }
    } else {
        for (int k = 0; k < 4; k++) {
            int e = base + k;
            if (e < E) {
                int d = dst[e];
                if (d >= lo && d < hi) { int p = atomicAdd(&cursor[d], 1); csr[p] = src[e]; }
            }
        }
    }
}

// ---------------- weight transpose+cast: W[k][c] fp32 -> Bt[c][k] bf16 ----------------

__global__ void k_prep_wt(const float* __restrict__ W, unsigned short* __restrict__ Bt,
                          int K, int C) {
    int t = blockIdx.x * 256 + threadIdx.x;
    if (t < K * C) { int k = t / C, c = t % C; Bt[c * K + k] = f2bf(W[t]); }
}

// ---------------- GEMM1: fp8 hpre + fused att-dots, via bf16 MFMA ----------------
// BM=128, BN=256 (full width), BK=32, 512 thr / 8 waves, wave tile 32x128.
__global__ __launch_bounds__(512) void k_gemm1_mfma(const float* __restrict__ A,
        const unsigned short* __restrict__ Bt, const float* __restrict__ att_s_g,
        const float* __restrict__ att_d_g, unsigned char* __restrict__ C,
        float* __restrict__ out_as, float* __restrict__ out_ad, int M) {
    constexpr int LDP = 40;                    // 80 B row: 2-way bank alias only (free)
    __shared__ __align__(16) unsigned short As[128 * LDP];
    __shared__ __align__(16) unsigned short Bs[256 * LDP];
    __shared__ float att_l[512];               // [0:256) att_s, [256:512) att_d (flat col)
    int tid = threadIdx.x;
    int bm = blockIdx.x * 128;
    int wave = tid >> 6, lane = tid & 63;
    int wr = wave >> 1, wc = wave & 1;
    int lg = lane >> 4, lr = lane & 15;

    att_l[tid] = (tid < 256) ? att_s_g[tid] : att_d_g[tid - 256];

    f32x4 acc[2][8] = {};

    for (int k0 = 0; k0 < 256; k0 += 32) {
        __syncthreads();
        {   // stage A: fp32 -> bf16
            int row = tid >> 2, part = tid & 3;
            int gr = bm + row;
            float4 v0, v1;
            if (gr < M) {
                const float4* p = (const float4*)(A + (size_t)gr * 256 + k0 + part * 8);
                v0 = p[0]; v1 = p[1];
            } else {
                v0 = make_float4(0.f,0.f,0.f,0.f); v1 = v0;
            }
            unsigned short* w = &As[row * LDP + part * 8];
            w[0]=f2bf(v0.x); w[1]=f2bf(v0.y); w[2]=f2bf(v0.z); w[3]=f2bf(v0.w);
            w[4]=f2bf(v1.x); w[5]=f2bf(v1.y); w[6]=f2bf(v1.z); w[7]=f2bf(v1.w);
        }
        {   // stage B
            int col = tid >> 1, part = tid & 1;
            const uint4* p = (const uint4*)(Bt + (size_t)col * 256 + k0 + part * 16);
            uint4 u0 = p[0], u1 = p[1];
            *(uint4*)&Bs[col * LDP + part * 16]     = u0;
            *(uint4*)&Bs[col * LDP + part * 16 + 8] = u1;
        }
        __syncthreads();
        short8_t a[2], b[8];
        #pragma unroll
        for (int i = 0; i < 2; i++)
            a[i] = *(const short8_t*)&As[(wr * 32 + i * 16 + lr) * LDP + lg * 8];
        #pragma unroll
        for (int j = 0; j < 8; j++)
            b[j] = *(const short8_t*)&Bs[(wc * 128 + j * 16 + lr) * LDP + lg * 8];
        #pragma unroll
        for (int i = 0; i < 2; i++)
            #pragma unroll
            for (int j = 0; j < 8; j++)
                acc[i][j] = __builtin_amdgcn_mfma_f32_16x16x32_bf16(a[i], b[j], acc[i][j], 0, 0, 0);
    }
    float ws[8], wd[8];
    #pragma unroll
    for (int j = 0; j < 8; j++) {
        int c = wc * 128 + j * 16 + lr;
        ws[j] = att_l[c]; wd[j] = att_l[256 + c];
    }
    #pragma unroll
    for (int i = 0; i < 2; i++) {
        #pragma unroll
        for (int b2 = 0; b2 < 4; b2++) {
            int row = bm + wr * 32 + i * 16 + lg * 4 + b2;
            #pragma unroll
            for (int j = 0; j < 8; j++) {
                int col = wc * 128 + j * 16 + lr;
                if (row < M) C[(size_t)row * 256 + col] = f2fp8(acc[i][j][b2]);
            }
            float s0=0.f, s1=0.f, d0=0.f, d1=0.f;
            #pragma unroll
            for (int j = 0; j < 4; j++) { float v = acc[i][j][b2];   s0 += v*ws[j];   d0 += v*wd[j]; }
            #pragma unroll
            for (int j = 4; j < 8; j++) { float v = acc[i][j][b2];   s1 += v*ws[j];   d1 += v*wd[j]; }
            #pragma unroll
            for (int off = 1; off < 16; off <<= 1) {
                s0 += __shfl_xor(s0, off); s1 += __shfl_xor(s1, off);
                d0 += __shfl_xor(d0, off); d1 += __shfl_xor(d1, off);
            }
            if (lr == 0 && row < M) {
                out_as[row * 4 + wc * 2]     = s0;
                out_as[row * 4 + wc * 2 + 1] = s1;
                out_ad[row * 4 + wc * 2]     = d0;
                out_ad[row * 4 + wc * 2 + 1] = d1;
            }
        }
    }
}

// ---------------- K=64 MFMA GEMM: C_fp8[M,NC] = A_fp32[M,64] @ Bt_bf16[NC][64] ----------------
// BM=64 (4 waves x 16 rows), BN=NC full width, single LDS stage, 2 K-steps.
// ATT (NC=128, heads=2): fused a_s/a_d epilogue via 16-lane shfl reduce.

template<int NC, bool ATT>
__global__ __launch_bounds__(256) void k_gemm_k64_mfma(const float* __restrict__ A,
        const unsigned short* __restrict__ Bt,
        const float* __restrict__ att_s_g, const float* __restrict__ att_d_g,
        unsigned char* __restrict__ C, float* __restrict__ out_as,
        float* __restrict__ out_ad, int M) {
    constexpr int NF  = NC / 16;               // col frags per wave (8 or 2)
    constexpr int LDP = 72;                    // 64 bf16 + 8 pad (144 B, 16B-aligned)
    __shared__ __align__(16) unsigned short As[64 * LDP];
    __shared__ __align__(16) unsigned short Bs[NC * LDP];
    __shared__ float att_l[ATT ? 2 * NC : 1];
    int tid = threadIdx.x;
    int bm = blockIdx.x * 64;
    int wave = tid >> 6, lane = tid & 63, lg = lane >> 4, lr = lane & 15;

    if constexpr (ATT) {
        if (tid < 2 * NC)
            att_l[tid] = (tid < NC) ? att_s_g[tid] : att_d_g[tid - NC];
    }
    {   // stage A: 64 rows x 64 k fp32 -> bf16 (16 values/thread)
        int row = tid >> 2, part = tid & 3;
        int gr = bm + row;
        float4 v0, v1, v2, v3;
        if (gr < M) {
            const float4* p = (const float4*)(A + (size_t)gr * 64 + part * 16);
            v0 = p[0]; v1 = p[1]; v2 = p[2]; v3 = p[3];
        } else {
            v0 = make_float4(0.f,0.f,0.f,0.f); v1 = v0; v2 = v0; v3 = v0;
        }
        unsigned short* w = &As[row * LDP + part * 16];
        w[0]=f2bf(v0.x);  w[1]=f2bf(v0.y);  w[2]=f2bf(v0.z);  w[3]=f2bf(v0.w);
        w[4]=f2bf(v1.x);  w[5]=f2bf(v1.y);  w[6]=f2bf(v1.z);  w[7]=f2bf(v1.w);
        w[8]=f2bf(v2.x);  w[9]=f2bf(v2.y);  w[10]=f2bf(v2.z); w[11]=f2bf(v2.w);
        w[12]=f2bf(v3.x); w[13]=f2bf(v3.y); w[14]=f2bf(v3.z); w[15]=f2bf(v3.w);
    }
    // stage B: NC cols x 64 k bf16 copy (uint4 = 8 bf16)
    for (int i = tid; i < NC * 8; i += 256) {
        int c = i >> 3, part = i & 7;
        *(uint4*)&Bs[c * LDP + part * 8] = *(const uint4*)(Bt + (size_t)c * 64 + part * 8);
    }
    __syncthreads();

    f32x4 acc[NF] = {};
    short8_t a0 = *(const short8_t*)&As[(wave * 16 + lr) * LDP + lg * 8];
    short8_t a1 = *(const short8_t*)&As[(wave * 16 + lr) * LDP + 32 + lg * 8];
    #pragma unroll
    for (int j = 0; j < NF; j++) {
        short8_t b0 = *(const short8_t*)&Bs[(j * 16 + lr) * LDP + lg * 8];
        short8_t b1 = *(const short8_t*)&Bs[(j * 16 + lr) * LDP + 32 + lg * 8];
        acc[j] = __builtin_amdgcn_mfma_f32_16x16x32_bf16(a0, b0, acc[j], 0, 0, 0);
        acc[j] = __builtin_amdgcn_mfma_f32_16x16x32_bf16(a1, b1, acc[j], 0, 0, 0);
    }
    float ws[NF], wd[NF];
    if constexpr (ATT) {
        #pragma unroll
        for (int j = 0; j < NF; j++) { ws[j] = att_l[j * 16 + lr]; wd[j] = att_l[NC + j * 16 + lr]; }
    }
    #pragma unroll
    for (int b2 = 0; b2 < 4; b2++) {
        int row = bm + wave * 16 + lg * 4 + b2;
        #pragma unroll
        for (int j = 0; j < NF; j++)
            if (row < M) C[(size_t)row * NC + j * 16 + lr] = f2fp8(acc[j][b2]);
        if constexpr (ATT) {   // heads = 2: j 0..3 head0, j 4..7 head1
            float s0=0.f, s1=0.f, d0=0.f, d1=0.f;
            #pragma unroll
            for (int j = 0; j < 4; j++) { float v = acc[j][b2]; s0 += v*ws[j]; d0 += v*wd[j]; }
            #pragma unroll
            for (int j = 4; j < 8; j++) { float v = acc[j][b2]; s1 += v*ws[j]; d1 += v*wd[j]; }
            #pragma unroll
            for (int off = 1; off < 16; off <<= 1) {
                s0 += __shfl_xor(s0, off); s1 += __shfl_xor(s1, off);
                d0 += __shfl_xor(d0, off); d1 += __shfl_xor(d1, off);
            }
            if (lr == 0 && row < M) {
                out_as[row * 2]     = s0;
                out_as[row * 2 + 1] = s1;
                out_ad[row * 2]     = d0;
                out_ad[row * 2 + 1] = d1;
            }
        }
    }
}

// ---------------- fused GAT aggregate (fp8 gather, multi-edge per iteration) ----------------
// One wave per node. Phase 1 (lanes over edges): p = exp(leaky(a_s[src]+a_d[n]))
// once per edge-head -> LDS. Phase 2: lane = (eo, h, dq8); each lane loads uint2
// (8 fp8) so EPI edges are processed per iteration (EPI=2 for H=4, 4 for H=2) ->
// per-edge LDS/address/sumh overhead divided by EPI (round-7: VALUBusy 62%).

template<int HEADS>
__global__ __launch_bounds__(256) void k_gat_fused(const unsigned char* __restrict__ hpre,
        const float* __restrict__ as_n, const float* __restrict__ ad_n,
        const float* __restrict__ bias,
        const int* __restrict__ offs, const int* __restrict__ csr,
        float* __restrict__ out, int n_nodes) {
    __shared__ int   s_src[4][64];
    __shared__ float s_p[4][64 * HEADS];
    int wif  = threadIdx.x >> 6;
    int lane = threadIdx.x & 63;
    int n = blockIdx.x * 4 + wif;
    if (n >= n_nodes) return;
    const int beg = offs[n];
    const int deg = offs[n + 1] - beg;

    constexpr int EPI = (HEADS == 4) ? 2 : 4;
    int eo, h;
    if constexpr (HEADS == 4) { eo = lane >> 5; h = (lane >> 3) & 3; }
    else                      { eo = lane >> 4; h = (lane >> 3) & 1; }
    int dq8 = lane & 7;

    float adv[HEADS];
    if constexpr (HEADS == 4) {
        float4 t = *(const float4*)(ad_n + (size_t)n * 4);
        adv[0]=t.x; adv[1]=t.y; adv[2]=t.z; adv[3]=t.w;
    } else {
        float2 t = *(const float2*)(ad_n + (size_t)n * 2);
        adv[0]=t.x; adv[1]=t.y;
    }

    float sumh = 0.f;
    float acc[8] = {};

    for (int j0 = 0; j0 < deg; j0 += 64) {
        int j = j0 + lane;
        int cnt = min(64, deg - j0);
        if (j < deg) {
            int s = csr[beg + j];
            s_src[wif][lane] = s;
            float ev[HEADS];
            if constexpr (HEADS == 4) {
                float4 t = *(const float4*)(as_n + (size_t)s * 4);
                ev[0]=t.x; ev[1]=t.y; ev[2]=t.z; ev[3]=t.w;
            } else {
                float2 t = *(const float2*)(as_n + (size_t)s * 2);
                ev[0]=t.x; ev[1]=t.y;
            }
            #pragma unroll
            for (int hh = 0; hh < HEADS; hh++) {
                float e = ev[hh] + adv[hh];
                e = fmaxf(e, 0.2f * e);
                s_p[wif][lane * HEADS + hh] = __expf(e);
            }
        }
        #pragma unroll 2
        for (int q = 0; q < cnt; q += EPI) {
            int qe = q + eo;
            if (qe < cnt) {
                int s = s_src[wif][qe];
                float p = s_p[wif][qe * HEADS + h];
                sumh += p;
                uint2 v = *(const uint2*)(hpre + (size_t)s * (HEADS * 64) + h * 64 + dq8 * 8);
                f32x2 c0 = fp8lo(v.x), c1 = fp8hi(v.x), c2 = fp8lo(v.y), c3 = fp8hi(v.y);
                acc[0] += p * c0[0]; acc[1] += p * c0[1];
                acc[2] += p * c1[0]; acc[3] += p * c1[1];
                acc[4] += p * c2[0]; acc[5] += p * c2[1];
                acc[6] += p * c3[0]; acc[7] += p * c3[1];
            }
        }
    }
    // combine over edge-slots (eo bits)
    if constexpr (HEADS == 4) {
        sumh += __shfl_xor(sumh, 32);
        #pragma unroll
        for (int i = 0; i < 8; i++) acc[i] += __shfl_xor(acc[i], 32);
    } else {
        sumh += __shfl_xor(sumh, 16); sumh += __shfl_xor(sumh, 32);
        #pragma unroll
        for (int i = 0; i < 8; i++) {
            acc[i] += __shfl_xor(acc[i], 16); acc[i] += __shfl_xor(acc[i], 32);
        }
    }
    float inv = 1.0f / (sumh + 1e-16f);
    float r[8];
    #pragma unroll
    for (int i = 0; i < 8; i++) r[i] = acc[i] * inv;
    // combine over heads + mean
    if constexpr (HEADS == 4) {
        #pragma unroll
        for (int i = 0; i < 8; i++) {
            r[i] += __shfl_xor(r[i], 8); r[i] += __shfl_xor(r[i], 16); r[i] *= 0.25f;
        }
    } else {
        #pragma unroll
        for (int i = 0; i < 8; i++) { r[i] += __shfl_xor(r[i], 8); r[i] *= 0.5f; }
    }
    if (lane < 8) {            // eo==0 && h==0
        float4 b0 = *(const float4*)(bias + dq8 * 8);
        float4 b1 = *(const float4*)(bias + dq8 * 8 + 4);
        float4 o0, o1;
        o0.x = fmaxf(r[0] + b0.x, 0.f); o0.y = fmaxf(r[1] + b0.y, 0.f);
        o0.z = fmaxf(r[2] + b0.z, 0.f); o0.w = fmaxf(r[3] + b0.w, 0.f);
        o1.x = fmaxf(r[4] + b1.x, 0.f); o1.y = fmaxf(r[5] + b1.y, 0.f);
        o1.z = fmaxf(r[6] + b1.z, 0.f); o1.w = fmaxf(r[7] + b1.w, 0.f);
        *(float4*)(out + (size_t)n * 64 + dq8 * 8)     = o0;
        *(float4*)(out + (size_t)n * 64 + dq8 * 8 + 4) = o1;
    }
}

// ---------------- GCN aggregate: 8 lanes per node, fp8 gather ----------------

__global__ __launch_bounds__(256) void k_gcn_agg(const unsigned char* __restrict__ hpre,
        const float* __restrict__ dinv, const float* __restrict__ bias,
        const int* __restrict__ offs, const int* __restrict__ csr,
        float* __restrict__ out, int n_nodes) {
    int gid = blockIdx.x * 256 + threadIdx.x;
    int n = gid >> 3, q = gid & 7;
    if (n >= n_nodes) return;
    const int beg = offs[n], end = offs[n + 1];
    float4 acc = make_float4(0.f,0.f,0.f,0.f);
    #pragma unroll 4
    for (int j = beg; j < end; j++) {
        int s = csr[j];
        float ds = dinv[s];
        unsigned v = *(const unsigned*)(hpre + (size_t)s * 32 + q * 4);
        f32x2 l = fp8lo(v), h2 = fp8hi(v);
        acc.x += ds * l[0]; acc.y += ds * l[1];
        acc.z += ds * h2[0]; acc.w += ds * h2[1];
    }
    float dn = dinv[n];
    float4 b = *(const float4*)(bias + q * 4);
    float4 o;
    o.x = fmaxf(acc.x * dn + b.x, 0.f); o.y = fmaxf(acc.y * dn + b.y, 0.f);
    o.z = fmaxf(acc.z * dn + b.z, 0.f); o.w = fmaxf(acc.w * dn + b.w, 0.f);
    *(float4*)(out + (size_t)n * 32 + q * 4) = o;
}

// ---------------- MLP head + sigmoid ----------------

__global__ __launch_bounds__(256) void k_mlp(const float* __restrict__ h3,
        const float* __restrict__ Wh1, const float* __restrict__ bh1,
        const float* __restrict__ Wh2, const float* __restrict__ bh2,
        float* __restrict__ out, int n_nodes) {
    __shared__ float w1[512];
    __shared__ float w2[16];
    __shared__ float b1s[16];
    __shared__ float b2s;
    int tid = threadIdx.x;
    for (int i = tid; i < 512; i += 256) w1[i] = Wh1[i];
    if (tid < 16) { w2[tid] = Wh2[tid]; b1s[tid] = bh1[tid]; }
    if (tid == 0) b2s = bh2[0];
    __syncthreads();
    int n = blockIdx.x * 256 + tid;
    if (n >= n_nodes) return;
    float x[32];
    const float4* p = (const float4*)(h3 + (size_t)n * 32);
    #pragma unroll
    for (int q = 0; q < 8; q++) { float4 v = p[q]; x[4*q] = v.x; x[4*q+1] = v.y; x[4*q+2] = v.z; x[4*q+3] = v.w; }
    float acc2 = b2s;
    #pragma unroll
    for (int j = 0; j < 16; j++) {
        float z = b1s[j];
        #pragma unroll
        for (int k = 0; k < 32; k++) z += x[k] * w1[k * 16 + j];
        z = fmaxf(z, 0.f);
        acc2 += z * w2[j];
    }
    out[n] = 1.0f / (1.0f + expf(-acc2));
}

// ---------------- launch ----------------

extern "C" void kernel_launch(void* const* d_in, const int* in_sizes, int n_in,
                              void* d_out, int out_size, void* d_ws, size_t ws_size,
                              hipStream_t stream) {
    const float* x   = (const float*)d_in[0];
    const int*   ei  = (const int*)d_in[1];
    const float* W1  = (const float*)d_in[2];
    const float* a1s = (const float*)d_in[3];
    const float* a1d = (const float*)d_in[4];
    const float* b1  = (const float*)d_in[5];
    const float* W2  = (const float*)d_in[6];
    const float* a2s = (const float*)d_in[7];
    const float* a2d = (const float*)d_in[8];
    const float* b2  = (const float*)d_in[9];
    const float* Wg  = (const float*)d_in[10];
    const float* bg  = (const float*)d_in[11];
    const float* Wh1 = (const float*)d_in[12];
    const float* bh1 = (const float*)d_in[13];
    const float* Wh2 = (const float*)d_in[14];
    const float* bh2 = (const float*)d_in[15];

    const int N = in_sizes[0] / 256;
    const int E = in_sizes[1] / 2;
    const int* srcs = ei;
    const int* dsts = ei + E;

    // workspace layout
    float* R0   = (float*)d_ws;              // N*256 fp32 region; reused as fp8 hpre
    float* R1   = R0 + (size_t)N * 256;      // N*64  : h1 / h3 (fp32)
    float* R2   = R1 + (size_t)N * 64;       // N*64  : h2 (fp32)
    float* As_  = R2 + (size_t)N * 64;       // N*4
    float* Ad_  = As_ + (size_t)N * 4;       // N*4
    float* dinv = Ad_ + (size_t)N * 4;       // N
    int* deg    = (int*)(dinv + N);          // N
    int* offs   = deg + N;                   // N+1
    int* cursor = offs + (N + 1);            // N
    int* csr    = cursor + N;                // E + N
    int* parts  = csr + (E + N);             // <=256
    unsigned short* W1t = (unsigned short*)(parts + 256);   // 256*256 bf16
    unsigned short* W2t = W1t + 65536;                      // 128*64 bf16
    unsigned short* Wgt = W2t + 8192;                       // 32*64 bf16
    unsigned char*  HP  = (unsigned char*)R0;               // fp8 h1pre/h2pre/h3pre

    // ---- CSR build (with self loops; XCD-windowed atomics) ----
    int wsize = cdiv(N, 8);
    hipMemsetAsync(deg, 0, (size_t)N * sizeof(int), stream);
    k_count_deg_win<<<cdiv(E, 1024) * 8, 256, 0, stream>>>(dsts, E, deg, wsize);
    int nch = cdiv(N, 1024);
    k_scan_partial<<<nch, 256, 0, stream>>>(deg, N, parts);
    k_scan_top<<<1, 64, 0, stream>>>(parts, nch, offs, N);
    k_scan_final<<<nch, 256, 0, stream>>>(deg, N, parts, offs, cursor, csr, dinv);
    k_fill_csr_win<<<cdiv(E, 1024) * 8, 256, 0, stream>>>(srcs, dsts, E, cursor, csr, wsize);

    // ---- weight preps (tiny) ----
    k_prep_wt<<<256, 256, 0, stream>>>(W1, W1t, 256, 256);
    k_prep_wt<<<32, 256, 0, stream>>>(W2, W2t, 64, 128);
    k_prep_wt<<<8, 256, 0, stream>>>(Wg, Wgt, 64, 32);

    // ---- GAT layer 1 (heads=4): MFMA GEMM w/ fused att-dots -> fp8 hpre ----
    k_gemm1_mfma<<<cdiv(N, 128), 512, 0, stream>>>(x, W1t, a1s, a1d, HP, As_, Ad_, N);
    k_gat_fused<4><<<cdiv(N, 4), 256, 0, stream>>>(HP, As_, Ad_, b1, offs, csr, R1, N);

    // ---- GAT layer 2 (heads=2): MFMA GEMM w/ fused att-dots -> fp8 hpre ----
    k_gemm_k64_mfma<128, true><<<cdiv(N, 64), 256, 0, stream>>>(R1, W2t, a2s, a2d, HP, As_, Ad_, N);
    k_gat_fused<2><<<cdiv(N, 4), 256, 0, stream>>>(HP, As_, Ad_, b2, offs, csr, R2, N);

    // ---- GCN ----
    k_gemm_k64_mfma<32, false><<<cdiv(N, 64), 256, 0, stream>>>(R2, Wgt, nullptr, nullptr, HP, nullptr, nullptr, N);
    k_gcn_agg<<<cdiv(N * 8, 256), 256, 0, stream>>>(HP, dinv, bg, offs, csr, R1, N);

    // ---- MLP head ----
    k_mlp<<<cdiv(N, 256), 256, 0, stream>>>(R1, Wh1, bh1, Wh2, bh2, (float*)d_out, N);
}

// Round 9
// 404.731 us; speedup vs baseline: 6.4742x; 1.0530x over previous
//
#include <hip/hip_runtime.h>
#include <math.h>

static inline int cdiv(int a, int b){ return (a + b - 1) / b; }

typedef __attribute__((ext_vector_type(8))) short short8_t;   // 8 bf16 (4 VGPRs)
typedef __attribute__((ext_vector_type(4))) float f32x4;      // MFMA acc
typedef __attribute__((ext_vector_type(2))) float f32x2;

static __device__ inline unsigned short f2bf(float f) {       // fp32 -> bf16 RTNE
    union { float f; unsigned u; } v; v.f = f;
    unsigned r = v.u + 0x7fff + ((v.u >> 16) & 1);
    return (unsigned short)(r >> 16);
}

// ---- fp8 e4m3fn (OCP) helpers ----
static __device__ inline unsigned char f2fp8(float f) {       // RTNE, saturating
    union { float f; unsigned u; } v; v.f = f;
    unsigned s = (v.u >> 24) & 0x80u;
    v.u &= 0x7fffffffu;
    v.f = fminf(v.f, 448.f);
    unsigned out;
    if (v.u >= (121u << 23)) {                 // |x| >= 2^-6 : normal
        unsigned u = v.u + 0x7FFFFu + ((v.u >> 20) & 1u);
        out = (((u >> 23) - 120u) << 3) | ((u >> 20) & 7u);
    } else {                                   // denormal: round(x * 2^9)
        out = (unsigned)(v.f * 512.f + 0.5f);
    }
    return (unsigned char)(out | s);
}

static __device__ inline float fp8_1(unsigned b) {            // scalar decode (fallback)
    unsigned s = (b & 0x80u) << 24;
    unsigned em = b & 0x7fu;
    union { unsigned u; float f; } n;
    n.u = (((em >> 3) + 120u) << 23) | ((em & 7u) << 20);
    float mag = (em >= 8u) ? n.f : (float)em * 0.001953125f;
    union { unsigned u; float f; } r; r.f = mag; r.u |= s;
    return r.f;
}

static __device__ __forceinline__ f32x2 fp8lo(unsigned v) {   // bytes 0,1
#if __has_builtin(__builtin_amdgcn_cvt_pk_f32_fp8)
    return __builtin_amdgcn_cvt_pk_f32_fp8((int)v, false);
#else
    f32x2 r; r[0] = fp8_1(v & 0xff); r[1] = fp8_1((v >> 8) & 0xff); return r;
#endif
}
static __device__ __forceinline__ f32x2 fp8hi(unsigned v) {   // bytes 2,3
#if __has_builtin(__builtin_amdgcn_cvt_pk_f32_fp8)
    return __builtin_amdgcn_cvt_pk_f32_fp8((int)v, true);
#else
    f32x2 r; r[0] = fp8_1((v >> 16) & 0xff); r[1] = fp8_1(v >> 24); return r;
#endif
}

// ---------------- graph build (CSR by dst, self-loops folded in) ----------------

// XCD-windowed count: window = blockIdx.x & 7 -> deg slice L2-resident per XCD.
__global__ __launch_bounds__(256) void k_count_deg_win(const int* __restrict__ dst, int E,
        int* __restrict__ deg, int wsize) {
    int win   = blockIdx.x & 7;
    int chunk = blockIdx.x >> 3;
    int lo = win * wsize, hi = lo + wsize;
    int base = (chunk * 256 + threadIdx.x) * 4;
    if (base + 3 < E) {
        int4 d = *(const int4*)(dst + base);
        if (d.x >= lo && d.x < hi) atomicAdd(&deg[d.x], 1);
        if (d.y >= lo && d.y < hi) atomicAdd(&deg[d.y], 1);
        if (d.z >= lo && d.z < hi) atomicAdd(&deg[d.z], 1);
        if (d.w >= lo && d.w < hi) atomicAdd(&deg[d.w], 1);
    } else {
        for (int k = 0; k < 4; k++) {
            int e = base + k;
            if (e < E) { int d = dst[e]; if (d >= lo && d < hi) atomicAdd(&deg[d], 1); }
        }
    }
}

__global__ void k_scan_partial(const int* __restrict__ deg, int n, int* __restrict__ partial) {
    __shared__ int sd[256];
    int base = blockIdx.x * 1024;
    int sum = 0;
    for (int i = threadIdx.x; i < 1024; i += 256) {
        int idx = base + i;
        if (idx < n) sum += deg[idx] + 1;          // +1: self loop
    }
    sd[threadIdx.x] = sum;
    __syncthreads();
    for (int s = 128; s > 0; s >>= 1) {
        if (threadIdx.x < s) sd[threadIdx.x] += sd[threadIdx.x + s];
        __syncthreads();
    }
    if (threadIdx.x == 0) partial[blockIdx.x] = sd[0];
}

__global__ void k_scan_top(int* __restrict__ partial, int nb, int* __restrict__ offs, int n) {
    if (blockIdx.x == 0 && threadIdx.x == 0) {
        int run = 0;
        for (int i = 0; i < nb; i++) { int v = partial[i]; partial[i] = run; run += v; }
        offs[n] = run;   // == E + N
    }
}

// scan + fused: offs, cursor init, self-loop slot, dinv
__global__ void k_scan_final(const int* __restrict__ deg, int n,
                             const int* __restrict__ partial, int* __restrict__ offs,
                             int* __restrict__ cursor, int* __restrict__ csr,
                             float* __restrict__ dinv) {
    __shared__ int sd[256];
    int tid = threadIdx.x;
    int base = blockIdx.x * 1024;
    int v[4]; int s0 = 0;
    #pragma unroll
    for (int j = 0; j < 4; j++) {
        int idx = base + tid*4 + j;
        v[j] = (idx < n) ? (deg[idx] + 1) : 0;
        s0 += v[j];
    }
    sd[tid] = s0;
    __syncthreads();
    for (int st = 1; st < 256; st <<= 1) {
        int t = (tid >= st) ? sd[tid - st] : 0;
        __syncthreads();
        sd[tid] += t;
        __syncthreads();
    }
    int ex = (tid > 0 ? sd[tid - 1] : 0) + partial[blockIdx.x];
    #pragma unroll
    for (int j = 0; j < 4; j++) {
        int idx = base + tid*4 + j;
        if (idx < n) {
            offs[idx]   = ex;
            cursor[idx] = ex;
            dinv[idx]   = rsqrtf((float)v[j]);
            csr[ex + v[j] - 1] = idx;          // self slot (fill never touches it)
        }
        ex += v[j];
    }
}

// XCD-pinned windowed fill (round-7 win); skips src load when quad has no match.
__global__ __launch_bounds__(256) void k_fill_csr_win(const int* __restrict__ src,
        const int* __restrict__ dst, int E,
        int* __restrict__ cursor, int* __restrict__ csr, int wsize) {
    int win   = blockIdx.x & 7;
    int chunk = blockIdx.x >> 3;
    int lo = win * wsize, hi = lo + wsize;
    int base = (chunk * 256 + threadIdx.x) * 4;
    if (base + 3 < E) {
        int4 d = *(const int4*)(dst + base);
        bool ix = d.x >= lo && d.x < hi, iy = d.y >= lo && d.y < hi;
        bool iz = d.z >= lo && d.z < hi, iw = d.w >= lo && d.w < hi;
        if (ix | iy | iz | iw) {
            int4 s = *(const int4*)(src + base);
            if (ix) { int p = atomicAdd(&cursor[d.x], 1); csr[p] = s.x; }
            if (iy) { int p = atomicAdd(&cursor[d.y], 1); csr[p] = s.y; }
            if (iz) { int p = atomicAdd(&cursor[d.z], 1); csr[p] = s.z; }
            if (iw) { int p = atomicAdd(&cursor[d.w], 1); csr[p] = s.w; }
        }
    } else {
        for (int k = 0; k < 4; k++) {
            int e = base + k;
            if (e < E) {
                int d = dst[e];
                if (d >= lo && d < hi) { int p = atomicAdd(&cursor[d], 1); csr[p] = src[e]; }
            }
        }
    }
}

// ---------------- merged weight transpose+cast (W1, W2, Wg in one launch) ----------------
// W[k][c] fp32 -> Bt[c][k] bf16

__global__ void k_prep_all(const float* __restrict__ W1, const float* __restrict__ W2,
                           const float* __restrict__ Wg, unsigned short* __restrict__ W1t,
                           unsigned short* __restrict__ W2t, unsigned short* __restrict__ Wgt) {
    int t = blockIdx.x * 256 + threadIdx.x;
    if (t < 65536) {                                   // W1: 256x256
        int k = t >> 8, c = t & 255;
        W1t[c * 256 + k] = f2bf(W1[t]);
    }
    if (t < 8192) {                                    // W2: 64x128
        int k = t >> 7, c = t & 127;
        W2t[c * 64 + k] = f2bf(W2[t]);
    }
    if (t < 2048) {                                    // Wg: 64x32
        int k = t >> 5, c = t & 31;
        Wgt[c * 64 + k] = f2bf(Wg[t]);
    }
}

// ---------------- GEMM1: fp8 hpre + fused att-dots, via bf16 MFMA ----------------
// BM=128, BN=256 (full width), BK=32, 512 thr / 8 waves, wave tile 32x128.
__global__ __launch_bounds__(512) void k_gemm1_mfma(const float* __restrict__ A,
        const unsigned short* __restrict__ Bt, const float* __restrict__ att_s_g,
        const float* __restrict__ att_d_g, unsigned char* __restrict__ C,
        float* __restrict__ out_as, float* __restrict__ out_ad, int M) {
    constexpr int LDP = 40;                    // 80 B row: 2-way bank alias only (free)
    __shared__ __align__(16) unsigned short As[128 * LDP];
    __shared__ __align__(16) unsigned short Bs[256 * LDP];
    __shared__ float att_l[512];               // [0:256) att_s, [256:512) att_d (flat col)
    int tid = threadIdx.x;
    int bm = blockIdx.x * 128;
    int wave = tid >> 6, lane = tid & 63;
    int wr = wave >> 1, wc = wave & 1;
    int lg = lane >> 4, lr = lane & 15;

    att_l[tid] = (tid < 256) ? att_s_g[tid] : att_d_g[tid - 256];

    f32x4 acc[2][8] = {};

    for (int k0 = 0; k0 < 256; k0 += 32) {
        __syncthreads();
        {   // stage A: fp32 -> bf16
            int row = tid >> 2, part = tid & 3;
            int gr = bm + row;
            float4 v0, v1;
            if (gr < M) {
                const float4* p = (const float4*)(A + (size_t)gr * 256 + k0 + part * 8);
                v0 = p[0]; v1 = p[1];
            } else {
                v0 = make_float4(0.f,0.f,0.f,0.f); v1 = v0;
            }
            unsigned short* w = &As[row * LDP + part * 8];
            w[0]=f2bf(v0.x); w[1]=f2bf(v0.y); w[2]=f2bf(v0.z); w[3]=f2bf(v0.w);
            w[4]=f2bf(v1.x); w[5]=f2bf(v1.y); w[6]=f2bf(v1.z); w[7]=f2bf(v1.w);
        }
        {   // stage B
            int col = tid >> 1, part = tid & 1;
            const uint4* p = (const uint4*)(Bt + (size_t)col * 256 + k0 + part * 16);
            uint4 u0 = p[0], u1 = p[1];
            *(uint4*)&Bs[col * LDP + part * 16]     = u0;
            *(uint4*)&Bs[col * LDP + part * 16 + 8] = u1;
        }
        __syncthreads();
        short8_t a[2], b[8];
        #pragma unroll
        for (int i = 0; i < 2; i++)
            a[i] = *(const short8_t*)&As[(wr * 32 + i * 16 + lr) * LDP + lg * 8];
        #pragma unroll
        for (int j = 0; j < 8; j++)
            b[j] = *(const short8_t*)&Bs[(wc * 128 + j * 16 + lr) * LDP + lg * 8];
        #pragma unroll
        for (int i = 0; i < 2; i++)
            #pragma unroll
            for (int j = 0; j < 8; j++)
                acc[i][j] = __builtin_amdgcn_mfma_f32_16x16x32_bf16(a[i], b[j], acc[i][j], 0, 0, 0);
    }
    float ws[8], wd[8];
    #pragma unroll
    for (int j = 0; j < 8; j++) {
        int c = wc * 128 + j * 16 + lr;
        ws[j] = att_l[c]; wd[j] = att_l[256 + c];
    }
    #pragma unroll
    for (int i = 0; i < 2; i++) {
        #pragma unroll
        for (int b2 = 0; b2 < 4; b2++) {
            int row = bm + wr * 32 + i * 16 + lg * 4 + b2;
            #pragma unroll
            for (int j = 0; j < 8; j++) {
                int col = wc * 128 + j * 16 + lr;
                if (row < M) C[(size_t)row * 256 + col] = f2fp8(acc[i][j][b2]);
            }
            float s0=0.f, s1=0.f, d0=0.f, d1=0.f;
            #pragma unroll
            for (int j = 0; j < 4; j++) { float v = acc[i][j][b2];   s0 += v*ws[j];   d0 += v*wd[j]; }
            #pragma unroll
            for (int j = 4; j < 8; j++) { float v = acc[i][j][b2];   s1 += v*ws[j];   d1 += v*wd[j]; }
            #pragma unroll
            for (int off = 1; off < 16; off <<= 1) {
                s0 += __shfl_xor(s0, off); s1 += __shfl_xor(s1, off);
                d0 += __shfl_xor(d0, off); d1 += __shfl_xor(d1, off);
            }
            if (lr == 0 && row < M) {
                out_as[row * 4 + wc * 2]     = s0;
                out_as[row * 4 + wc * 2 + 1] = s1;
                out_ad[row * 4 + wc * 2]     = d0;
                out_ad[row * 4 + wc * 2 + 1] = d1;
            }
        }
    }
}

// ---------------- K=64 MFMA GEMM (round-8 win, kept) ----------------

template<int NC, bool ATT>
__global__ __launch_bounds__(256) void k_gemm_k64_mfma(const float* __restrict__ A,
        const unsigned short* __restrict__ Bt,
        const float* __restrict__ att_s_g, const float* __restrict__ att_d_g,
        unsigned char* __restrict__ C, float* __restrict__ out_as,
        float* __restrict__ out_ad, int M) {
    constexpr int NF  = NC / 16;               // col frags per wave (8 or 2)
    constexpr int LDP = 72;                    // 64 bf16 + 8 pad
    __shared__ __align__(16) unsigned short As[64 * LDP];
    __shared__ __align__(16) unsigned short Bs[NC * LDP];
    __shared__ float att_l[ATT ? 2 * NC : 1];
    int tid = threadIdx.x;
    int bm = blockIdx.x * 64;
    int wave = tid >> 6, lane = tid & 63, lg = lane >> 4, lr = lane & 15;

    if constexpr (ATT) {
        if (tid < 2 * NC)
            att_l[tid] = (tid < NC) ? att_s_g[tid] : att_d_g[tid - NC];
    }
    {   // stage A: 64 rows x 64 k fp32 -> bf16 (16 values/thread)
        int row = tid >> 2, part = tid & 3;
        int gr = bm + row;
        float4 v0, v1, v2, v3;
        if (gr < M) {
            const float4* p = (const float4*)(A + (size_t)gr * 64 + part * 16);
            v0 = p[0]; v1 = p[1]; v2 = p[2]; v3 = p[3];
        } else {
            v0 = make_float4(0.f,0.f,0.f,0.f); v1 = v0; v2 = v0; v3 = v0;
        }
        unsigned short* w = &As[row * LDP + part * 16];
        w[0]=f2bf(v0.x);  w[1]=f2bf(v0.y);  w[2]=f2bf(v0.z);  w[3]=f2bf(v0.w);
        w[4]=f2bf(v1.x);  w[5]=f2bf(v1.y);  w[6]=f2bf(v1.z);  w[7]=f2bf(v1.w);
        w[8]=f2bf(v2.x);  w[9]=f2bf(v2.y);  w[10]=f2bf(v2.z); w[11]=f2bf(v2.w);
        w[12]=f2bf(v3.x); w[13]=f2bf(v3.y); w[14]=f2bf(v3.z); w[15]=f2bf(v3.w);
    }
    for (int i = tid; i < NC * 8; i += 256) {
        int c = i >> 3, part = i & 7;
        *(uint4*)&Bs[c * LDP + part * 8] = *(const uint4*)(Bt + (size_t)c * 64 + part * 8);
    }
    __syncthreads();

    f32x4 acc[NF] = {};
    short8_t a0 = *(const short8_t*)&As[(wave * 16 + lr) * LDP + lg * 8];
    short8_t a1 = *(const short8_t*)&As[(wave * 16 + lr) * LDP + 32 + lg * 8];
    #pragma unroll
    for (int j = 0; j < NF; j++) {
        short8_t b0 = *(const short8_t*)&Bs[(j * 16 + lr) * LDP + lg * 8];
        short8_t b1 = *(const short8_t*)&Bs[(j * 16 + lr) * LDP + 32 + lg * 8];
        acc[j] = __builtin_amdgcn_mfma_f32_16x16x32_bf16(a0, b0, acc[j], 0, 0, 0);
        acc[j] = __builtin_amdgcn_mfma_f32_16x16x32_bf16(a1, b1, acc[j], 0, 0, 0);
    }
    float ws[NF], wd[NF];
    if constexpr (ATT) {
        #pragma unroll
        for (int j = 0; j < NF; j++) { ws[j] = att_l[j * 16 + lr]; wd[j] = att_l[NC + j * 16 + lr]; }
    }
    #pragma unroll
    for (int b2 = 0; b2 < 4; b2++) {
        int row = bm + wave * 16 + lg * 4 + b2;
        #pragma unroll
        for (int j = 0; j < NF; j++)
            if (row < M) C[(size_t)row * NC + j * 16 + lr] = f2fp8(acc[j][b2]);
        if constexpr (ATT) {   // heads = 2
            float s0=0.f, s1=0.f, d0=0.f, d1=0.f;
            #pragma unroll
            for (int j = 0; j < 4; j++) { float v = acc[j][b2]; s0 += v*ws[j]; d0 += v*wd[j]; }
            #pragma unroll
            for (int j = 4; j < 8; j++) { float v = acc[j][b2]; s1 += v*ws[j]; d1 += v*wd[j]; }
            #pragma unroll
            for (int off = 1; off < 16; off <<= 1) {
                s0 += __shfl_xor(s0, off); s1 += __shfl_xor(s1, off);
                d0 += __shfl_xor(d0, off); d1 += __shfl_xor(d1, off);
            }
            if (lr == 0 && row < M) {
                out_as[row * 2]     = s0;
                out_as[row * 2 + 1] = s1;
                out_ad[row * 2]     = d0;
                out_ad[row * 2 + 1] = d1;
            }
        }
    }
}

// ---------------- fused GAT aggregate (fp8 gather; round-7 structure) ----------------
// One wave per node, 1 edge per phase-2 iteration, 4B/lane — maximizes
// independent loads in flight (round-8 lesson: 2-edge/iter variant with a lane
// guard went latency-bound, 78->95 µs). s_src caches the row BYTE OFFSET so the
// inner loop does int add only.

template<int HEADS>
__global__ __launch_bounds__(256) void k_gat_fused(const unsigned char* __restrict__ hpre,
        const float* __restrict__ as_n, const float* __restrict__ ad_n,
        const float* __restrict__ bias,
        const int* __restrict__ offs, const int* __restrict__ csr,
        float* __restrict__ out, int n_nodes) {
    __shared__ int   s_off[4][64];
    __shared__ float s_p[4][64 * HEADS];
    int wif  = threadIdx.x >> 6;
    int lane = threadIdx.x & 63;
    int n = blockIdx.x * 4 + wif;
    if (n >= n_nodes) return;
    const int beg = offs[n];
    const int deg = offs[n + 1] - beg;

    int h_id, dq;
    if constexpr (HEADS == 4) { h_id = lane >> 4; dq = lane & 15; }
    else                      { h_id = lane >> 5; dq = lane & 31; }
    const int lane_off = h_id * 64 + dq * 4;   // byte offset within row (4 B/lane)

    float adv[HEADS];
    if constexpr (HEADS == 4) {
        float4 t = *(const float4*)(ad_n + (size_t)n * 4);
        adv[0]=t.x; adv[1]=t.y; adv[2]=t.z; adv[3]=t.w;
    } else {
        float2 t = *(const float2*)(ad_n + (size_t)n * 2);
        adv[0]=t.x; adv[1]=t.y;
    }

    float sumh = 0.f;
    float acc[HEADS] = {};

    for (int j0 = 0; j0 < deg; j0 += 64) {
        int j = j0 + lane;
        int cnt = min(64, deg - j0);
        if (j < deg) {
            int s = csr[beg + j];
            s_off[wif][lane] = s * (HEADS * 64);      // row byte offset
            float ev[HEADS];
            if constexpr (HEADS == 4) {
                float4 t = *(const float4*)(as_n + (size_t)s * 4);
                ev[0]=t.x; ev[1]=t.y; ev[2]=t.z; ev[3]=t.w;
            } else {
                float2 t = *(const float2*)(as_n + (size_t)s * 2);
                ev[0]=t.x; ev[1]=t.y;
            }
            #pragma unroll
            for (int h = 0; h < HEADS; h++) {
                float e = ev[h] + adv[h];
                e = fmaxf(e, 0.2f * e);
                s_p[wif][lane * HEADS + h] = __expf(e);
            }
        }
        #pragma unroll 4
        for (int q = 0; q < cnt; q++) {
            int off = s_off[wif][q];
            float p = s_p[wif][q * HEADS + h_id];
            sumh += p;
            if constexpr (HEADS == 4) {
                unsigned v = *(const unsigned*)(hpre + off + lane_off);
                f32x2 l = fp8lo(v), h2 = fp8hi(v);
                acc[0] += p * l[0]; acc[1] += p * l[1];
                acc[2] += p * h2[0]; acc[3] += p * h2[1];
            } else {
                unsigned v = *(const unsigned short*)(hpre + off + (lane_off >> 1));
                f32x2 l = fp8lo(v);
                acc[0] += p * l[0]; acc[1] += p * l[1];
            }
        }
    }
    float inv = 1.0f / (sumh + 1e-16f);
    float r[HEADS];
    #pragma unroll
    for (int c = 0; c < HEADS; c++) r[c] = acc[c] * inv;
    if constexpr (HEADS == 4) {
        #pragma unroll
        for (int c = 0; c < 4; c++) {
            r[c] += __shfl_xor(r[c], 16);
            r[c] += __shfl_xor(r[c], 32);
            r[c] *= 0.25f;
        }
        if (h_id == 0) {
            float4 b = *(const float4*)(bias + dq * 4);
            float4 o;
            o.x = fmaxf(r[0] + b.x, 0.f); o.y = fmaxf(r[1] + b.y, 0.f);
            o.z = fmaxf(r[2] + b.z, 0.f); o.w = fmaxf(r[3] + b.w, 0.f);
            *(float4*)(out + (size_t)n * 64 + dq * 4) = o;
        }
    } else {
        #pragma unroll
        for (int c = 0; c < 2; c++) {
            r[c] += __shfl_xor(r[c], 32);
            r[c] *= 0.5f;
        }
        if (h_id == 0) {
            float2 b = *(const float2*)(bias + dq * 2);
            float2 o;
            o.x = fmaxf(r[0] + b.x, 0.f); o.y = fmaxf(r[1] + b.y, 0.f);
            *(float2*)(out + (size_t)n * 64 + dq * 2) = o;
        }
    }
}

// ---------------- GCN aggregate: 8 lanes per node, fp8 gather ----------------

__global__ __launch_bounds__(256) void k_gcn_agg(const unsigned char* __restrict__ hpre,
        const float* __restrict__ dinv, const float* __restrict__ bias,
        const int* __restrict__ offs, const int* __restrict__ csr,
        float* __restrict__ out, int n_nodes) {
    int gid = blockIdx.x * 256 + threadIdx.x;
    int n = gid >> 3, q = gid & 7;
    if (n >= n_nodes) return;
    const int beg = offs[n], end = offs[n + 1];
    float4 acc = make_float4(0.f,0.f,0.f,0.f);
    #pragma unroll 4
    for (int j = beg; j < end; j++) {
        int s = csr[j];
        float ds = dinv[s];
        unsigned v = *(const unsigned*)(hpre + (size_t)s * 32 + q * 4);
        f32x2 l = fp8lo(v), h2 = fp8hi(v);
        acc.x += ds * l[0]; acc.y += ds * l[1];
        acc.z += ds * h2[0]; acc.w += ds * h2[1];
    }
    float dn = dinv[n];
    float4 b = *(const float4*)(bias + q * 4);
    float4 o;
    o.x = fmaxf(acc.x * dn + b.x, 0.f); o.y = fmaxf(acc.y * dn + b.y, 0.f);
    o.z = fmaxf(acc.z * dn + b.z, 0.f); o.w = fmaxf(acc.w * dn + b.w, 0.f);
    *(float4*)(out + (size_t)n * 32 + q * 4) = o;
}

// ---------------- MLP head + sigmoid ----------------

__global__ __launch_bounds__(256) void k_mlp(const float* __restrict__ h3,
        const float* __restrict__ Wh1, const float* __restrict__ bh1,
        const float* __restrict__ Wh2, const float* __restrict__ bh2,
        float* __restrict__ out, int n_nodes) {
    __shared__ float w1[512];
    __shared__ float w2[16];
    __shared__ float b1s[16];
    __shared__ float b2s;
    int tid = threadIdx.x;
    for (int i = tid; i < 512; i += 256) w1[i] = Wh1[i];
    if (tid < 16) { w2[tid] = Wh2[tid]; b1s[tid] = bh1[tid]; }
    if (tid == 0) b2s = bh2[0];
    __syncthreads();
    int n = blockIdx.x * 256 + tid;
    if (n >= n_nodes) return;
    float x[32];
    const float4* p = (const float4*)(h3 + (size_t)n * 32);
    #pragma unroll
    for (int q = 0; q < 8; q++) { float4 v = p[q]; x[4*q] = v.x; x[4*q+1] = v.y; x[4*q+2] = v.z; x[4*q+3] = v.w; }
    float acc2 = b2s;
    #pragma unroll
    for (int j = 0; j < 16; j++) {
        float z = b1s[j];
        #pragma unroll
        for (int k = 0; k < 32; k++) z += x[k] * w1[k * 16 + j];
        z = fmaxf(z, 0.f);
        acc2 += z * w2[j];
    }
    out[n] = 1.0f / (1.0f + expf(-acc2));
}

// ---------------- launch ----------------

extern "C" void kernel_launch(void* const* d_in, const int* in_sizes, int n_in,
                              void* d_out, int out_size, void* d_ws, size_t ws_size,
                              hipStream_t stream) {
    const float* x   = (const float*)d_in[0];
    const int*   ei  = (const int*)d_in[1];
    const float* W1  = (const float*)d_in[2];
    const float* a1s = (const float*)d_in[3];
    const float* a1d = (const float*)d_in[4];
    const float* b1  = (const float*)d_in[5];
    const float* W2  = (const float*)d_in[6];
    const float* a2s = (const float*)d_in[7];
    const float* a2d = (const float*)d_in[8];
    const float* b2  = (const float*)d_in[9];
    const float* Wg  = (const float*)d_in[10];
    const float* bg  = (const float*)d_in[11];
    const float* Wh1 = (const float*)d_in[12];
    const float* bh1 = (const float*)d_in[13];
    const float* Wh2 = (const float*)d_in[14];
    const float* bh2 = (const float*)d_in[15];

    const int N = in_sizes[0] / 256;
    const int E = in_sizes[1] / 2;
    const int* srcs = ei;
    const int* dsts = ei + E;

    // workspace layout
    float* R0   = (float*)d_ws;              // N*256 fp32 region; reused as fp8 hpre
    float* R1   = R0 + (size_t)N * 256;      // N*64  : h1 / h3 (fp32)
    float* R2   = R1 + (size_t)N * 64;       // N*64  : h2 (fp32)
    float* As_  = R2 + (size_t)N * 64;       // N*4
    float* Ad_  = As_ + (size_t)N * 4;       // N*4
    float* dinv = Ad_ + (size_t)N * 4;       // N
    int* deg    = (int*)(dinv + N);          // N
    int* offs   = deg + N;                   // N+1
    int* cursor = offs + (N + 1);            // N
    int* csr    = cursor + N;                // E + N
    int* parts  = csr + (E + N);             // <=256
    unsigned short* W1t = (unsigned short*)(parts + 256);   // 256*256 bf16
    unsigned short* W2t = W1t + 65536;                      // 128*64 bf16
    unsigned short* Wgt = W2t + 8192;                       // 32*64 bf16
    unsigned char*  HP  = (unsigned char*)R0;               // fp8 h1pre/h2pre/h3pre

    // ---- CSR build (with self loops; XCD-windowed atomics) ----
    int wsize = cdiv(N, 8);
    hipMemsetAsync(deg, 0, (size_t)N * sizeof(int), stream);
    k_count_deg_win<<<cdiv(E, 1024) * 8, 256, 0, stream>>>(dsts, E, deg, wsize);
    int nch = cdiv(N, 1024);
    k_scan_partial<<<nch, 256, 0, stream>>>(deg, N, parts);
    k_scan_top<<<1, 64, 0, stream>>>(parts, nch, offs, N);
    k_scan_final<<<nch, 256, 0, stream>>>(deg, N, parts, offs, cursor, csr, dinv);
    k_fill_csr_win<<<cdiv(E, 1024) * 8, 256, 0, stream>>>(srcs, dsts, E, cursor, csr, wsize);

    // ---- weight preps (single launch) ----
    k_prep_all<<<256, 256, 0, stream>>>(W1, W2, Wg, W1t, W2t, Wgt);

    // ---- GAT layer 1 (heads=4): MFMA GEMM w/ fused att-dots -> fp8 hpre ----
    k_gemm1_mfma<<<cdiv(N, 128), 512, 0, stream>>>(x, W1t, a1s, a1d, HP, As_, Ad_, N);
    k_gat_fused<4><<<cdiv(N, 4), 256, 0, stream>>>(HP, As_, Ad_, b1, offs, csr, R1, N);

    // ---- GAT layer 2 (heads=2): MFMA GEMM w/ fused att-dots -> fp8 hpre ----
    k_gemm_k64_mfma<128, true><<<cdiv(N, 64), 256, 0, stream>>>(R1, W2t, a2s, a2d, HP, As_, Ad_, N);
    k_gat_fused<2><<<cdiv(N, 4), 256, 0, stream>>>(HP, As_, Ad_, b2, offs, csr, R2, N);

    // ---- GCN ----
    k_gemm_k64_mfma<32, false><<<cdiv(N, 64), 256, 0, stream>>>(R2, Wgt, nullptr, nullptr, HP, nullptr, nullptr, N);
    k_gcn_agg<<<cdiv(N * 8, 256), 256, 0, stream>>>(HP, dinv, bg, offs, csr, R1, N);

    // ---- MLP head ----
    k_mlp<<<cdiv(N, 256), 256, 0, stream>>>(R1, Wh1, bh1, Wh2, bh2, (float*)d_out, N);
}

// Round 10
// 377.631 us; speedup vs baseline: 6.9388x; 1.0718x over previous
//
#include <hip/hip_runtime.h>
#include <math.h>

static inline int cdiv(int a, int b){ return (a + b - 1) / b; }

typedef __attribute__((ext_vector_type(8))) short short8_t;   // 8 bf16 (4 VGPRs)
typedef __attribute__((ext_vector_type(4))) float f32x4;      // MFMA acc
typedef __attribute__((ext_vector_type(2))) float f32x2;

static __device__ inline unsigned short f2bf(float f) {       // fp32 -> bf16 RTNE
    union { float f; unsigned u; } v; v.f = f;
    unsigned r = v.u + 0x7fff + ((v.u >> 16) & 1);
    return (unsigned short)(r >> 16);
}

// ---- fp8 e4m3fn (OCP) helpers ----
static __device__ inline unsigned char f2fp8(float f) {       // RTNE, saturating
    union { float f; unsigned u; } v; v.f = f;
    unsigned s = (v.u >> 24) & 0x80u;
    v.u &= 0x7fffffffu;
    v.f = fminf(v.f, 448.f);
    unsigned out;
    if (v.u >= (121u << 23)) {                 // |x| >= 2^-6 : normal
        unsigned u = v.u + 0x7FFFFu + ((v.u >> 20) & 1u);
        out = (((u >> 23) - 120u) << 3) | ((u >> 20) & 7u);
    } else {                                   // denormal: round(x * 2^9)
        out = (unsigned)(v.f * 512.f + 0.5f);
    }
    return (unsigned char)(out | s);
}

static __device__ inline float fp8_1(unsigned b) {            // scalar decode (fallback)
    unsigned s = (b & 0x80u) << 24;
    unsigned em = b & 0x7fu;
    union { unsigned u; float f; } n;
    n.u = (((em >> 3) + 120u) << 23) | ((em & 7u) << 20);
    float mag = (em >= 8u) ? n.f : (float)em * 0.001953125f;
    union { unsigned u; float f; } r; r.f = mag; r.u |= s;
    return r.f;
}

static __device__ __forceinline__ f32x2 fp8lo(unsigned v) {   // bytes 0,1
#if __has_builtin(__builtin_amdgcn_cvt_pk_f32_fp8)
    return __builtin_amdgcn_cvt_pk_f32_fp8((int)v, false);
#else
    f32x2 r; r[0] = fp8_1(v & 0xff); r[1] = fp8_1((v >> 8) & 0xff); return r;
#endif
}
static __device__ __forceinline__ f32x2 fp8hi(unsigned v) {   // bytes 2,3
#if __has_builtin(__builtin_amdgcn_cvt_pk_f32_fp8)
    return __builtin_amdgcn_cvt_pk_f32_fp8((int)v, true);
#else
    f32x2 r; r[0] = fp8_1((v >> 16) & 0xff); r[1] = fp8_1(v >> 24); return r;
#endif
}

// ---------------- graph build (CSR by dst, self-loops folded in) ----------------

// XCD-windowed count (blocks < fillBlocks) + weight transpose/cast (trailing blocks).
__global__ __launch_bounds__(256) void k_count_prep(const int* __restrict__ dst, int E,
        int* __restrict__ deg, int wsize, int fillBlocks,
        const float* __restrict__ W1, const float* __restrict__ W2,
        const float* __restrict__ Wg, unsigned short* __restrict__ W1t,
        unsigned short* __restrict__ W2t, unsigned short* __restrict__ Wgt) {
    if (blockIdx.x >= fillBlocks) {            // weight prep tail: 256 blocks
        int t = (blockIdx.x - fillBlocks) * 256 + threadIdx.x;
        if (t < 65536) { int k = t >> 8, c = t & 255; W1t[c * 256 + k] = f2bf(W1[t]); }
        if (t < 8192)  { int k = t >> 7, c = t & 127; W2t[c * 64 + k]  = f2bf(W2[t]); }
        if (t < 2048)  { int k = t >> 5, c = t & 31;  Wgt[c * 64 + k]  = f2bf(Wg[t]); }
        return;
    }
    int win   = blockIdx.x & 7;
    int chunk = blockIdx.x >> 3;
    int lo = win * wsize, hi = lo + wsize;
    int base = (chunk * 256 + threadIdx.x) * 4;
    if (base + 3 < E) {
        int4 d = *(const int4*)(dst + base);
        if (d.x >= lo && d.x < hi) atomicAdd(&deg[d.x], 1);
        if (d.y >= lo && d.y < hi) atomicAdd(&deg[d.y], 1);
        if (d.z >= lo && d.z < hi) atomicAdd(&deg[d.z], 1);
        if (d.w >= lo && d.w < hi) atomicAdd(&deg[d.w], 1);
    } else {
        for (int k = 0; k < 4; k++) {
            int e = base + k;
            if (e < E) { int d = dst[e]; if (d >= lo && d < hi) atomicAdd(&deg[d], 1); }
        }
    }
}

__global__ void k_scan_partial(const int* __restrict__ deg, int n, int* __restrict__ partial) {
    __shared__ int sd[256];
    int base = blockIdx.x * 1024;
    int sum = 0;
    for (int i = threadIdx.x; i < 1024; i += 256) {
        int idx = base + i;
        if (idx < n) sum += deg[idx] + 1;          // +1: self loop
    }
    sd[threadIdx.x] = sum;
    __syncthreads();
    for (int s = 128; s > 0; s >>= 1) {
        if (threadIdx.x < s) sd[threadIdx.x] += sd[threadIdx.x + s];
        __syncthreads();
    }
    if (threadIdx.x == 0) partial[blockIdx.x] = sd[0];
}

// scan with in-kernel lookback (partials are raw chunk sums) + fused:
// offs, cursor init, self-loop slot, dinv. Last block writes offs[n] total.
__global__ void k_scan_final(const int* __restrict__ deg, int n,
                             const int* __restrict__ partial, int* __restrict__ offs,
                             int* __restrict__ cursor, int* __restrict__ csr,
                             float* __restrict__ dinv) {
    __shared__ int sd[256];
    int tid = threadIdx.x;
    // lookback: sum of partials of preceding blocks
    int pre = 0;
    for (int i = tid; i < (int)blockIdx.x; i += 256) pre += partial[i];
    sd[tid] = pre;
    __syncthreads();
    for (int s = 128; s > 0; s >>= 1) {
        if (tid < s) sd[tid] += sd[tid + s];
        __syncthreads();
    }
    int base_pre = sd[0];
    __syncthreads();
    int base = blockIdx.x * 1024;
    int v[4]; int s0 = 0;
    #pragma unroll
    for (int j = 0; j < 4; j++) {
        int idx = base + tid*4 + j;
        v[j] = (idx < n) ? (deg[idx] + 1) : 0;
        s0 += v[j];
    }
    sd[tid] = s0;
    __syncthreads();
    for (int st = 1; st < 256; st <<= 1) {
        int t = (tid >= st) ? sd[tid - st] : 0;
        __syncthreads();
        sd[tid] += t;
        __syncthreads();
    }
    int ex = (tid > 0 ? sd[tid - 1] : 0) + base_pre;
    #pragma unroll
    for (int j = 0; j < 4; j++) {
        int idx = base + tid*4 + j;
        if (idx < n) {
            offs[idx]   = ex;
            cursor[idx] = ex;
            dinv[idx]   = rsqrtf((float)v[j]);
            csr[ex + v[j] - 1] = idx;          // self slot (fill never touches it)
        }
        ex += v[j];
    }
    if (blockIdx.x == gridDim.x - 1 && tid == 255) offs[n] = ex;   // == E + N
}

// XCD-pinned windowed fill; skips src load when quad has no match.
__global__ __launch_bounds__(256) void k_fill_csr_win(const int* __restrict__ src,
        const int* __restrict__ dst, int E,
        int* __restrict__ cursor, int* __restrict__ csr, int wsize) {
    int win   = blockIdx.x & 7;
    int chunk = blockIdx.x >> 3;
    int lo = win * wsize, hi = lo + wsize;
    int base = (chunk * 256 + threadIdx.x) * 4;
    if (base + 3 < E) {
        int4 d = *(const int4*)(dst + base);
        bool ix = d.x >= lo && d.x < hi, iy = d.y >= lo && d.y < hi;
        bool iz = d.z >= lo && d.z < hi, iw = d.w >= lo && d.w < hi;
        if (ix | iy | iz | iw) {
            int4 s = *(const int4*)(src + base);
            if (ix) { int p = atomicAdd(&cursor[d.x], 1); csr[p] = s.x; }
            if (iy) { int p = atomicAdd(&cursor[d.y], 1); csr[p] = s.y; }
            if (iz) { int p = atomicAdd(&cursor[d.z], 1); csr[p] = s.z; }
            if (iw) { int p = atomicAdd(&cursor[d.w], 1); csr[p] = s.w; }
        }
    } else {
        for (int k = 0; k < 4; k++) {
            int e = base + k;
            if (e < E) {
                int d = dst[e];
                if (d >= lo && d < hi) { int p = atomicAdd(&cursor[d], 1); csr[p] = src[e]; }
            }
        }
    }
}

// ---------------- GEMM1: fp8 hpre + fused att-dots, via bf16 MFMA ----------------
// BM=128, BN=256 (full width), BK=32, 512 thr / 8 waves, wave tile 32x128.
__global__ __launch_bounds__(512) void k_gemm1_mfma(const float* __restrict__ A,
        const unsigned short* __restrict__ Bt, const float* __restrict__ att_s_g,
        const float* __restrict__ att_d_g, unsigned char* __restrict__ C,
        float* __restrict__ out_as, float* __restrict__ out_ad, int M) {
    constexpr int LDP = 40;                    // 80 B row: 2-way bank alias only (free)
    __shared__ __align__(16) unsigned short As[128 * LDP];
    __shared__ __align__(16) unsigned short Bs[256 * LDP];
    __shared__ float att_l[512];               // [0:256) att_s, [256:512) att_d (flat col)
    int tid = threadIdx.x;
    int bm = blockIdx.x * 128;
    int wave = tid >> 6, lane = tid & 63;
    int wr = wave >> 1, wc = wave & 1;
    int lg = lane >> 4, lr = lane & 15;

    att_l[tid] = (tid < 256) ? att_s_g[tid] : att_d_g[tid - 256];

    f32x4 acc[2][8] = {};

    for (int k0 = 0; k0 < 256; k0 += 32) {
        __syncthreads();
        {   // stage A: fp32 -> bf16
            int row = tid >> 2, part = tid & 3;
            int gr = bm + row;
            float4 v0, v1;
            if (gr < M) {
                const float4* p = (const float4*)(A + (size_t)gr * 256 + k0 + part * 8);
                v0 = p[0]; v1 = p[1];
            } else {
                v0 = make_float4(0.f,0.f,0.f,0.f); v1 = v0;
            }
            unsigned short* w = &As[row * LDP + part * 8];
            w[0]=f2bf(v0.x); w[1]=f2bf(v0.y); w[2]=f2bf(v0.z); w[3]=f2bf(v0.w);
            w[4]=f2bf(v1.x); w[5]=f2bf(v1.y); w[6]=f2bf(v1.z); w[7]=f2bf(v1.w);
        }
        {   // stage B
            int col = tid >> 1, part = tid & 1;
            const uint4* p = (const uint4*)(Bt + (size_t)col * 256 + k0 + part * 16);
            uint4 u0 = p[0], u1 = p[1];
            *(uint4*)&Bs[col * LDP + part * 16]     = u0;
            *(uint4*)&Bs[col * LDP + part * 16 + 8] = u1;
        }
        __syncthreads();
        short8_t a[2], b[8];
        #pragma unroll
        for (int i = 0; i < 2; i++)
            a[i] = *(const short8_t*)&As[(wr * 32 + i * 16 + lr) * LDP + lg * 8];
        #pragma unroll
        for (int j = 0; j < 8; j++)
            b[j] = *(const short8_t*)&Bs[(wc * 128 + j * 16 + lr) * LDP + lg * 8];
        #pragma unroll
        for (int i = 0; i < 2; i++)
            #pragma unroll
            for (int j = 0; j < 8; j++)
                acc[i][j] = __builtin_amdgcn_mfma_f32_16x16x32_bf16(a[i], b[j], acc[i][j], 0, 0, 0);
    }
    float ws[8], wd[8];
    #pragma unroll
    for (int j = 0; j < 8; j++) {
        int c = wc * 128 + j * 16 + lr;
        ws[j] = att_l[c]; wd[j] = att_l[256 + c];
    }
    #pragma unroll
    for (int i = 0; i < 2; i++) {
        #pragma unroll
        for (int b2 = 0; b2 < 4; b2++) {
            int row = bm + wr * 32 + i * 16 + lg * 4 + b2;
            #pragma unroll
            for (int j = 0; j < 8; j++) {
                int col = wc * 128 + j * 16 + lr;
                if (row < M) C[(size_t)row * 256 + col] = f2fp8(acc[i][j][b2]);
            }
            float s0=0.f, s1=0.f, d0=0.f, d1=0.f;
            #pragma unroll
            for (int j = 0; j < 4; j++) { float v = acc[i][j][b2];   s0 += v*ws[j];   d0 += v*wd[j]; }
            #pragma unroll
            for (int j = 4; j < 8; j++) { float v = acc[i][j][b2];   s1 += v*ws[j];   d1 += v*wd[j]; }
            #pragma unroll
            for (int off = 1; off < 16; off <<= 1) {
                s0 += __shfl_xor(s0, off); s1 += __shfl_xor(s1, off);
                d0 += __shfl_xor(d0, off); d1 += __shfl_xor(d1, off);
            }
            if (lr == 0 && row < M) {
                out_as[row * 4 + wc * 2]     = s0;
                out_as[row * 4 + wc * 2 + 1] = s1;
                out_ad[row * 4 + wc * 2]     = d0;
                out_ad[row * 4 + wc * 2 + 1] = d1;
            }
        }
    }
}

// ---------------- K=64 MFMA GEMM (round-8 win, kept) ----------------

template<int NC, bool ATT>
__global__ __launch_bounds__(256) void k_gemm_k64_mfma(const float* __restrict__ A,
        const unsigned short* __restrict__ Bt,
        const float* __restrict__ att_s_g, const float* __restrict__ att_d_g,
        unsigned char* __restrict__ C, float* __restrict__ out_as,
        float* __restrict__ out_ad, int M) {
    constexpr int NF  = NC / 16;               // col frags per wave (8 or 2)
    constexpr int LDP = 72;                    // 64 bf16 + 8 pad
    __shared__ __align__(16) unsigned short As[64 * LDP];
    __shared__ __align__(16) unsigned short Bs[NC * LDP];
    __shared__ float att_l[ATT ? 2 * NC : 1];
    int tid = threadIdx.x;
    int bm = blockIdx.x * 64;
    int wave = tid >> 6, lane = tid & 63, lg = lane >> 4, lr = lane & 15;

    if constexpr (ATT) {
        if (tid < 2 * NC)
            att_l[tid] = (tid < NC) ? att_s_g[tid] : att_d_g[tid - NC];
    }
    {   // stage A: 64 rows x 64 k fp32 -> bf16 (16 values/thread)
        int row = tid >> 2, part = tid & 3;
        int gr = bm + row;
        float4 v0, v1, v2, v3;
        if (gr < M) {
            const float4* p = (const float4*)(A + (size_t)gr * 64 + part * 16);
            v0 = p[0]; v1 = p[1]; v2 = p[2]; v3 = p[3];
        } else {
            v0 = make_float4(0.f,0.f,0.f,0.f); v1 = v0; v2 = v0; v3 = v0;
        }
        unsigned short* w = &As[row * LDP + part * 16];
        w[0]=f2bf(v0.x);  w[1]=f2bf(v0.y);  w[2]=f2bf(v0.z);  w[3]=f2bf(v0.w);
        w[4]=f2bf(v1.x);  w[5]=f2bf(v1.y);  w[6]=f2bf(v1.z);  w[7]=f2bf(v1.w);
        w[8]=f2bf(v2.x);  w[9]=f2bf(v2.y);  w[10]=f2bf(v2.z); w[11]=f2bf(v2.w);
        w[12]=f2bf(v3.x); w[13]=f2bf(v3.y); w[14]=f2bf(v3.z); w[15]=f2bf(v3.w);
    }
    for (int i = tid; i < NC * 8; i += 256) {
        int c = i >> 3, part = i & 7;
        *(uint4*)&Bs[c * LDP + part * 8] = *(const uint4*)(Bt + (size_t)c * 64 + part * 8);
    }
    __syncthreads();

    f32x4 acc[NF] = {};
    short8_t a0 = *(const short8_t*)&As[(wave * 16 + lr) * LDP + lg * 8];
    short8_t a1 = *(const short8_t*)&As[(wave * 16 + lr) * LDP + 32 + lg * 8];
    #pragma unroll
    for (int j = 0; j < NF; j++) {
        short8_t b0 = *(const short8_t*)&Bs[(j * 16 + lr) * LDP + lg * 8];
        short8_t b1 = *(const short8_t*)&Bs[(j * 16 + lr) * LDP + 32 + lg * 8];
        acc[j] = __builtin_amdgcn_mfma_f32_16x16x32_bf16(a0, b0, acc[j], 0, 0, 0);
        acc[j] = __builtin_amdgcn_mfma_f32_16x16x32_bf16(a1, b1, acc[j], 0, 0, 0);
    }
    float ws[NF], wd[NF];
    if constexpr (ATT) {
        #pragma unroll
        for (int j = 0; j < NF; j++) { ws[j] = att_l[j * 16 + lr]; wd[j] = att_l[NC + j * 16 + lr]; }
    }
    #pragma unroll
    for (int b2 = 0; b2 < 4; b2++) {
        int row = bm + wave * 16 + lg * 4 + b2;
        #pragma unroll
        for (int j = 0; j < NF; j++)
            if (row < M) C[(size_t)row * NC + j * 16 + lr] = f2fp8(acc[j][b2]);
        if constexpr (ATT) {   // heads = 2
            float s0=0.f, s1=0.f, d0=0.f, d1=0.f;
            #pragma unroll
            for (int j = 0; j < 4; j++) { float v = acc[j][b2]; s0 += v*ws[j]; d0 += v*wd[j]; }
            #pragma unroll
            for (int j = 4; j < 8; j++) { float v = acc[j][b2]; s1 += v*ws[j]; d1 += v*wd[j]; }
            #pragma unroll
            for (int off = 1; off < 16; off <<= 1) {
                s0 += __shfl_xor(s0, off); s1 += __shfl_xor(s1, off);
                d0 += __shfl_xor(d0, off); d1 += __shfl_xor(d1, off);
            }
            if (lr == 0 && row < M) {
                out_as[row * 2]     = s0;
                out_as[row * 2 + 1] = s1;
                out_ad[row * 2]     = d0;
                out_ad[row * 2 + 1] = d1;
            }
        }
    }
}

// ---------------- fused GAT aggregate, HEADS=4 (proven round-7/9 structure) ----------------
// One wave per node, 1 edge per phase-2 iteration, 4B/lane.

__global__ __launch_bounds__(256) void k_gat_fused4(const unsigned char* __restrict__ hpre,
        const float* __restrict__ as_n, const float* __restrict__ ad_n,
        const float* __restrict__ bias,
        const int* __restrict__ offs, const int* __restrict__ csr,
        float* __restrict__ out, int n_nodes) {
    __shared__ int   s_off[4][64];
    __shared__ float s_p[4][64 * 4];
    int wif  = threadIdx.x >> 6;
    int lane = threadIdx.x & 63;
    int n = blockIdx.x * 4 + wif;
    if (n >= n_nodes) return;
    const int beg = offs[n];
    const int deg = offs[n + 1] - beg;

    int h_id = lane >> 4, dq = lane & 15;
    const int lane_off = h_id * 64 + dq * 4;   // byte offset within 256 B row

    float4 t = *(const float4*)(ad_n + (size_t)n * 4);
    float adv[4] = {t.x, t.y, t.z, t.w};

    float sumh = 0.f;
    float acc[4] = {};

    for (int j0 = 0; j0 < deg; j0 += 64) {
        int j = j0 + lane;
        int cnt = min(64, deg - j0);
        if (j < deg) {
            int s = csr[beg + j];
            s_off[wif][lane] = s * 256;
            float4 tv = *(const float4*)(as_n + (size_t)s * 4);
            float ev[4] = {tv.x, tv.y, tv.z, tv.w};
            #pragma unroll
            for (int h = 0; h < 4; h++) {
                float e = ev[h] + adv[h];
                e = fmaxf(e, 0.2f * e);
                s_p[wif][lane * 4 + h] = __expf(e);
            }
        }
        #pragma unroll 4
        for (int q = 0; q < cnt; q++) {
            int off = s_off[wif][q];
            float p = s_p[wif][q * 4 + h_id];
            sumh += p;
            unsigned v = *(const unsigned*)(hpre + off + lane_off);
            f32x2 l = fp8lo(v), h2 = fp8hi(v);
            acc[0] += p * l[0]; acc[1] += p * l[1];
            acc[2] += p * h2[0]; acc[3] += p * h2[1];
        }
    }
    float inv = 1.0f / (sumh + 1e-16f);
    float r[4];
    #pragma unroll
    for (int c = 0; c < 4; c++) r[c] = acc[c] * inv;
    #pragma unroll
    for (int c = 0; c < 4; c++) {
        r[c] += __shfl_xor(r[c], 16);
        r[c] += __shfl_xor(r[c], 32);
        r[c] *= 0.25f;
    }
    if (h_id == 0) {
        float4 b = *(const float4*)(bias + dq * 4);
        float4 o;
        o.x = fmaxf(r[0] + b.x, 0.f); o.y = fmaxf(r[1] + b.y, 0.f);
        o.z = fmaxf(r[2] + b.z, 0.f); o.w = fmaxf(r[3] + b.w, 0.f);
        *(float4*)(out + (size_t)n * 64 + dq * 4) = o;
    }
}

// ---------------- fused GAT aggregate, HEADS=2: 32 lanes per node ----------------
// Half-wave per node (2 nodes/wave): lane covers 4 B of the 128 B row -> same
// cache-line requests as 64-lane/2B but half the VALU instructions per edge.

__global__ __launch_bounds__(256) void k_gat_fused2(const unsigned char* __restrict__ hpre,
        const float* __restrict__ as_n, const float* __restrict__ ad_n,
        const float* __restrict__ bias,
        const int* __restrict__ offs, const int* __restrict__ csr,
        float* __restrict__ out, int n_nodes) {
    __shared__ int   s_off[4][2][32];
    __shared__ float s_p[4][2][64];
    int wif  = threadIdx.x >> 6;
    int lane = threadIdx.x & 63;
    int half = lane >> 5;                      // node within wave
    int l    = lane & 31;
    int n = blockIdx.x * 8 + wif * 2 + half;
    bool act = n < n_nodes;
    int beg = 0, deg = 0;
    float adv0 = 0.f, adv1 = 0.f;
    if (act) {
        beg = offs[n];
        deg = offs[n + 1] - beg;
        float2 t = *(const float2*)(ad_n + (size_t)n * 2);
        adv0 = t.x; adv1 = t.y;
    }
    int h_id = l >> 4, dq = l & 15;
    const int lane_off = h_id * 64 + dq * 4;   // byte offset within 128 B row

    float sumh = 0.f;
    float acc[4] = {};

    for (int j0 = 0; j0 < deg; j0 += 32) {
        int j = j0 + l;
        int cnt = min(32, deg - j0);
        if (j < deg) {
            int s = csr[beg + j];
            s_off[wif][half][l] = s * 128;
            float2 t = *(const float2*)(as_n + (size_t)s * 2);
            float e0 = t.x + adv0; e0 = fmaxf(e0, 0.2f * e0);
            float e1 = t.y + adv1; e1 = fmaxf(e1, 0.2f * e1);
            s_p[wif][half][l * 2]     = __expf(e0);
            s_p[wif][half][l * 2 + 1] = __expf(e1);
        }
        #pragma unroll 4
        for (int q = 0; q < cnt; q++) {
            int off = s_off[wif][half][q];
            float p = s_p[wif][half][q * 2 + h_id];
            sumh += p;
            unsigned v = *(const unsigned*)(hpre + off + lane_off);
            f32x2 lo = fp8lo(v), hi = fp8hi(v);
            acc[0] += p * lo[0]; acc[1] += p * lo[1];
            acc[2] += p * hi[0]; acc[3] += p * hi[1];
        }
    }
    float inv = 1.0f / (sumh + 1e-16f);
    float r[4];
    #pragma unroll
    for (int c = 0; c < 4; c++) r[c] = acc[c] * inv;
    // combine the two heads (lane ^ 16 stays within the 32-lane half), then mean
    #pragma unroll
    for (int c = 0; c < 4; c++) {
        r[c] += __shfl_xor(r[c], 16);
        r[c] *= 0.5f;
    }
    if (act && h_id == 0) {
        float4 b = *(const float4*)(bias + dq * 4);
        float4 o;
        o.x = fmaxf(r[0] + b.x, 0.f); o.y = fmaxf(r[1] + b.y, 0.f);
        o.z = fmaxf(r[2] + b.z, 0.f); o.w = fmaxf(r[3] + b.w, 0.f);
        *(float4*)(out + (size_t)n * 64 + dq * 4) = o;
    }
}

// ---------------- fused GCN aggregate + MLP head + sigmoid ----------------
// 8 lanes per node: gather h3 (4 dims/lane, fp8), relu+bias in-register, then
// the 32->16->1 MLP via 3-step shfl reduction — h3 never touches memory.

__global__ __launch_bounds__(256) void k_gcn_mlp(const unsigned char* __restrict__ hpre,
        const float* __restrict__ dinv, const float* __restrict__ bias,
        const int* __restrict__ offs, const int* __restrict__ csr,
        const float* __restrict__ Wh1, const float* __restrict__ bh1,
        const float* __restrict__ Wh2, const float* __restrict__ bh2,
        float* __restrict__ out, int n_nodes) {
    __shared__ float w1[512];
    __shared__ float w2[16];
    __shared__ float b1s[16];
    __shared__ float b2s;
    int tid = threadIdx.x;
    for (int i = tid; i < 512; i += 256) w1[i] = Wh1[i];
    if (tid < 16) { w2[tid] = Wh2[tid]; b1s[tid] = bh1[tid]; }
    if (tid == 0) b2s = bh2[0];
    __syncthreads();

    int gid = blockIdx.x * 256 + tid;
    int n = gid >> 3, q = gid & 7;
    if (n >= n_nodes) return;
    const int beg = offs[n], end = offs[n + 1];
    float4 acc = make_float4(0.f,0.f,0.f,0.f);
    #pragma unroll 4
    for (int j = beg; j < end; j++) {
        int s = csr[j];
        float ds = dinv[s];
        unsigned v = *(const unsigned*)(hpre + (size_t)s * 32 + q * 4);
        f32x2 l = fp8lo(v), h2 = fp8hi(v);
        acc.x += ds * l[0]; acc.y += ds * l[1];
        acc.z += ds * h2[0]; acc.w += ds * h2[1];
    }
    float dn = dinv[n];
    float4 b = *(const float4*)(bias + q * 4);
    float x0 = fmaxf(acc.x * dn + b.x, 0.f);
    float x1 = fmaxf(acc.y * dn + b.y, 0.f);
    float x2 = fmaxf(acc.z * dn + b.z, 0.f);
    float x3 = fmaxf(acc.w * dn + b.w, 0.f);

    // MLP layer 1 partials: this lane holds x[k] for k = q*4 .. q*4+3
    float pz[16];
    const float* w1r = w1 + q * 64;            // rows q*4..q*4+3, 16 cols each
    #pragma unroll
    for (int jj = 0; jj < 16; jj++)
        pz[jj] = x0 * w1r[jj] + x1 * w1r[16 + jj] + x2 * w1r[32 + jj] + x3 * w1r[48 + jj];
    #pragma unroll
    for (int off = 1; off < 8; off <<= 1)
        #pragma unroll
        for (int jj = 0; jj < 16; jj++) pz[jj] += __shfl_xor(pz[jj], off);
    float acc2 = b2s;
    #pragma unroll
    for (int jj = 0; jj < 16; jj++)
        acc2 += fmaxf(pz[jj] + b1s[jj], 0.f) * w2[jj];
    if (q == 0) out[n] = 1.0f / (1.0f + expf(-acc2));
}

// ---------------- launch ----------------

extern "C" void kernel_launch(void* const* d_in, const int* in_sizes, int n_in,
                              void* d_out, int out_size, void* d_ws, size_t ws_size,
                              hipStream_t stream) {
    const float* x   = (const float*)d_in[0];
    const int*   ei  = (const int*)d_in[1];
    const float* W1  = (const float*)d_in[2];
    const float* a1s = (const float*)d_in[3];
    const float* a1d = (const float*)d_in[4];
    const float* b1  = (const float*)d_in[5];
    const float* W2  = (const float*)d_in[6];
    const float* a2s = (const float*)d_in[7];
    const float* a2d = (const float*)d_in[8];
    const float* b2  = (const float*)d_in[9];
    const float* Wg  = (const float*)d_in[10];
    const float* bg  = (const float*)d_in[11];
    const float* Wh1 = (const float*)d_in[12];
    const float* bh1 = (const float*)d_in[13];
    const float* Wh2 = (const float*)d_in[14];
    const float* bh2 = (const float*)d_in[15];

    const int N = in_sizes[0] / 256;
    const int E = in_sizes[1] / 2;
    const int* srcs = ei;
    const int* dsts = ei + E;

    // workspace layout
    float* R0   = (float*)d_ws;              // N*256 fp32 region; reused as fp8 hpre
    float* R1   = R0 + (size_t)N * 256;      // N*64  : h1 (fp32)
    float* R2   = R1 + (size_t)N * 64;       // N*64  : h2 (fp32)
    float* As_  = R2 + (size_t)N * 64;       // N*4
    float* Ad_  = As_ + (size_t)N * 4;       // N*4
    float* dinv = Ad_ + (size_t)N * 4;       // N
    int* deg    = (int*)(dinv + N);          // N
    int* offs   = deg + N;                   // N+1
    int* cursor = offs + (N + 1);            // N
    int* csr    = cursor + N;                // E + N
    int* parts  = csr + (E + N);             // <=256
    unsigned short* W1t = (unsigned short*)(parts + 256);   // 256*256 bf16
    unsigned short* W2t = W1t + 65536;                      // 128*64 bf16
    unsigned short* Wgt = W2t + 8192;                       // 32*64 bf16
    unsigned char*  HP  = (unsigned char*)R0;               // fp8 h1pre/h2pre/h3pre

    // ---- CSR build (with self loops; XCD-windowed atomics) + weight prep ----
    int wsize = cdiv(N, 8);
    int fillBlocks = cdiv(E, 1024) * 8;
    hipMemsetAsync(deg, 0, (size_t)N * sizeof(int), stream);
    k_count_prep<<<fillBlocks + 256, 256, 0, stream>>>(dsts, E, deg, wsize, fillBlocks,
                                                       W1, W2, Wg, W1t, W2t, Wgt);
    int nch = cdiv(N, 1024);
    k_scan_partial<<<nch, 256, 0, stream>>>(deg, N, parts);
    k_scan_final<<<nch, 256, 0, stream>>>(deg, N, parts, offs, cursor, csr, dinv);
    k_fill_csr_win<<<fillBlocks, 256, 0, stream>>>(srcs, dsts, E, cursor, csr, wsize);

    // ---- GAT layer 1 (heads=4): MFMA GEMM w/ fused att-dots -> fp8 hpre ----
    k_gemm1_mfma<<<cdiv(N, 128), 512, 0, stream>>>(x, W1t, a1s, a1d, HP, As_, Ad_, N);
    k_gat_fused4<<<cdiv(N, 4), 256, 0, stream>>>(HP, As_, Ad_, b1, offs, csr, R1, N);

    // ---- GAT layer 2 (heads=2): MFMA GEMM w/ fused att-dots -> fp8 hpre ----
    k_gemm_k64_mfma<128, true><<<cdiv(N, 64), 256, 0, stream>>>(R1, W2t, a2s, a2d, HP, As_, Ad_, N);
    k_gat_fused2<<<cdiv(N, 8), 256, 0, stream>>>(HP, As_, Ad_, b2, offs, csr, R2, N);

    // ---- GCN GEMM -> fp8, then fused GCN-aggregate + MLP head ----
    k_gemm_k64_mfma<32, false><<<cdiv(N, 64), 256, 0, stream>>>(R2, Wgt, nullptr, nullptr, HP, nullptr, nullptr, N);
    k_gcn_mlp<<<cdiv(N * 8, 256), 256, 0, stream>>>(HP, dinv, bg, offs, csr,
                                                    Wh1, bh1, Wh2, bh2, (float*)d_out, N);
}